// Round 1
// baseline (1861.396 us; speedup 1.0000x reference)
//
#include <hip/hip_runtime.h>
#include <math.h>

#define MUL0 64
#define MUL1 32
#define RADF 8
#define HIDF 64
#define WNUM 192
#define NODE_F 160   // 64 + 96
#define AGG_F  384   // 64(A) + 32(D) + 192(B) + 96(C)

#define INV_SQRT64 0.125f
#define INV_SQRT32 0.17677669529663687f
#define INV_SQRT8  0.35355339059327373f
#define INV_SQRT96 0.10206207261596575f
#define INV_SQRT10 0.31622776601683794f
#define INV_SQRT3  0.5773502691896258f

// ---------------- kernel 1: f = _lin(s_in, v_in, W1_s, W1_v, attr) ----------------
__global__ void k_node_lin(const float* __restrict__ node_input,
                           const float* __restrict__ node_attr,
                           const float* __restrict__ W1_s,
                           const float* __restrict__ W1_v,
                           float* __restrict__ f, int N)
{
    int t = blockIdx.x * blockDim.x + threadIdx.x;
    int n = t / NODE_F;
    int c = t % NODE_F;
    if (n >= N) return;
    const float* row = node_input + (size_t)n * NODE_F;
    float attr = node_attr[n];
    float acc = 0.f;
    if (c < MUL0) {
        #pragma unroll
        for (int u = 0; u < MUL0; ++u)
            acc = fmaf(row[u], W1_s[u * MUL0 + c], acc);
        acc *= attr * INV_SQRT64;
    } else {
        int cc = c - MUL0;
        int v = cc / 3, d = cc % 3;
        #pragma unroll
        for (int u = 0; u < MUL1; ++u)
            acc = fmaf(row[MUL0 + u * 3 + d], W1_v[u * MUL1 + v], acc);
        acc *= attr * INV_SQRT32;
    }
    f[(size_t)n * NODE_F + c] = acc;
}

// ---------------- kernel 2: per-edge MLP + tensor product + atomic scatter ----------------
__global__ __launch_bounds__(256) void k_edge(
    const float* __restrict__ f,
    const float* __restrict__ edge_attr,
    const float* __restrict__ edge_scalars,
    const float* __restrict__ fcW1,
    const float* __restrict__ fcW2,
    const int* __restrict__ edge_src,
    const int* __restrict__ edge_dst,
    float* agg, int E)
{
    __shared__ float s_fcW2[HIDF * WNUM];   // 48 KB
    for (int i = threadIdx.x; i < HIDF * WNUM; i += 256)
        s_fcW2[i] = fcW2[i];
    __syncthreads();

    int wv   = threadIdx.x >> 6;
    int lane = threadIdx.x & 63;
    int e = blockIdx.x * 4 + wv;
    if (e >= E) return;

    int src = edge_src[e];
    int dst = edge_dst[e];

    // hidden: h[lane] = silu(es @ fcW1 / sqrt(8))
    const float* es = edge_scalars + (size_t)e * RADF;
    float hval = 0.f;
    #pragma unroll
    for (int r = 0; r < RADF; ++r)
        hval = fmaf(es[r], fcW1[r * HIDF + lane], hval);
    hval *= INV_SQRT8;
    hval = hval / (1.0f + __expf(-hval));   // silu

    // w[j] = (h @ fcW2)/8 ; lane owns j = lane, 64+lane, 128+lane
    float w0 = 0.f, w1 = 0.f, w2 = 0.f;
    #pragma unroll 8
    for (int k = 0; k < HIDF; ++k) {
        float hk = __shfl(hval, k);
        const float* rowW = s_fcW2 + k * WNUM;
        w0 = fmaf(hk, rowW[lane], w0);
        w1 = fmaf(hk, rowW[64 + lane], w1);
        w2 = fmaf(hk, rowW[128 + lane], w2);
    }
    w0 *= INV_SQRT64; w1 *= INV_SQRT64; w2 *= INV_SQRT64;

    float y0  = edge_attr[(size_t)e * 4 + 0];
    float y1a = edge_attr[(size_t)e * 4 + 1];
    float y1b = edge_attr[(size_t)e * 4 + 2];
    float y1c = edge_attr[(size_t)e * 4 + 3];

    const float* fs = f + (size_t)src * NODE_F;
    float xs = fs[lane];
    float* aggd = agg + (size_t)dst * AGG_F;

    // wD[lane] (lane<32) = w[160+lane] = w2 of lane+32  (compute pre-divergence)
    float wD = __shfl(w2, (lane + 32) & 63);

    // A: agg[0:64]
    atomicAdd(&aggd[lane], w0 * xs * y0);
    // B: agg[96 + l*3 + d]
    float bx = w1 * xs;
    atomicAdd(&aggd[96 + lane * 3 + 0], bx * y1a);
    atomicAdd(&aggd[96 + lane * 3 + 1], bx * y1b);
    atomicAdd(&aggd[96 + lane * 3 + 2], bx * y1c);

    if (lane < MUL1) {
        float xv0 = fs[MUL0 + lane * 3 + 0];
        float xv1 = fs[MUL0 + lane * 3 + 1];
        float xv2 = fs[MUL0 + lane * 3 + 2];
        // D: agg[64 + l]
        float dotv = xv0 * y1a + xv1 * y1b + xv2 * y1c;
        atomicAdd(&aggd[64 + lane], wD * dotv * INV_SQRT3);
        // C: agg[288 + l*3 + d]
        float c0 = w2 * y0;
        atomicAdd(&aggd[288 + lane * 3 + 0], c0 * xv0);
        atomicAdd(&aggd[288 + lane * 3 + 1], c0 * xv1);
        atomicAdd(&aggd[288 + lane * 3 + 2], c0 * xv2);
    }
}

// ---------------- kernel 3: output combine ----------------
__global__ void k_out(const float* __restrict__ node_input,
                      const float* __restrict__ node_attr,
                      const float* __restrict__ agg,
                      const float* __restrict__ W_sc_s,
                      const float* __restrict__ W_sc_v,
                      const float* __restrict__ W2_s,
                      const float* __restrict__ W2_v,
                      const float* __restrict__ W3,
                      float* __restrict__ out, int N)
{
    int t = blockIdx.x * blockDim.x + threadIdx.x;
    int n = t / NODE_F;
    int c = t % NODE_F;
    if (n >= N) return;
    const float* ag  = agg + (size_t)n * AGG_F;
    const float* row = node_input + (size_t)n * NODE_F;
    float attr = node_attr[n];

    // angle = 0.1 * (ms @ W3) * attr / sqrt(96);  ms = agg[:96] / sqrt(10)
    float ang = 0.f;
    #pragma unroll
    for (int j = 0; j < 96; ++j)
        ang = fmaf(ag[j], W3[j], ang);
    ang *= INV_SQRT10 * 0.1f * INV_SQRT96 * attr;
    float sn = sinf(ang), cs = cosf(ang);

    float conv, sc;
    if (c < MUL0) {
        float acc = 0.f;
        #pragma unroll
        for (int j = 0; j < 96; ++j)
            acc = fmaf(ag[j], W2_s[j * MUL0 + c], acc);
        conv = acc * INV_SQRT10 * INV_SQRT96 * attr;
        float a2 = 0.f;
        #pragma unroll
        for (int u = 0; u < MUL0; ++u)
            a2 = fmaf(row[u], W_sc_s[u * MUL0 + c], a2);
        sc = a2 * INV_SQRT64 * attr;
    } else {
        int cc = c - MUL0;
        int v = cc / 3, d = cc % 3;
        float acc = 0.f;
        #pragma unroll
        for (int j = 0; j < 96; ++j)
            acc = fmaf(ag[96 + j * 3 + d], W2_v[j * MUL1 + v], acc);
        conv = acc * INV_SQRT10 * INV_SQRT96 * attr;
        float a2 = 0.f;
        #pragma unroll
        for (int u = 0; u < MUL1; ++u)
            a2 = fmaf(row[MUL0 + u * 3 + d], W_sc_v[u * MUL1 + v], a2);
        sc = a2 * INV_SQRT32 * attr;
    }
    out[(size_t)n * NODE_F + c] = cs * sc + sn * conv;
}

extern "C" void kernel_launch(void* const* d_in, const int* in_sizes, int n_in,
                              void* d_out, int out_size, void* d_ws, size_t ws_size,
                              hipStream_t stream)
{
    const float* node_input   = (const float*)d_in[0];
    const float* node_attr    = (const float*)d_in[1];
    const float* edge_attr    = (const float*)d_in[2];
    const float* edge_scalars = (const float*)d_in[3];
    const float* W_sc_s       = (const float*)d_in[4];
    const float* W_sc_v       = (const float*)d_in[5];
    const float* W1_s         = (const float*)d_in[6];
    const float* W1_v         = (const float*)d_in[7];
    const float* W2_s         = (const float*)d_in[8];
    const float* W2_v         = (const float*)d_in[9];
    const float* W3           = (const float*)d_in[10];
    const float* fcW1         = (const float*)d_in[11];
    const float* fcW2         = (const float*)d_in[12];
    const int*   edge_src     = (const int*)d_in[13];
    const int*   edge_dst     = (const int*)d_in[14];
    float* out = (float*)d_out;

    const int N = in_sizes[1];        // node_attr is (N,1)
    const int E = in_sizes[13];       // edge_src is (E,)

    float* agg = (float*)d_ws;                                         // N*384 f32
    float* f   = (float*)((char*)d_ws + (size_t)N * AGG_F * sizeof(float)); // N*160 f32

    hipMemsetAsync(agg, 0, (size_t)N * AGG_F * sizeof(float), stream);

    int nt = N * NODE_F;
    k_node_lin<<<(nt + 255) / 256, 256, 0, stream>>>(node_input, node_attr, W1_s, W1_v, f, N);
    k_edge<<<(E + 3) / 4, 256, 0, stream>>>(f, edge_attr, edge_scalars, fcW1, fcW2,
                                            edge_src, edge_dst, agg, E);
    k_out<<<(nt + 255) / 256, 256, 0, stream>>>(node_input, node_attr, agg,
                                                W_sc_s, W_sc_v, W2_s, W2_v, W3, out, N);
}

// Round 2
// 1823.715 us; speedup vs baseline: 1.0207x; 1.0207x over previous
//
#include <hip/hip_runtime.h>
#include <math.h>

#define MUL0 64
#define MUL1 32
#define RADF 8
#define HIDF 64
#define WNUM 192
#define NODE_F 160   // 64 + 96
#define AGG_F  384   // 64(A) + 32(D) + 192(B) + 96(C)

#define INV_SQRT64 0.125f
#define INV_SQRT32 0.17677669529663687f
#define INV_SQRT8  0.35355339059327373f
#define INV_SQRT96 0.10206207261596575f
#define INV_SQRT10 0.31622776601683794f
#define INV_SQRT3  0.5773502691896258f

// ---------------- kernel 1: f = _lin(s_in, v_in, W1_s, W1_v, attr) ----------------
__global__ void k_node_lin(const float* __restrict__ node_input,
                           const float* __restrict__ node_attr,
                           const float* __restrict__ W1_s,
                           const float* __restrict__ W1_v,
                           float* __restrict__ f, int N)
{
    int t = blockIdx.x * blockDim.x + threadIdx.x;
    int n = t / NODE_F;
    int c = t % NODE_F;
    if (n >= N) return;
    const float* row = node_input + (size_t)n * NODE_F;
    float attr = node_attr[n];
    float acc = 0.f;
    if (c < MUL0) {
        #pragma unroll
        for (int u = 0; u < MUL0; ++u)
            acc = fmaf(row[u], W1_s[u * MUL0 + c], acc);
        acc *= attr * INV_SQRT64;
    } else {
        int cc = c - MUL0;
        int v = cc / 3, d = cc % 3;
        #pragma unroll
        for (int u = 0; u < MUL1; ++u)
            acc = fmaf(row[MUL0 + u * 3 + d], W1_v[u * MUL1 + v], acc);
        acc *= attr * INV_SQRT32;
    }
    f[(size_t)n * NODE_F + c] = acc;
}

// ---------------- CSR build ----------------
__global__ void k_count(const int* __restrict__ edge_dst, int* deg, int E)
{
    int e = blockIdx.x * blockDim.x + threadIdx.x;
    if (e < E) atomicAdd(&deg[edge_dst[e]], 1);
}

__global__ __launch_bounds__(1024) void k_scan(const int* __restrict__ deg,
                                               int* __restrict__ off,
                                               int* __restrict__ cur, int N)
{
    __shared__ int swsum[16];
    __shared__ int swoff[16];
    __shared__ int sbase;
    __shared__ int stotal;
    int lane = threadIdx.x & 63, wid = threadIdx.x >> 6;
    if (threadIdx.x == 0) sbase = 0;
    __syncthreads();
    for (int base = 0; base < N; base += 1024) {
        int i = base + threadIdx.x;
        int v = (i < N) ? deg[i] : 0;
        int val = v;
        #pragma unroll
        for (int s = 1; s < 64; s <<= 1) {
            int t = __shfl_up(val, s);
            if (lane >= s) val += t;
        }
        if (lane == 63) swsum[wid] = val;
        __syncthreads();
        if (threadIdx.x < 16) {
            int x = swsum[threadIdx.x];
            int xv = x;
            #pragma unroll
            for (int s = 1; s < 16; s <<= 1) {
                int t = __shfl_up(xv, s);
                if ((int)threadIdx.x >= s) xv += t;
            }
            swoff[threadIdx.x] = xv - x;
            if (threadIdx.x == 15) stotal = xv;
        }
        __syncthreads();
        int excl = (val - v) + swoff[wid] + sbase;
        if (i < N) { off[i] = excl; cur[i] = excl; }
        __syncthreads();
        if (threadIdx.x == 0) sbase += stotal;
        __syncthreads();
    }
    if (threadIdx.x == 0) off[N] = sbase;
}

__global__ void k_scatter(const int* __restrict__ edge_dst,
                          int* cur, int* __restrict__ csr, int E)
{
    int e = blockIdx.x * blockDim.x + threadIdx.x;
    if (e < E) {
        int d = edge_dst[e];
        int pos = atomicAdd(&cur[d], 1);
        csr[pos] = e;
    }
}

// ---------------- kernel 2: dst-gather, no atomics ----------------
__global__ __launch_bounds__(256) void k_gather(
    const float* __restrict__ f,
    const float* __restrict__ node_attr,
    const float* __restrict__ edge_attr,
    const float* __restrict__ edge_scalars,
    const float* __restrict__ fcW1,
    const float* __restrict__ fcW2,
    const float* __restrict__ W3,
    const int* __restrict__ edge_src,
    const int* __restrict__ off,
    const int* __restrict__ csr,
    float* __restrict__ agg,
    float* __restrict__ trig, int N)
{
    __shared__ float s_fcW2[HIDF * WNUM];   // 48 KB
    for (int i = threadIdx.x; i < HIDF * WNUM; i += 256)
        s_fcW2[i] = fcW2[i];
    __syncthreads();

    int lane = threadIdx.x & 63;
    int gwave = blockIdx.x * 4 + (threadIdx.x >> 6);
    int nwaves = gridDim.x * 4;

    // fcW1 column `lane` in registers
    float w1reg[RADF];
    #pragma unroll
    for (int r = 0; r < RADF; ++r)
        w1reg[r] = fcW1[r * HIDF + lane];

    float w3a = W3[lane];                       // for A part
    float w3d = (lane >= 32) ? W3[lane + 32] : 0.f; // for D part (lane-32 -> 64+(lane-32))

    for (int n = gwave; n < N; n += nwaves) {
        int beg = off[n], end = off[n + 1];

        float accA = 0.f, accB0 = 0.f, accB1 = 0.f, accB2 = 0.f;
        float accX0 = 0.f, accX1 = 0.f, accX2 = 0.f;  // lanes<32: C[0..2]; lanes>=32: X0 = D

        for (int p = beg; p < end; p += 4) {
            float h[4]; int srcs[4];
            float y0[4], ya[4], yb[4], yc[4];
            #pragma unroll
            for (int q = 0; q < 4; ++q) {
                int idx = p + q;
                bool valid = idx < end;
                int e = valid ? csr[idx] : 0;
                srcs[q] = valid ? edge_src[e] : 0;
                const float* ea = edge_attr + (size_t)e * 4;
                y0[q] = valid ? ea[0] : 0.f;
                ya[q] = valid ? ea[1] : 0.f;
                yb[q] = valid ? ea[2] : 0.f;
                yc[q] = valid ? ea[3] : 0.f;
                const float* es = edge_scalars + (size_t)e * RADF;
                float hv = 0.f;
                #pragma unroll
                for (int r = 0; r < RADF; ++r)
                    hv = fmaf(es[r], w1reg[r], hv);
                hv *= INV_SQRT8;
                hv = hv / (1.0f + __expf(-hv));
                h[q] = valid ? hv : 0.f;
            }

            float w0[4] = {0,0,0,0}, w1[4] = {0,0,0,0}, w2[4] = {0,0,0,0};
            #pragma unroll
            for (int k = 0; k < HIDF; ++k) {
                float b0 = s_fcW2[k * WNUM + lane];
                float b1 = s_fcW2[k * WNUM + 64 + lane];
                float b2 = s_fcW2[k * WNUM + 128 + lane];
                #pragma unroll
                for (int q = 0; q < 4; ++q) {
                    float hk = __int_as_float(__builtin_amdgcn_readlane(__float_as_int(h[q]), k));
                    w0[q] = fmaf(hk, b0, w0[q]);
                    w1[q] = fmaf(hk, b1, w1[q]);
                    w2[q] = fmaf(hk, b2, w2[q]);
                }
            }

            #pragma unroll
            for (int q = 0; q < 4; ++q) {
                const float* fs = f + (size_t)srcs[q] * NODE_F;
                float xs = fs[lane];
                int u = lane & 31;
                float xv0 = fs[MUL0 + u * 3 + 0];
                float xv1 = fs[MUL0 + u * 3 + 1];
                float xv2 = fs[MUL0 + u * 3 + 2];
                float W0 = w0[q] * INV_SQRT64;
                float W1 = w1[q] * INV_SQRT64;
                float W2 = w2[q] * INV_SQRT64;
                accA  += W0 * xs * y0[q];
                float bx = W1 * xs;
                accB0 += bx * ya[q];
                accB1 += bx * yb[q];
                accB2 += bx * yc[q];
                if (lane < 32) {
                    float cc = W2 * y0[q];
                    accX0 += cc * xv0;
                    accX1 += cc * xv1;
                    accX2 += cc * xv2;
                } else {
                    accX0 += W2 * (xv0 * ya[q] + xv1 * yb[q] + xv2 * yc[q]) * INV_SQRT3;
                }
            }
        }

        // angle = 0.1 * (ms @ W3) * attr / sqrt(96), ms = agg[:96]*INV_SQRT10
        float part = accA * w3a;
        if (lane >= 32) part += accX0 * w3d;
        #pragma unroll
        for (int s = 32; s >= 1; s >>= 1)
            part += __shfl_xor(part, s);
        float ang = 0.1f * INV_SQRT96 * INV_SQRT10 * node_attr[n] * part;
        if (lane == 0) {
            trig[2 * n]     = cosf(ang);
            trig[2 * n + 1] = sinf(ang);
        }

        float* aggn = agg + (size_t)n * AGG_F;
        aggn[lane] = accA;
        aggn[96 + lane * 3 + 0] = accB0;
        aggn[96 + lane * 3 + 1] = accB1;
        aggn[96 + lane * 3 + 2] = accB2;
        if (lane < 32) {
            aggn[288 + lane * 3 + 0] = accX0;
            aggn[288 + lane * 3 + 1] = accX1;
            aggn[288 + lane * 3 + 2] = accX2;
        } else {
            aggn[64 + lane - 32] = accX0;
        }
    }
}

// ---------------- kernel 3: output combine ----------------
__global__ void k_out(const float* __restrict__ node_input,
                      const float* __restrict__ node_attr,
                      const float* __restrict__ agg,
                      const float* __restrict__ trig,
                      const float* __restrict__ W_sc_s,
                      const float* __restrict__ W_sc_v,
                      const float* __restrict__ W2_s,
                      const float* __restrict__ W2_v,
                      float* __restrict__ out, int N)
{
    int t = blockIdx.x * blockDim.x + threadIdx.x;
    int n = t / NODE_F;
    int c = t % NODE_F;
    if (n >= N) return;
    const float* ag  = agg + (size_t)n * AGG_F;
    const float* row = node_input + (size_t)n * NODE_F;
    float attr = node_attr[n];
    float cs = trig[2 * n], sn = trig[2 * n + 1];

    float conv, sc;
    if (c < MUL0) {
        float acc = 0.f;
        #pragma unroll
        for (int j = 0; j < 96; ++j)
            acc = fmaf(ag[j], W2_s[j * MUL0 + c], acc);
        conv = acc * INV_SQRT10 * INV_SQRT96 * attr;
        float a2 = 0.f;
        #pragma unroll
        for (int u = 0; u < MUL0; ++u)
            a2 = fmaf(row[u], W_sc_s[u * MUL0 + c], a2);
        sc = a2 * INV_SQRT64 * attr;
    } else {
        int cc = c - MUL0;
        int v = cc / 3, d = cc % 3;
        float acc = 0.f;
        #pragma unroll
        for (int j = 0; j < 96; ++j)
            acc = fmaf(ag[96 + j * 3 + d], W2_v[j * MUL1 + v], acc);
        conv = acc * INV_SQRT10 * INV_SQRT96 * attr;
        float a2 = 0.f;
        #pragma unroll
        for (int u = 0; u < MUL1; ++u)
            a2 = fmaf(row[MUL0 + u * 3 + d], W_sc_v[u * MUL1 + v], a2);
        sc = a2 * INV_SQRT32 * attr;
    }
    out[(size_t)n * NODE_F + c] = cs * sc + sn * conv;
}

extern "C" void kernel_launch(void* const* d_in, const int* in_sizes, int n_in,
                              void* d_out, int out_size, void* d_ws, size_t ws_size,
                              hipStream_t stream)
{
    const float* node_input   = (const float*)d_in[0];
    const float* node_attr    = (const float*)d_in[1];
    const float* edge_attr    = (const float*)d_in[2];
    const float* edge_scalars = (const float*)d_in[3];
    const float* W_sc_s       = (const float*)d_in[4];
    const float* W_sc_v       = (const float*)d_in[5];
    const float* W1_s         = (const float*)d_in[6];
    const float* W1_v         = (const float*)d_in[7];
    const float* W2_s         = (const float*)d_in[8];
    const float* W2_v         = (const float*)d_in[9];
    const float* W3           = (const float*)d_in[10];
    const float* fcW1         = (const float*)d_in[11];
    const float* fcW2         = (const float*)d_in[12];
    const int*   edge_src     = (const int*)d_in[13];
    const int*   edge_dst     = (const int*)d_in[14];
    float* out = (float*)d_out;

    const int N = in_sizes[1];        // node_attr is (N,1)
    const int E = in_sizes[13];       // edge_src is (E,)

    // workspace layout
    float* agg  = (float*)d_ws;                       // N*384 f32
    float* trig = agg + (size_t)N * AGG_F;            // 2N f32
    int*   deg  = (int*)(trig + 2 * (size_t)N);       // N
    int*   off  = deg + N;                            // N+1
    int*   cur  = off + N + 1;                        // N
    int*   csr  = cur + N;                            // E
    // f lives in d_out (fully rewritten by k_out at the end)
    float* f = out;

    hipMemsetAsync(deg, 0, (size_t)N * sizeof(int), stream);

    int eb = (E + 255) / 256;
    k_count<<<eb, 256, 0, stream>>>(edge_dst, deg, E);
    k_scan<<<1, 1024, 0, stream>>>(deg, off, cur, N);
    k_scatter<<<eb, 256, 0, stream>>>(edge_dst, cur, csr, E);

    int nt = N * NODE_F;
    k_node_lin<<<(nt + 255) / 256, 256, 0, stream>>>(node_input, node_attr, W1_s, W1_v, f, N);

    k_gather<<<768, 256, 0, stream>>>(f, node_attr, edge_attr, edge_scalars,
                                      fcW1, fcW2, W3, edge_src, off, csr,
                                      agg, trig, N);

    k_out<<<(nt + 255) / 256, 256, 0, stream>>>(node_input, node_attr, agg, trig,
                                                W_sc_s, W_sc_v, W2_s, W2_v, out, N);
}

// Round 3
// 765.651 us; speedup vs baseline: 2.4311x; 2.3819x over previous
//
#include <hip/hip_runtime.h>
#include <math.h>

#define MUL0 64
#define MUL1 32
#define RADF 8
#define HIDF 64
#define WNUM 192
#define NODE_F 160   // 64 + 96
#define AGG_F  384   // 64(A) + 32(D) + 192(B) + 96(C)

#define INV_SQRT64 0.125f
#define INV_SQRT32 0.17677669529663687f
#define INV_SQRT8  0.35355339059327373f
#define INV_SQRT96 0.10206207261596575f
#define INV_SQRT10 0.31622776601683794f
#define INV_SQRT3  0.5773502691896258f

__device__ __forceinline__ float bf2f(unsigned short u) {
    return __uint_as_float((unsigned)u << 16);
}
__device__ __forceinline__ unsigned bf16pack(float a, float b) {
    unsigned ua = __float_as_uint(a);
    unsigned ub = __float_as_uint(b);
    ua = (ua + 0x7FFF + ((ua >> 16) & 1)) >> 16;
    ub = (ub + 0x7FFF + ((ub >> 16) & 1)) >> 16;
    return ua | (ub << 16);
}

// ---------------- kernel: f = _lin(s_in, v_in, W1_s, W1_v, attr) ----------------
__global__ void k_node_lin(const float* __restrict__ node_input,
                           const float* __restrict__ node_attr,
                           const float* __restrict__ W1_s,
                           const float* __restrict__ W1_v,
                           float* __restrict__ f, int N)
{
    int t = blockIdx.x * blockDim.x + threadIdx.x;
    int n = t / NODE_F;
    int c = t % NODE_F;
    if (n >= N) return;
    const float* row = node_input + (size_t)n * NODE_F;
    float attr = node_attr[n];
    float acc = 0.f;
    if (c < MUL0) {
        #pragma unroll
        for (int u = 0; u < MUL0; ++u)
            acc = fmaf(row[u], W1_s[u * MUL0 + c], acc);
        acc *= attr * INV_SQRT64;
    } else {
        int cc = c - MUL0;
        int v = cc / 3, d = cc % 3;
        #pragma unroll
        for (int u = 0; u < MUL1; ++u)
            acc = fmaf(row[MUL0 + u * 3 + d], W1_v[u * MUL1 + v], acc);
        acc *= attr * INV_SQRT32;
    }
    f[(size_t)n * NODE_F + c] = acc;
}

// ---------------- CSR build ----------------
__global__ void k_count(const int* __restrict__ edge_dst, int* deg, int E)
{
    int e = blockIdx.x * blockDim.x + threadIdx.x;
    if (e < E) atomicAdd(&deg[edge_dst[e]], 1);
}

__global__ __launch_bounds__(1024) void k_scan(const int* __restrict__ deg,
                                               int* __restrict__ off,
                                               int* __restrict__ cur, int N)
{
    __shared__ int swsum[16];
    __shared__ int swoff[16];
    __shared__ int sbase;
    __shared__ int stotal;
    int lane = threadIdx.x & 63, wid = threadIdx.x >> 6;
    if (threadIdx.x == 0) sbase = 0;
    __syncthreads();
    int ngroups = N >> 2;
    for (int base = 0; base < ngroups; base += 1024) {
        int g = base + threadIdx.x;
        int4 v = make_int4(0, 0, 0, 0);
        if (g < ngroups) v = ((const int4*)deg)[g];
        int s = v.x + v.y + v.z + v.w;
        int val = s;
        #pragma unroll
        for (int sh = 1; sh < 64; sh <<= 1) {
            int t = __shfl_up(val, sh);
            if (lane >= sh) val += t;
        }
        if (lane == 63) swsum[wid] = val;
        __syncthreads();
        if (threadIdx.x < 16) {
            int x = swsum[threadIdx.x];
            int xv = x;
            #pragma unroll
            for (int sh = 1; sh < 16; sh <<= 1) {
                int t = __shfl_up(xv, sh);
                if ((int)threadIdx.x >= sh) xv += t;
            }
            swoff[threadIdx.x] = xv - x;
            if (threadIdx.x == 15) stotal = xv;
        }
        __syncthreads();
        if (g < ngroups) {
            int b = sbase + swoff[wid] + (val - s);
            int4 o;
            o.x = b; o.y = b + v.x; o.z = o.y + v.y; o.w = o.z + v.z;
            ((int4*)off)[g] = o;
            ((int4*)cur)[g] = o;
        }
        __syncthreads();
        if (threadIdx.x == 0) sbase += stotal;
        __syncthreads();
    }
    if (threadIdx.x == 0) {
        int b = sbase;
        for (int i = (ngroups << 2); i < N; ++i) { off[i] = b; cur[i] = b; b += deg[i]; }
        off[N] = b;
    }
}

__global__ void k_scatter(const int* __restrict__ edge_dst,
                          int* cur, int* __restrict__ csr, int E)
{
    int e = blockIdx.x * blockDim.x + threadIdx.x;
    if (e < E) {
        int d = edge_dst[e];
        int pos = atomicAdd(&cur[d], 1);
        csr[pos] = e;
    }
}

// ---------------- kernel A: dense per-edge MLP (GEMM), CSR-ordered bf16 output ----------------
__global__ __launch_bounds__(256) void k_mlp(
    const float* __restrict__ edge_scalars,
    const float* __restrict__ fcW1,
    const float* __restrict__ fcW2,
    const float* __restrict__ edge_attr,
    const int* __restrict__ edge_src,
    const int* __restrict__ csr,
    const int* __restrict__ off,
    int n0, int n1,
    unsigned short* __restrict__ w,      // [chunk_edges][192] bf16
    int* __restrict__ src_perm,
    float* __restrict__ ea_perm)
{
    __shared__ float s_fcW2[HIDF * WNUM];   // 48 KB
    __shared__ float s_h[HIDF * 128];       // 32 KB
    for (int i = threadIdx.x; i < HIDF * WNUM; i += 256)
        s_fcW2[i] = fcW2[i];

    int lane = threadIdx.x & 63;
    float w1c[RADF];
    #pragma unroll
    for (int r = 0; r < RADF; ++r)
        w1c[r] = fcW1[r * HIDF + lane];

    int sbeg = off[n0], send = off[n1];
    int cnt = send - sbeg;
    int tiles = (cnt + 127) >> 7;
    int khalf = threadIdx.x >> 7;        // wave-uniform
    int i_loc = threadIdx.x & 127;
    int g_j = threadIdx.x & 15;
    int g_e = threadIdx.x >> 4;
    __syncthreads();

    for (int t = blockIdx.x; t < tiles; t += gridDim.x) {
        int P = sbeg + (t << 7);
        int m = min(128, send - P);

        // ---- phase 1: h tile ----
        {
            bool valid = i_loc < m;
            int pos = P + (valid ? i_loc : 0);
            int e = csr[pos];
            const float* es = edge_scalars + (size_t)e * RADF;
            float esr[RADF];
            #pragma unroll
            for (int r = 0; r < RADF; ++r) esr[r] = es[r];
            if (valid && khalf == 0) {
                src_perm[pos] = edge_src[e];
                float4 eav = *(const float4*)(edge_attr + (size_t)e * 4);
                *(float4*)(ea_perm + (size_t)pos * 4) = eav;
            }
            #pragma unroll
            for (int kk = 0; kk < 32; ++kk) {
                int k = khalf * 32 + kk;
                float acc = 0.f;
                #pragma unroll
                for (int r = 0; r < RADF; ++r) {
                    float c = __int_as_float(__builtin_amdgcn_readlane(__float_as_int(w1c[r]), k));
                    acc = fmaf(esr[r], c, acc);
                }
                acc *= INV_SQRT8;
                acc = acc / (1.f + __expf(-acc));
                s_h[k * 128 + i_loc] = valid ? acc : 0.f;
            }
        }
        __syncthreads();

        // ---- phase 2: w = h @ fcW2 (8 edges x 12 cols per thread) ----
        float acc[8][12];
        #pragma unroll
        for (int q = 0; q < 8; ++q)
            #pragma unroll
            for (int j = 0; j < 12; ++j) acc[q][j] = 0.f;

        const float* hbase = s_h + g_e * 8;
        const float* bbase = s_fcW2 + g_j * 12;
        #pragma unroll 2
        for (int k = 0; k < HIDF; ++k) {
            float4 h0 = *(const float4*)(hbase + k * 128);
            float4 h1 = *(const float4*)(hbase + k * 128 + 4);
            float4 b0 = *(const float4*)(bbase + k * WNUM);
            float4 b1 = *(const float4*)(bbase + k * WNUM + 4);
            float4 b2 = *(const float4*)(bbase + k * WNUM + 8);
            float hq[8]  = {h0.x, h0.y, h0.z, h0.w, h1.x, h1.y, h1.z, h1.w};
            float bj[12] = {b0.x, b0.y, b0.z, b0.w, b1.x, b1.y, b1.z, b1.w,
                            b2.x, b2.y, b2.z, b2.w};
            #pragma unroll
            for (int q = 0; q < 8; ++q)
                #pragma unroll
                for (int j = 0; j < 12; ++j)
                    acc[q][j] = fmaf(hq[q], bj[j], acc[q][j]);
        }

        // ---- phase 3: store bf16 (fold 1/sqrt(64)) ----
        int tbase = P - sbeg;
        #pragma unroll
        for (int q = 0; q < 8; ++q) {
            int el = g_e * 8 + q;
            if (el < m) {
                unsigned* dst = (unsigned*)(w + ((size_t)(tbase + el) * WNUM + g_j * 12));
                #pragma unroll
                for (int jj = 0; jj < 6; ++jj)
                    dst[jj] = bf16pack(acc[q][2 * jj] * INV_SQRT64,
                                       acc[q][2 * jj + 1] * INV_SQRT64);
            }
        }
        __syncthreads();
    }
}

// ---------------- kernel B: per-node tensor-product reduction (streaming) ----------------
__global__ __launch_bounds__(256) void k_tp(
    const float* __restrict__ f,
    const float* __restrict__ node_attr,
    const unsigned short* __restrict__ w,
    const float* __restrict__ ea_perm,
    const int* __restrict__ src_perm,
    const int* __restrict__ off,
    const float* __restrict__ W3,
    float* __restrict__ agg,
    float* __restrict__ trig,
    int n0, int n1)
{
    int lane = threadIdx.x & 63;
    int n = n0 + blockIdx.x * 4 + (threadIdx.x >> 6);
    if (n >= n1) return;
    int base = off[n0];
    int beg = off[n], end = off[n + 1];
    float w3a = W3[lane];
    float w3d = (lane >= 32) ? W3[lane + 32] : 0.f;
    float accA = 0.f, accB0 = 0.f, accB1 = 0.f, accB2 = 0.f;
    float accX0 = 0.f, accX1 = 0.f, accX2 = 0.f;
    int u = lane & 31;

    for (int p = beg; p < end; p += 4) {
        float W0[4], W1[4], W2[4], xs[4], xv0[4], xv1[4], xv2[4];
        float4 ea[4];
        #pragma unroll
        for (int q = 0; q < 4; ++q) {
            int idx = p + q;
            bool valid = idx < end;
            if (!valid) idx = end - 1;
            const unsigned short* wr = w + (size_t)(idx - base) * WNUM;
            W0[q] = bf2f(wr[lane]);
            W1[q] = bf2f(wr[64 + lane]);
            W2[q] = bf2f(wr[128 + lane]);
            float4 e4 = *(const float4*)(ea_perm + (size_t)idx * 4);
            if (!valid) { e4.x = 0.f; e4.y = 0.f; e4.z = 0.f; e4.w = 0.f; }
            ea[q] = e4;
            const float* fs = f + (size_t)src_perm[idx] * NODE_F;
            xs[q] = fs[lane];
            xv0[q] = fs[MUL0 + u * 3 + 0];
            xv1[q] = fs[MUL0 + u * 3 + 1];
            xv2[q] = fs[MUL0 + u * 3 + 2];
        }
        #pragma unroll
        for (int q = 0; q < 4; ++q) {
            accA = fmaf(W0[q] * xs[q], ea[q].x, accA);
            float bx = W1[q] * xs[q];
            accB0 = fmaf(bx, ea[q].y, accB0);
            accB1 = fmaf(bx, ea[q].z, accB1);
            accB2 = fmaf(bx, ea[q].w, accB2);
            if (lane < 32) {
                float cc = W2[q] * ea[q].x;
                accX0 = fmaf(cc, xv0[q], accX0);
                accX1 = fmaf(cc, xv1[q], accX1);
                accX2 = fmaf(cc, xv2[q], accX2);
            } else {
                float dv = xv0[q] * ea[q].y + xv1[q] * ea[q].z + xv2[q] * ea[q].w;
                accX0 = fmaf(W2[q] * INV_SQRT3, dv, accX0);
            }
        }
    }

    float part = accA * w3a;
    if (lane >= 32) part = fmaf(accX0, w3d, part);
    #pragma unroll
    for (int s = 32; s >= 1; s >>= 1) part += __shfl_xor(part, s);
    if (lane == 0) {
        float ang = 0.1f * INV_SQRT96 * INV_SQRT10 * node_attr[n] * part;
        trig[2 * n]     = cosf(ang);
        trig[2 * n + 1] = sinf(ang);
    }

    float* aggn = agg + (size_t)n * AGG_F;
    aggn[lane] = accA;
    aggn[96 + lane * 3 + 0] = accB0;
    aggn[96 + lane * 3 + 1] = accB1;
    aggn[96 + lane * 3 + 2] = accB2;
    if (lane < 32) {
        aggn[288 + lane * 3 + 0] = accX0;
        aggn[288 + lane * 3 + 1] = accX1;
        aggn[288 + lane * 3 + 2] = accX2;
    } else {
        aggn[64 + lane - 32] = accX0;
    }
}

// ---------------- kernel: output combine ----------------
__global__ void k_out(const float* __restrict__ node_input,
                      const float* __restrict__ node_attr,
                      const float* __restrict__ agg,
                      const float* __restrict__ trig,
                      const float* __restrict__ W_sc_s,
                      const float* __restrict__ W_sc_v,
                      const float* __restrict__ W2_s,
                      const float* __restrict__ W2_v,
                      float* __restrict__ out, int N)
{
    int t = blockIdx.x * blockDim.x + threadIdx.x;
    int n = t / NODE_F;
    int c = t % NODE_F;
    if (n >= N) return;
    const float* ag  = agg + (size_t)n * AGG_F;
    const float* row = node_input + (size_t)n * NODE_F;
    float attr = node_attr[n];
    float cs = trig[2 * n], sn = trig[2 * n + 1];

    float conv, sc;
    if (c < MUL0) {
        float acc = 0.f;
        #pragma unroll
        for (int j = 0; j < 96; ++j)
            acc = fmaf(ag[j], W2_s[j * MUL0 + c], acc);
        conv = acc * INV_SQRT10 * INV_SQRT96 * attr;
        float a2 = 0.f;
        #pragma unroll
        for (int u = 0; u < MUL0; ++u)
            a2 = fmaf(row[u], W_sc_s[u * MUL0 + c], a2);
        sc = a2 * INV_SQRT64 * attr;
    } else {
        int cc = c - MUL0;
        int v = cc / 3, d = cc % 3;
        float acc = 0.f;
        #pragma unroll
        for (int j = 0; j < 96; ++j)
            acc = fmaf(ag[96 + j * 3 + d], W2_v[j * MUL1 + v], acc);
        conv = acc * INV_SQRT10 * INV_SQRT96 * attr;
        float a2 = 0.f;
        #pragma unroll
        for (int u = 0; u < MUL1; ++u)
            a2 = fmaf(row[MUL0 + u * 3 + d], W_sc_v[u * MUL1 + v], a2);
        sc = a2 * INV_SQRT32 * attr;
    }
    out[(size_t)n * NODE_F + c] = cs * sc + sn * conv;
}

extern "C" void kernel_launch(void* const* d_in, const int* in_sizes, int n_in,
                              void* d_out, int out_size, void* d_ws, size_t ws_size,
                              hipStream_t stream)
{
    const float* node_input   = (const float*)d_in[0];
    const float* node_attr    = (const float*)d_in[1];
    const float* edge_attr    = (const float*)d_in[2];
    const float* edge_scalars = (const float*)d_in[3];
    const float* W_sc_s       = (const float*)d_in[4];
    const float* W_sc_v       = (const float*)d_in[5];
    const float* W1_s         = (const float*)d_in[6];
    const float* W1_v         = (const float*)d_in[7];
    const float* W2_s         = (const float*)d_in[8];
    const float* W2_v         = (const float*)d_in[9];
    const float* W3           = (const float*)d_in[10];
    const float* fcW1         = (const float*)d_in[11];
    const float* fcW2         = (const float*)d_in[12];
    const int*   edge_src     = (const int*)d_in[13];
    const int*   edge_dst     = (const int*)d_in[14];
    float* out = (float*)d_out;

    const int N = in_sizes[1];
    const int E = in_sizes[13];

    // ---- workspace layout (all 16B-aligned) ----
    char* p = (char*)d_ws;
    float* agg      = (float*)p;  p += (size_t)N * AGG_F * sizeof(float);
    float* trig     = (float*)p;  p += (size_t)N * 2 * sizeof(float);
    float* ea_perm  = (float*)p;  p += (size_t)E * 4 * sizeof(float);
    int*   deg      = (int*)p;    p += (size_t)N * sizeof(int);
    int*   cur      = (int*)p;    p += (size_t)N * sizeof(int);
    int*   csr      = (int*)p;    p += (size_t)E * sizeof(int);
    int*   src_perm = (int*)p;    p += (size_t)E * sizeof(int);
    int*   off      = (int*)p;    p += (size_t)(N + 1) * sizeof(int);
    p = (char*)(((size_t)p + 255) & ~(size_t)255);
    unsigned short* w = (unsigned short*)p;

    size_t used  = (size_t)(p - (char*)d_ws);
    size_t avail = (ws_size > used) ? (ws_size - used) : 0;
    size_t cap_edges = avail / (WNUM * sizeof(unsigned short));

    int nchunks = 1;
    if ((size_t)E > cap_edges) {
        nchunks = 2;
        while (nchunks < 64 &&
               ((size_t)(E / nchunks) * 5 / 4 + 256) > cap_edges)
            nchunks++;
    }

    float* f = out;   // f lives in d_out, overwritten by k_out at the end

    hipMemsetAsync(deg, 0, (size_t)N * sizeof(int), stream);

    int eb = (E + 255) / 256;
    k_count<<<eb, 256, 0, stream>>>(edge_dst, deg, E);
    k_scan<<<1, 1024, 0, stream>>>(deg, off, cur, N);
    k_scatter<<<eb, 256, 0, stream>>>(edge_dst, cur, csr, E);

    int nt = N * NODE_F;
    k_node_lin<<<(nt + 255) / 256, 256, 0, stream>>>(node_input, node_attr, W1_s, W1_v, f, N);

    int epc = E / nchunks + 1;
    int gridA = (epc / 128) * 3 / 2 + 8;
    if (gridA > 3200) gridA = 3200;

    for (int c = 0; c < nchunks; ++c) {
        int n0 = (int)((long long)N * c / nchunks);
        int n1 = (int)((long long)N * (c + 1) / nchunks);
        if (n1 <= n0) continue;
        k_mlp<<<gridA, 256, 0, stream>>>(edge_scalars, fcW1, fcW2, edge_attr,
                                         edge_src, csr, off, n0, n1,
                                         w, src_perm, ea_perm);
        k_tp<<<(n1 - n0 + 3) / 4, 256, 0, stream>>>(f, node_attr, w, ea_perm,
                                                    src_perm, off, W3,
                                                    agg, trig, n0, n1);
    }

    k_out<<<(nt + 255) / 256, 256, 0, stream>>>(node_input, node_attr, agg, trig,
                                                W_sc_s, W_sc_v, W2_s, W2_v, out, N);
}

// Round 4
// 510.883 us; speedup vs baseline: 3.6435x; 1.4987x over previous
//
#include <hip/hip_runtime.h>
#include <math.h>

#define MUL0 64
#define MUL1 32
#define RADF 8
#define HIDF 64
#define WNUM 192
#define NODE_F 160   // 64 + 96
#define AGG_F  384   // A(64) | D(32) | mv_d0(96) | mv_d1(96) | mv_d2(96)

#define INV_SQRT64 0.125f
#define INV_SQRT32 0.17677669529663687f
#define INV_SQRT8  0.35355339059327373f
#define INV_SQRT96 0.10206207261596575f
#define INV_SQRT10 0.31622776601683794f
#define INV_SQRT3  0.5773502691896258f

__device__ __forceinline__ float bf2f(unsigned short u) {
    return __uint_as_float((unsigned)u << 16);
}
__device__ __forceinline__ unsigned bf16pack(float a, float b) {
    unsigned ua = __float_as_uint(a);
    unsigned ub = __float_as_uint(b);
    ua = (ua + 0x7FFF + ((ua >> 16) & 1)) >> 16;
    ub = (ub + 0x7FFF + ((ub >> 16) & 1)) >> 16;
    return ua | (ub << 16);
}

// ---------------- kernel: f = _lin(s_in, v_in, W1_s, W1_v, attr) ----------------
__global__ void k_node_lin(const float* __restrict__ node_input,
                           const float* __restrict__ node_attr,
                           const float* __restrict__ W1_s,
                           const float* __restrict__ W1_v,
                           float* __restrict__ f, int N)
{
    int t = blockIdx.x * blockDim.x + threadIdx.x;
    int n = t / NODE_F;
    int c = t % NODE_F;
    if (n >= N) return;
    const float* row = node_input + (size_t)n * NODE_F;
    float attr = node_attr[n];
    float acc = 0.f;
    if (c < MUL0) {
        #pragma unroll
        for (int u = 0; u < MUL0; ++u)
            acc = fmaf(row[u], W1_s[u * MUL0 + c], acc);
        acc *= attr * INV_SQRT64;
    } else {
        int cc = c - MUL0;
        int v = cc / 3, d = cc % 3;
        #pragma unroll
        for (int u = 0; u < MUL1; ++u)
            acc = fmaf(row[MUL0 + u * 3 + d], W1_v[u * MUL1 + v], acc);
        acc *= attr * INV_SQRT32;
    }
    f[(size_t)n * NODE_F + c] = acc;
}

// ---------------- CSR build ----------------
__global__ void k_count(const int* __restrict__ edge_dst, int* deg, int E)
{
    int e = blockIdx.x * blockDim.x + threadIdx.x;
    if (e < E) atomicAdd(&deg[edge_dst[e]], 1);
}

__global__ __launch_bounds__(1024) void k_scan(const int* __restrict__ deg,
                                               int* __restrict__ off,
                                               int* __restrict__ cur, int N)
{
    __shared__ int swsum[16];
    __shared__ int swoff[16];
    __shared__ int sbase;
    __shared__ int stotal;
    int lane = threadIdx.x & 63, wid = threadIdx.x >> 6;
    if (threadIdx.x == 0) sbase = 0;
    __syncthreads();
    int ngroups = N >> 2;
    for (int base = 0; base < ngroups; base += 1024) {
        int g = base + threadIdx.x;
        int4 v = make_int4(0, 0, 0, 0);
        if (g < ngroups) v = ((const int4*)deg)[g];
        int s = v.x + v.y + v.z + v.w;
        int val = s;
        #pragma unroll
        for (int sh = 1; sh < 64; sh <<= 1) {
            int t = __shfl_up(val, sh);
            if (lane >= sh) val += t;
        }
        if (lane == 63) swsum[wid] = val;
        __syncthreads();
        if (threadIdx.x < 16) {
            int x = swsum[threadIdx.x];
            int xv = x;
            #pragma unroll
            for (int sh = 1; sh < 16; sh <<= 1) {
                int t = __shfl_up(xv, sh);
                if ((int)threadIdx.x >= sh) xv += t;
            }
            swoff[threadIdx.x] = xv - x;
            if (threadIdx.x == 15) stotal = xv;
        }
        __syncthreads();
        if (g < ngroups) {
            int b = sbase + swoff[wid] + (val - s);
            int4 o;
            o.x = b; o.y = b + v.x; o.z = o.y + v.y; o.w = o.z + v.z;
            ((int4*)off)[g] = o;
            ((int4*)cur)[g] = o;
        }
        __syncthreads();
        if (threadIdx.x == 0) sbase += stotal;
        __syncthreads();
    }
    if (threadIdx.x == 0) {
        int b = sbase;
        for (int i = (ngroups << 2); i < N; ++i) { off[i] = b; cur[i] = b; b += deg[i]; }
        off[N] = b;
    }
}

__global__ void k_scatter(const int* __restrict__ edge_dst,
                          int* cur, int* __restrict__ csr, int E)
{
    int e = blockIdx.x * blockDim.x + threadIdx.x;
    if (e < E) {
        int d = edge_dst[e];
        int pos = atomicAdd(&cur[d], 1);
        csr[pos] = e;
    }
}

// ---------------- kernel A: dense per-edge MLP (GEMM), CSR-ordered bf16 output ----------------
__global__ __launch_bounds__(256) void k_mlp(
    const float* __restrict__ edge_scalars,
    const float* __restrict__ fcW1,
    const float* __restrict__ fcW2,
    const float* __restrict__ edge_attr,
    const int* __restrict__ edge_src,
    const int* __restrict__ csr,
    const int* __restrict__ off,
    int n0, int n1,
    unsigned short* __restrict__ w,      // [chunk_edges][192] bf16
    int* __restrict__ src_perm,
    float* __restrict__ ea_perm)
{
    __shared__ float s_fcW2[HIDF * WNUM];   // 48 KB
    __shared__ float s_h[HIDF * 128];       // 32 KB
    for (int i = threadIdx.x; i < HIDF * WNUM; i += 256)
        s_fcW2[i] = fcW2[i];

    int lane = threadIdx.x & 63;
    float w1c[RADF];
    #pragma unroll
    for (int r = 0; r < RADF; ++r)
        w1c[r] = fcW1[r * HIDF + lane];

    int sbeg = off[n0], send = off[n1];
    int cnt = send - sbeg;
    int tiles = (cnt + 127) >> 7;
    int khalf = threadIdx.x >> 7;        // wave-uniform
    int i_loc = threadIdx.x & 127;
    int g_j = threadIdx.x & 15;
    int g_e = threadIdx.x >> 4;
    __syncthreads();

    for (int t = blockIdx.x; t < tiles; t += gridDim.x) {
        int P = sbeg + (t << 7);
        int m = min(128, send - P);

        // ---- phase 1: h tile ----
        {
            bool valid = i_loc < m;
            int pos = P + (valid ? i_loc : 0);
            int e = csr[pos];
            const float* es = edge_scalars + (size_t)e * RADF;
            float esr[RADF];
            #pragma unroll
            for (int r = 0; r < RADF; ++r) esr[r] = es[r];
            if (valid && khalf == 0) {
                src_perm[pos] = edge_src[e];
                float4 eav = *(const float4*)(edge_attr + (size_t)e * 4);
                *(float4*)(ea_perm + (size_t)pos * 4) = eav;
            }
            #pragma unroll
            for (int kk = 0; kk < 32; ++kk) {
                int k = khalf * 32 + kk;
                float acc = 0.f;
                #pragma unroll
                for (int r = 0; r < RADF; ++r) {
                    float c = __int_as_float(__builtin_amdgcn_readlane(__float_as_int(w1c[r]), k));
                    acc = fmaf(esr[r], c, acc);
                }
                acc *= INV_SQRT8;
                acc = acc / (1.f + __expf(-acc));
                s_h[k * 128 + i_loc] = valid ? acc : 0.f;
            }
        }
        __syncthreads();

        // ---- phase 2: w = h @ fcW2 (8 edges x 12 cols per thread) ----
        float acc[8][12];
        #pragma unroll
        for (int q = 0; q < 8; ++q)
            #pragma unroll
            for (int j = 0; j < 12; ++j) acc[q][j] = 0.f;

        const float* hbase = s_h + g_e * 8;
        const float* bbase = s_fcW2 + g_j * 12;
        #pragma unroll 2
        for (int k = 0; k < HIDF; ++k) {
            float4 h0 = *(const float4*)(hbase + k * 128);
            float4 h1 = *(const float4*)(hbase + k * 128 + 4);
            float4 b0 = *(const float4*)(bbase + k * WNUM);
            float4 b1 = *(const float4*)(bbase + k * WNUM + 4);
            float4 b2 = *(const float4*)(bbase + k * WNUM + 8);
            float hq[8]  = {h0.x, h0.y, h0.z, h0.w, h1.x, h1.y, h1.z, h1.w};
            float bj[12] = {b0.x, b0.y, b0.z, b0.w, b1.x, b1.y, b1.z, b1.w,
                            b2.x, b2.y, b2.z, b2.w};
            #pragma unroll
            for (int q = 0; q < 8; ++q)
                #pragma unroll
                for (int j = 0; j < 12; ++j)
                    acc[q][j] = fmaf(hq[q], bj[j], acc[q][j]);
        }

        // ---- phase 3: store bf16 (fold 1/sqrt(64)) ----
        int tbase = P - sbeg;
        #pragma unroll
        for (int q = 0; q < 8; ++q) {
            int el = g_e * 8 + q;
            if (el < m) {
                unsigned* dst = (unsigned*)(w + ((size_t)(tbase + el) * WNUM + g_j * 12));
                #pragma unroll
                for (int jj = 0; jj < 6; ++jj)
                    dst[jj] = bf16pack(acc[q][2 * jj] * INV_SQRT64,
                                       acc[q][2 * jj + 1] * INV_SQRT64);
            }
        }
        __syncthreads();
    }
}

// ---------------- kernel B: per-node tensor-product reduction (streaming) ----------------
__global__ __launch_bounds__(256) void k_tp(
    const float* __restrict__ f,
    const float* __restrict__ node_attr,
    const unsigned short* __restrict__ w,
    const float* __restrict__ ea_perm,
    const int* __restrict__ src_perm,
    const int* __restrict__ off,
    const float* __restrict__ W3,
    float* __restrict__ agg,
    float* __restrict__ trig,
    int n0, int n1)
{
    int lane = threadIdx.x & 63;
    int n = n0 + blockIdx.x * 4 + (threadIdx.x >> 6);
    if (n >= n1) return;
    int base = off[n0];
    int beg = off[n], end = off[n + 1];
    float w3a = W3[lane];
    float w3d = (lane >= 32) ? W3[lane + 32] : 0.f;
    float accA = 0.f, accB0 = 0.f, accB1 = 0.f, accB2 = 0.f;
    float accX0 = 0.f, accX1 = 0.f, accX2 = 0.f;
    int u = lane & 31;

    for (int p = beg; p < end; p += 4) {
        float W0[4], W1[4], W2[4], xs[4], xv0[4], xv1[4], xv2[4];
        float4 ea[4];
        #pragma unroll
        for (int q = 0; q < 4; ++q) {
            int idx = p + q;
            bool valid = idx < end;
            if (!valid) idx = end - 1;
            const unsigned short* wr = w + (size_t)(idx - base) * WNUM;
            W0[q] = bf2f(wr[lane]);
            W1[q] = bf2f(wr[64 + lane]);
            W2[q] = bf2f(wr[128 + lane]);
            float4 e4 = *(const float4*)(ea_perm + (size_t)idx * 4);
            if (!valid) { e4.x = 0.f; e4.y = 0.f; e4.z = 0.f; e4.w = 0.f; }
            ea[q] = e4;
            const float* fs = f + (size_t)src_perm[idx] * NODE_F;
            xs[q] = fs[lane];
            xv0[q] = fs[MUL0 + u * 3 + 0];
            xv1[q] = fs[MUL0 + u * 3 + 1];
            xv2[q] = fs[MUL0 + u * 3 + 2];
        }
        #pragma unroll
        for (int q = 0; q < 4; ++q) {
            accA = fmaf(W0[q] * xs[q], ea[q].x, accA);
            float bx = W1[q] * xs[q];
            accB0 = fmaf(bx, ea[q].y, accB0);
            accB1 = fmaf(bx, ea[q].z, accB1);
            accB2 = fmaf(bx, ea[q].w, accB2);
            if (lane < 32) {
                float cc = W2[q] * ea[q].x;
                accX0 = fmaf(cc, xv0[q], accX0);
                accX1 = fmaf(cc, xv1[q], accX1);
                accX2 = fmaf(cc, xv2[q], accX2);
            } else {
                float dv = xv0[q] * ea[q].y + xv1[q] * ea[q].z + xv2[q] * ea[q].w;
                accX0 = fmaf(W2[q] * INV_SQRT3, dv, accX0);
            }
        }
    }

    float part = accA * w3a;
    if (lane >= 32) part = fmaf(accX0, w3d, part);
    #pragma unroll
    for (int s = 32; s >= 1; s >>= 1) part += __shfl_xor(part, s);
    if (lane == 0) {
        float ang = 0.1f * INV_SQRT96 * INV_SQRT10 * node_attr[n] * part;
        trig[2 * n]     = cosf(ang);
        trig[2 * n + 1] = sinf(ang);
    }

    // d-major layout: [A(64) | D(32) | mv_d0(96) | mv_d1(96) | mv_d2(96)]
    // mv_d rows 0..63 = B (accB_d), rows 64..95 = C (accX_d, lanes<32)
    float* aggn = agg + (size_t)n * AGG_F;
    aggn[lane] = accA;
    aggn[96  + lane] = accB0;
    aggn[192 + lane] = accB1;
    aggn[288 + lane] = accB2;
    if (lane < 32) {
        aggn[160 + lane] = accX0;
        aggn[256 + lane] = accX1;
        aggn[352 + lane] = accX2;
    } else {
        aggn[64 + lane - 32] = accX0;
    }
}

// ---------------- kernel: output combine (LDS-tiled mini-GEMM) ----------------
#define ONT 16   // nodes per block
__global__ __launch_bounds__(320) void k_out(
    const float* __restrict__ node_input,
    const float* __restrict__ node_attr,
    const float* __restrict__ agg,
    const float* __restrict__ trig,
    const float* __restrict__ W_sc_s,
    const float* __restrict__ W_sc_v,
    const float* __restrict__ W2_s,
    const float* __restrict__ W2_v,
    float* __restrict__ out, int N)
{
    __shared__ float s_ag [ONT * AGG_F];      // 24.6 KB (prescaled)
    __shared__ float s_ins[ONT * 64];         // 4 KB
    __shared__ float s_inv[ONT * 3 * 32];     // 6 KB (d-major)
    __shared__ float s_out[ONT * NODE_F];     // 10.2 KB
    __shared__ float s_cs[ONT], s_sn[ONT], s_attr[ONT];

    int tid = threadIdx.x;
    int n0 = blockIdx.x * ONT;
    int nv = min(ONT, N - n0);
    const float pre = INV_SQRT10 * INV_SQRT96;

    // ---- stage ----
    {
        const float4* gsrc = (const float4*)(agg + (size_t)n0 * AGG_F);
        float4* ldst = (float4*)s_ag;
        int cnt4 = nv * (AGG_F / 4);
        for (int i = tid; i < ONT * (AGG_F / 4); i += 320) {
            float4 v = (i < cnt4) ? gsrc[i] : make_float4(0, 0, 0, 0);
            v.x *= pre; v.y *= pre; v.z *= pre; v.w *= pre;
            ldst[i] = v;
        }
        const float* isrc = node_input + (size_t)n0 * NODE_F;
        int icnt = nv * NODE_F;
        for (int i = tid; i < ONT * NODE_F; i += 320) {
            float val = (i < icnt) ? isrc[i] : 0.f;
            int nt = i / NODE_F, c = i % NODE_F;
            if (c < MUL0) s_ins[nt * 64 + c] = val;
            else {
                int cc = c - MUL0;
                s_inv[(nt * 3 + (cc % 3)) * 32 + (cc / 3)] = val;
            }
        }
        if (tid < ONT) {
            bool ok = tid < nv;
            s_cs[tid]   = ok ? trig[2 * (n0 + tid)]     : 0.f;
            s_sn[tid]   = ok ? trig[2 * (n0 + tid) + 1] : 0.f;
            s_attr[tid] = ok ? node_attr[n0 + tid]      : 0.f;
        }
    }
    __syncthreads();

    int wid = tid >> 6;
    int lane = tid & 63;

    if (wid < 2) {
        // ---- scalar part: lane = channel, 8 nodes ----
        int qbase = wid * 8;
        float acc[8] = {0,0,0,0,0,0,0,0};
        float scc[8] = {0,0,0,0,0,0,0,0};
        for (int j4 = 0; j4 < 96; j4 += 4) {
            float w0 = W2_s[(j4 + 0) * MUL0 + lane];
            float w1 = W2_s[(j4 + 1) * MUL0 + lane];
            float w2 = W2_s[(j4 + 2) * MUL0 + lane];
            float w3 = W2_s[(j4 + 3) * MUL0 + lane];
            #pragma unroll
            for (int q = 0; q < 8; ++q) {
                float4 a = *(const float4*)&s_ag[(qbase + q) * AGG_F + j4];
                acc[q] = fmaf(a.x, w0, fmaf(a.y, w1, fmaf(a.z, w2, fmaf(a.w, w3, acc[q]))));
            }
        }
        for (int u4 = 0; u4 < 64; u4 += 4) {
            float w0 = W_sc_s[(u4 + 0) * MUL0 + lane];
            float w1 = W_sc_s[(u4 + 1) * MUL0 + lane];
            float w2 = W_sc_s[(u4 + 2) * MUL0 + lane];
            float w3 = W_sc_s[(u4 + 3) * MUL0 + lane];
            #pragma unroll
            for (int q = 0; q < 8; ++q) {
                float4 b = *(const float4*)&s_ins[(qbase + q) * 64 + u4];
                scc[q] = fmaf(b.x, w0, fmaf(b.y, w1, fmaf(b.z, w2, fmaf(b.w, w3, scc[q]))));
            }
        }
        #pragma unroll
        for (int q = 0; q < 8; ++q) {
            int nt = qbase + q;
            s_out[nt * NODE_F + lane] =
                s_attr[nt] * (s_cs[nt] * (INV_SQRT64 * scc[q]) + s_sn[nt] * acc[q]);
        }
    } else {
        // ---- vector part: d = wid-2; lanes = 2 nodes x 32 v-channels ----
        int d = wid - 2;
        int v = lane & 31;
        int np = lane >> 5;
        float acc[8] = {0,0,0,0,0,0,0,0};
        float scc[8] = {0,0,0,0,0,0,0,0};
        int agoff = 96 + d * 96;
        for (int j4 = 0; j4 < 96; j4 += 4) {
            float w0 = W2_v[(j4 + 0) * MUL1 + v];
            float w1 = W2_v[(j4 + 1) * MUL1 + v];
            float w2 = W2_v[(j4 + 2) * MUL1 + v];
            float w3 = W2_v[(j4 + 3) * MUL1 + v];
            #pragma unroll
            for (int it = 0; it < 8; ++it) {
                int nt = it * 2 + np;
                float4 a = *(const float4*)&s_ag[nt * AGG_F + agoff + j4];
                acc[it] = fmaf(a.x, w0, fmaf(a.y, w1, fmaf(a.z, w2, fmaf(a.w, w3, acc[it]))));
            }
        }
        for (int u4 = 0; u4 < 32; u4 += 4) {
            float w0 = W_sc_v[(u4 + 0) * MUL1 + v];
            float w1 = W_sc_v[(u4 + 1) * MUL1 + v];
            float w2 = W_sc_v[(u4 + 2) * MUL1 + v];
            float w3 = W_sc_v[(u4 + 3) * MUL1 + v];
            #pragma unroll
            for (int it = 0; it < 8; ++it) {
                int nt = it * 2 + np;
                float4 b = *(const float4*)&s_inv[(nt * 3 + d) * 32 + u4];
                scc[it] = fmaf(b.x, w0, fmaf(b.y, w1, fmaf(b.z, w2, fmaf(b.w, w3, scc[it]))));
            }
        }
        #pragma unroll
        for (int it = 0; it < 8; ++it) {
            int nt = it * 2 + np;
            s_out[nt * NODE_F + MUL0 + v * 3 + d] =
                s_attr[nt] * (s_cs[nt] * (INV_SQRT32 * scc[it]) + s_sn[nt] * acc[it]);
        }
    }
    __syncthreads();

    // ---- coalesced store ----
    {
        float4* gdst = (float4*)(out + (size_t)n0 * NODE_F);
        const float4* lsrc = (const float4*)s_out;
        int cnt4 = nv * (NODE_F / 4);
        for (int i = tid; i < cnt4; i += 320)
            gdst[i] = lsrc[i];
    }
}

extern "C" void kernel_launch(void* const* d_in, const int* in_sizes, int n_in,
                              void* d_out, int out_size, void* d_ws, size_t ws_size,
                              hipStream_t stream)
{
    const float* node_input   = (const float*)d_in[0];
    const float* node_attr    = (const float*)d_in[1];
    const float* edge_attr    = (const float*)d_in[2];
    const float* edge_scalars = (const float*)d_in[3];
    const float* W_sc_s       = (const float*)d_in[4];
    const float* W_sc_v       = (const float*)d_in[5];
    const float* W1_s         = (const float*)d_in[6];
    const float* W1_v         = (const float*)d_in[7];
    const float* W2_s         = (const float*)d_in[8];
    const float* W2_v         = (const float*)d_in[9];
    const float* W3           = (const float*)d_in[10];
    const float* fcW1         = (const float*)d_in[11];
    const float* fcW2         = (const float*)d_in[12];
    const int*   edge_src     = (const int*)d_in[13];
    const int*   edge_dst     = (const int*)d_in[14];
    float* out = (float*)d_out;

    const int N = in_sizes[1];
    const int E = in_sizes[13];

    // ---- workspace layout (all 16B-aligned) ----
    char* p = (char*)d_ws;
    float* agg      = (float*)p;  p += (size_t)N * AGG_F * sizeof(float);
    float* trig     = (float*)p;  p += (size_t)N * 2 * sizeof(float);
    float* ea_perm  = (float*)p;  p += (size_t)E * 4 * sizeof(float);
    int*   deg      = (int*)p;    p += (size_t)N * sizeof(int);
    int*   cur      = (int*)p;    p += (size_t)N * sizeof(int);
    int*   csr      = (int*)p;    p += (size_t)E * sizeof(int);
    int*   src_perm = (int*)p;    p += (size_t)E * sizeof(int);
    int*   off      = (int*)p;    p += (size_t)(N + 1) * sizeof(int);
    p = (char*)(((size_t)p + 255) & ~(size_t)255);
    unsigned short* w = (unsigned short*)p;

    size_t used  = (size_t)(p - (char*)d_ws);
    size_t avail = (ws_size > used) ? (ws_size - used) : 0;
    size_t cap_edges = avail / (WNUM * sizeof(unsigned short));

    int nchunks = 1;
    if ((size_t)E > cap_edges) {
        nchunks = 2;
        while (nchunks < 64 &&
               ((size_t)(E / nchunks) * 5 / 4 + 256) > cap_edges)
            nchunks++;
    }

    float* f = out;   // f lives in d_out, overwritten by k_out at the end

    hipMemsetAsync(deg, 0, (size_t)N * sizeof(int), stream);

    int eb = (E + 255) / 256;
    k_count<<<eb, 256, 0, stream>>>(edge_dst, deg, E);
    k_scan<<<1, 1024, 0, stream>>>(deg, off, cur, N);
    k_scatter<<<eb, 256, 0, stream>>>(edge_dst, cur, csr, E);

    int nt = N * NODE_F;
    k_node_lin<<<(nt + 255) / 256, 256, 0, stream>>>(node_input, node_attr, W1_s, W1_v, f, N);

    int epc = E / nchunks + 1;
    int gridA = (epc / 128) * 3 / 2 + 8;
    if (gridA > 3200) gridA = 3200;

    for (int c = 0; c < nchunks; ++c) {
        int n0 = (int)((long long)N * c / nchunks);
        int n1 = (int)((long long)N * (c + 1) / nchunks);
        if (n1 <= n0) continue;
        k_mlp<<<gridA, 256, 0, stream>>>(edge_scalars, fcW1, fcW2, edge_attr,
                                         edge_src, csr, off, n0, n1,
                                         w, src_perm, ea_perm);
        k_tp<<<(n1 - n0 + 3) / 4, 256, 0, stream>>>(f, node_attr, w, ea_perm,
                                                    src_perm, off, W3,
                                                    agg, trig, n0, n1);
    }

    k_out<<<(N + ONT - 1) / ONT, 320, 0, stream>>>(node_input, node_attr, agg, trig,
                                                   W_sc_s, W_sc_v, W2_s, W2_v, out, N);
}

// Round 6
// 464.000 us; speedup vs baseline: 4.0116x; 1.1010x over previous
//
#include <hip/hip_runtime.h>
#include <math.h>

#define MUL0 64
#define MUL1 32
#define RADF 8
#define HIDF 64
#define WNUM 192
#define NODE_F 160   // 64 + 96
#define AGG_F  384   // A(64) | D(32) | mv_d0(96) | mv_d1(96) | mv_d2(96)

#define INV_SQRT64 0.125f
#define INV_SQRT32 0.17677669529663687f
#define INV_SQRT8  0.35355339059327373f
#define INV_SQRT96 0.10206207261596575f
#define INV_SQRT10 0.31622776601683794f
#define INV_SQRT3  0.5773502691896258f

typedef __attribute__((ext_vector_type(8))) short bf16x8;
typedef __attribute__((ext_vector_type(4))) float f32x4;

__device__ __forceinline__ float bf2f(unsigned short u) {
    return __uint_as_float((unsigned)u << 16);
}
__device__ __forceinline__ unsigned short f2bfu(float x) {
    unsigned ua = __float_as_uint(x);
    return (unsigned short)((ua + 0x7FFF + ((ua >> 16) & 1)) >> 16);
}
__device__ __forceinline__ unsigned bf16pack(float a, float b) {
    unsigned ua = __float_as_uint(a);
    unsigned ub = __float_as_uint(b);
    ua = (ua + 0x7FFF + ((ua >> 16) & 1)) >> 16;
    ub = (ub + 0x7FFF + ((ub >> 16) & 1)) >> 16;
    return ua | (ub << 16);
}

// ---------------- kernel: f = _lin(s_in, v_in, W1_s, W1_v, attr) ----------------
__global__ void k_node_lin(const float* __restrict__ node_input,
                           const float* __restrict__ node_attr,
                           const float* __restrict__ W1_s,
                           const float* __restrict__ W1_v,
                           float* __restrict__ f, int N)
{
    int t = blockIdx.x * blockDim.x + threadIdx.x;
    int n = t / NODE_F;
    int c = t % NODE_F;
    if (n >= N) return;
    const float* row = node_input + (size_t)n * NODE_F;
    float attr = node_attr[n];
    float acc = 0.f;
    if (c < MUL0) {
        #pragma unroll
        for (int u = 0; u < MUL0; ++u)
            acc = fmaf(row[u], W1_s[u * MUL0 + c], acc);
        acc *= attr * INV_SQRT64;
    } else {
        int cc = c - MUL0;
        int v = cc / 3, d = cc % 3;
        #pragma unroll
        for (int u = 0; u < MUL1; ++u)
            acc = fmaf(row[MUL0 + u * 3 + d], W1_v[u * MUL1 + v], acc);
        acc *= attr * INV_SQRT32;
    }
    f[(size_t)n * NODE_F + c] = acc;
}

// ---------------- CSR build ----------------
__global__ void k_count(const int* __restrict__ edge_dst, int* deg, int E)
{
    int e = blockIdx.x * blockDim.x + threadIdx.x;
    if (e < E) atomicAdd(&deg[edge_dst[e]], 1);
}

__global__ __launch_bounds__(1024) void k_scan(const int* __restrict__ deg,
                                               int* __restrict__ off,
                                               int* __restrict__ cur, int N)
{
    __shared__ int swsum[16];
    __shared__ int swoff[16];
    __shared__ int sbase;
    __shared__ int stotal;
    int lane = threadIdx.x & 63, wid = threadIdx.x >> 6;
    if (threadIdx.x == 0) sbase = 0;
    __syncthreads();
    int ngroups = N >> 2;
    for (int base = 0; base < ngroups; base += 1024) {
        int g = base + threadIdx.x;
        int4 v = make_int4(0, 0, 0, 0);
        if (g < ngroups) v = ((const int4*)deg)[g];
        int s = v.x + v.y + v.z + v.w;
        int val = s;
        #pragma unroll
        for (int sh = 1; sh < 64; sh <<= 1) {
            int t = __shfl_up(val, sh);
            if (lane >= sh) val += t;
        }
        if (lane == 63) swsum[wid] = val;
        __syncthreads();
        if (threadIdx.x < 16) {
            int x = swsum[threadIdx.x];
            int xv = x;
            #pragma unroll
            for (int sh = 1; sh < 16; sh <<= 1) {
                int t = __shfl_up(xv, sh);
                if ((int)threadIdx.x >= sh) xv += t;
            }
            swoff[threadIdx.x] = xv - x;
            if (threadIdx.x == 15) stotal = xv;
        }
        __syncthreads();
        if (g < ngroups) {
            int b = sbase + swoff[wid] + (val - s);
            int4 o;
            o.x = b; o.y = b + v.x; o.z = o.y + v.y; o.w = o.z + v.z;
            ((int4*)off)[g] = o;
            ((int4*)cur)[g] = o;
        }
        __syncthreads();
        if (threadIdx.x == 0) sbase += stotal;
        __syncthreads();
    }
    if (threadIdx.x == 0) {
        int b = sbase;
        for (int i = (ngroups << 2); i < N; ++i) { off[i] = b; cur[i] = b; b += deg[i]; }
        off[N] = b;
    }
}

__global__ void k_scatter(const int* __restrict__ edge_dst,
                          int* cur, int* __restrict__ csr, int E)
{
    int e = blockIdx.x * blockDim.x + threadIdx.x;
    if (e < E) {
        int d = edge_dst[e];
        int pos = atomicAdd(&cur[d], 1);
        csr[pos] = e;
    }
}

// ---------------- fused edge kernel: MLP (MFMA) + TP + atomic aggregate ----------------
__global__ __launch_bounds__(256, 2) void k_edge_fused(
    const float* __restrict__ f,
    const float* __restrict__ edge_scalars,
    const float* __restrict__ edge_attr,
    const float* __restrict__ fcW1,
    const float* __restrict__ fcW2,
    const int* __restrict__ edge_src,
    const int* __restrict__ edge_dst,
    const int* __restrict__ csr,
    float* agg, int E)
{
    // fcW2 transposed, bf16, k-oct-major: s_w2t[oct][col][8k]
    __shared__ unsigned short s_w2t[8 * 192 * 8];   // 24576 B
    // h bf16, k-oct-major: s_h[oct][edge][8k]
    __shared__ unsigned short s_h[8 * 64 * 8];      // 8192 B
    // per-edge weights w, bf16, stride 216 (bank spread)
    __shared__ unsigned short s_w[64 * 216];        // 27648 B
    __shared__ float s_fcW1[8 * 64];                // 2048 B
    __shared__ int s_eid[64], s_src[64], s_dst[64];
    __shared__ float4 s_ea[64];

    int tid  = threadIdx.x;
    int lane = tid & 63;
    int wv   = tid >> 6;
    int l15  = lane & 15, lh = lane >> 4;
    int u    = lane & 31;

    // ---- once per block: stage fcW2^T (bf16) and fcW1 ----
    for (int task = tid; task < 1536; task += 256) {
        int col = task % 192, oct = task / 192;
        unsigned pk0, pk1, pk2, pk3;
        {
            const float* wp = fcW2 + (size_t)(oct * 8) * WNUM + col;
            pk0 = bf16pack(wp[0 * WNUM], wp[1 * WNUM]);
            pk1 = bf16pack(wp[2 * WNUM], wp[3 * WNUM]);
            pk2 = bf16pack(wp[4 * WNUM], wp[5 * WNUM]);
            pk3 = bf16pack(wp[6 * WNUM], wp[7 * WNUM]);
        }
        *(uint4*)&s_w2t[oct * 1536 + col * 8] = make_uint4(pk0, pk1, pk2, pk3);
    }
    for (int i = tid; i < 512; i += 256)       // FIX: stage ALL of fcW1 (was tid<512 with 256 threads)
        s_fcW1[i] = fcW1[i];
    __syncthreads();

    int tiles = (E + 63) >> 6;
    for (int t = blockIdx.x; t < tiles; t += gridDim.x) {
        int P = t << 6;
        int m = min(64, E - P);

        // ---- stage A: edge metadata ----
        if (tid < 64) {
            int e = (tid < m) ? csr[P + tid] : 0;
            s_eid[tid] = e;
            s_src[tid] = edge_src[e];
            s_dst[tid] = edge_dst[e];
            s_ea[tid]  = *(const float4*)(edge_attr + (size_t)e * 4);
        }
        __syncthreads();

        // ---- phase 1: h = silu(es @ fcW1 / sqrt(8)) -> bf16 LDS ----
        #pragma unroll
        for (int p = 0; p < 2; ++p) {
            int task = tid + (p << 8);
            int edge = task & 63, oct = task >> 6;
            int eid = s_eid[edge];
            const float4* esp = (const float4*)(edge_scalars + (size_t)eid * RADF);
            float4 e0 = esp[0], e1 = esp[1];
            float es[8] = {e0.x, e0.y, e0.z, e0.w, e1.x, e1.y, e1.z, e1.w};
            unsigned pk[4];
            #pragma unroll
            for (int jp = 0; jp < 4; ++jp) {
                float hv2[2];
                #pragma unroll
                for (int c = 0; c < 2; ++c) {
                    int kk = oct * 8 + 2 * jp + c;
                    float a = 0.f;
                    #pragma unroll
                    for (int r = 0; r < 8; ++r)
                        a = fmaf(es[r], s_fcW1[r * 64 + kk], a);
                    a *= INV_SQRT8;
                    hv2[c] = a / (1.f + __expf(-a));
                }
                pk[jp] = bf16pack(hv2[0], hv2[1]);
            }
            *(uint4*)&s_h[oct * 512 + edge * 8] = make_uint4(pk[0], pk[1], pk[2], pk[3]);
        }
        __syncthreads();

        // ---- phase 2: w = h @ fcW2 / sqrt(64) via MFMA ----
        {
            int rb = wv;  // wave owns 16-edge row block
            bf16x8 a0 = *(const bf16x8*)&s_h[ lh      * 512 + (rb * 16 + l15) * 8];
            bf16x8 a1 = *(const bf16x8*)&s_h[(4 + lh) * 512 + (rb * 16 + l15) * 8];
            #pragma unroll
            for (int cb = 0; cb < 12; ++cb) {
                bf16x8 b0 = *(const bf16x8*)&s_w2t[ lh      * 1536 + (cb * 16 + l15) * 8];
                bf16x8 b1 = *(const bf16x8*)&s_w2t[(4 + lh) * 1536 + (cb * 16 + l15) * 8];
                f32x4 acc = {0.f, 0.f, 0.f, 0.f};
                acc = __builtin_amdgcn_mfma_f32_16x16x32_bf16(a0, b0, acc, 0, 0, 0);
                acc = __builtin_amdgcn_mfma_f32_16x16x32_bf16(a1, b1, acc, 0, 0, 0);
                #pragma unroll
                for (int r = 0; r < 4; ++r) {
                    int erow = rb * 16 + lh * 4 + r;
                    s_w[erow * 216 + cb * 16 + l15] = f2bfu(acc[r] * INV_SQRT64);
                }
            }
        }
        __syncthreads();

        // ---- phase 3: tensor product + dst-segmented atomic reduction ----
        {
            int i0 = wv * 16, i1 = min(i0 + 16, m);
            if (i0 < i1) {
                float accA = 0.f, accB0 = 0.f, accB1 = 0.f, accB2 = 0.f;
                float accX0 = 0.f, accX1 = 0.f, accX2 = 0.f;
                int cur = s_dst[i0];

                // prefetch f row for i0
                const float* fs_n = f + (size_t)s_src[i0] * NODE_F;
                float xs_n  = fs_n[lane];
                float xv0_n = fs_n[MUL0 + u * 3 + 0];
                float xv1_n = fs_n[MUL0 + u * 3 + 1];
                float xv2_n = fs_n[MUL0 + u * 3 + 2];

                for (int i = i0; i < i1; ++i) {
                    int d = s_dst[i];
                    if (d != cur) {
                        float* an = agg + (size_t)cur * AGG_F;
                        atomicAdd(&an[lane], accA);
                        atomicAdd(&an[96  + lane], accB0);
                        atomicAdd(&an[192 + lane], accB1);
                        atomicAdd(&an[288 + lane], accB2);
                        if (lane < 32) {
                            atomicAdd(&an[160 + u], accX0);
                            atomicAdd(&an[256 + u], accX1);
                            atomicAdd(&an[352 + u], accX2);
                        } else {
                            atomicAdd(&an[64 + u], accX0);
                        }
                        accA = accB0 = accB1 = accB2 = 0.f;
                        accX0 = accX1 = accX2 = 0.f;
                        cur = d;
                    }
                    float xs = xs_n, xv0 = xv0_n, xv1 = xv1_n, xv2 = xv2_n;
                    if (i + 1 < i1) {
                        const float* fsp = f + (size_t)s_src[i + 1] * NODE_F;
                        xs_n  = fsp[lane];
                        xv0_n = fsp[MUL0 + u * 3 + 0];
                        xv1_n = fsp[MUL0 + u * 3 + 1];
                        xv2_n = fsp[MUL0 + u * 3 + 2];
                    }
                    float W0 = bf2f(s_w[i * 216 + lane]);
                    float W1 = bf2f(s_w[i * 216 + 64 + lane]);
                    float W2 = bf2f(s_w[i * 216 + 128 + lane]);
                    float4 ea = s_ea[i];
                    accA = fmaf(W0 * xs, ea.x, accA);
                    float bx = W1 * xs;
                    accB0 = fmaf(bx, ea.y, accB0);
                    accB1 = fmaf(bx, ea.z, accB1);
                    accB2 = fmaf(bx, ea.w, accB2);
                    if (lane < 32) {
                        float cc = W2 * ea.x;
                        accX0 = fmaf(cc, xv0, accX0);
                        accX1 = fmaf(cc, xv1, accX1);
                        accX2 = fmaf(cc, xv2, accX2);
                    } else {
                        float dv = xv0 * ea.y + xv1 * ea.z + xv2 * ea.w;
                        accX0 = fmaf(W2 * INV_SQRT3, dv, accX0);
                    }
                }
                // final flush
                {
                    float* an = agg + (size_t)cur * AGG_F;
                    atomicAdd(&an[lane], accA);
                    atomicAdd(&an[96  + lane], accB0);
                    atomicAdd(&an[192 + lane], accB1);
                    atomicAdd(&an[288 + lane], accB2);
                    if (lane < 32) {
                        atomicAdd(&an[160 + u], accX0);
                        atomicAdd(&an[256 + u], accX1);
                        atomicAdd(&an[352 + u], accX2);
                    } else {
                        atomicAdd(&an[64 + u], accX0);
                    }
                }
            }
        }
        __syncthreads();
    }
}

// ---------------- kernel: output combine (LDS-tiled mini-GEMM + fused angle) ----------------
#define ONT 16   // nodes per block
__global__ __launch_bounds__(320) void k_out(
    const float* __restrict__ node_input,
    const float* __restrict__ node_attr,
    const float* __restrict__ agg,
    const float* __restrict__ W_sc_s,
    const float* __restrict__ W_sc_v,
    const float* __restrict__ W2_s,
    const float* __restrict__ W2_v,
    const float* __restrict__ W3,
    float* __restrict__ out, int N)
{
    __shared__ float s_ag [ONT * AGG_F];      // 24.6 KB (prescaled)
    __shared__ float s_ins[ONT * 64];         // 4 KB
    __shared__ float s_inv[ONT * 3 * 32];     // 6 KB (d-major)
    __shared__ float s_out[ONT * NODE_F];     // 10.2 KB
    __shared__ float s_cs[ONT], s_sn[ONT], s_attr[ONT];

    int tid = threadIdx.x;
    int n0 = blockIdx.x * ONT;
    int nv = min(ONT, N - n0);
    const float pre = INV_SQRT10 * INV_SQRT96;

    // ---- stage ----
    {
        const float4* gsrc = (const float4*)(agg + (size_t)n0 * AGG_F);
        float4* ldst = (float4*)s_ag;
        int cnt4 = nv * (AGG_F / 4);
        for (int i = tid; i < ONT * (AGG_F / 4); i += 320) {
            float4 v = (i < cnt4) ? gsrc[i] : make_float4(0, 0, 0, 0);
            v.x *= pre; v.y *= pre; v.z *= pre; v.w *= pre;
            ldst[i] = v;
        }
        const float* isrc = node_input + (size_t)n0 * NODE_F;
        int icnt = nv * NODE_F;
        for (int i = tid; i < ONT * NODE_F; i += 320) {
            float val = (i < icnt) ? isrc[i] : 0.f;
            int nt = i / NODE_F, c = i % NODE_F;
            if (c < MUL0) s_ins[nt * 64 + c] = val;
            else {
                int cc = c - MUL0;
                s_inv[(nt * 3 + (cc % 3)) * 32 + (cc / 3)] = val;
            }
        }
        if (tid < ONT) {
            s_attr[tid] = (tid < nv) ? node_attr[n0 + tid] : 0.f;
        }
    }
    __syncthreads();

    // ---- angle: per-node dot(ms, W3) over prescaled s_ag[0:96] ----
    {
        int g = tid >> 5;        // half-wave group 0..9
        int hl = tid & 31;
        #pragma unroll
        for (int pass = 0; pass < 2; ++pass) {
            int nt = pass * 10 + g;
            if (nt < ONT) {
                const float* ag = s_ag + nt * AGG_F;
                float pa = ag[hl] * W3[hl]
                         + ag[32 + hl] * W3[32 + hl]
                         + ag[64 + hl] * W3[64 + hl];
                #pragma unroll
                for (int s = 16; s >= 1; s >>= 1)
                    pa += __shfl_xor(pa, s);
                if (hl == 0) {
                    float ang = 0.1f * s_attr[nt] * pa;
                    s_cs[nt] = cosf(ang);
                    s_sn[nt] = sinf(ang);
                }
            }
        }
    }
    __syncthreads();

    int wid = tid >> 6;
    int lane = tid & 63;

    if (wid < 2) {
        // ---- scalar part: lane = channel, 8 nodes ----
        int qbase = wid * 8;
        float acc[8] = {0,0,0,0,0,0,0,0};
        float scc[8] = {0,0,0,0,0,0,0,0};
        for (int j4 = 0; j4 < 96; j4 += 4) {
            float w0 = W2_s[(j4 + 0) * MUL0 + lane];
            float w1 = W2_s[(j4 + 1) * MUL0 + lane];
            float w2 = W2_s[(j4 + 2) * MUL0 + lane];
            float w3 = W2_s[(j4 + 3) * MUL0 + lane];
            #pragma unroll
            for (int q = 0; q < 8; ++q) {
                float4 a = *(const float4*)&s_ag[(qbase + q) * AGG_F + j4];
                acc[q] = fmaf(a.x, w0, fmaf(a.y, w1, fmaf(a.z, w2, fmaf(a.w, w3, acc[q]))));
            }
        }
        for (int u4 = 0; u4 < 64; u4 += 4) {
            float w0 = W_sc_s[(u4 + 0) * MUL0 + lane];
            float w1 = W_sc_s[(u4 + 1) * MUL0 + lane];
            float w2 = W_sc_s[(u4 + 2) * MUL0 + lane];
            float w3 = W_sc_s[(u4 + 3) * MUL0 + lane];
            #pragma unroll
            for (int q = 0; q < 8; ++q) {
                float4 b = *(const float4*)&s_ins[(qbase + q) * 64 + u4];
                scc[q] = fmaf(b.x, w0, fmaf(b.y, w1, fmaf(b.z, w2, fmaf(b.w, w3, scc[q]))));
            }
        }
        #pragma unroll
        for (int q = 0; q < 8; ++q) {
            int nt = qbase + q;
            s_out[nt * NODE_F + lane] =
                s_attr[nt] * (s_cs[nt] * (INV_SQRT64 * scc[q]) + s_sn[nt] * acc[q]);
        }
    } else {
        // ---- vector part: d = wid-2; lanes = 2 nodes x 32 v-channels ----
        int d = wid - 2;
        int v = lane & 31;
        int np = lane >> 5;
        float acc[8] = {0,0,0,0,0,0,0,0};
        float scc[8] = {0,0,0,0,0,0,0,0};
        int agoff = 96 + d * 96;
        for (int j4 = 0; j4 < 96; j4 += 4) {
            float w0 = W2_v[(j4 + 0) * MUL1 + v];
            float w1 = W2_v[(j4 + 1) * MUL1 + v];
            float w2 = W2_v[(j4 + 2) * MUL1 + v];
            float w3 = W2_v[(j4 + 3) * MUL1 + v];
            #pragma unroll
            for (int it = 0; it < 8; ++it) {
                int nt = it * 2 + np;
                float4 a = *(const float4*)&s_ag[nt * AGG_F + agoff + j4];
                acc[it] = fmaf(a.x, w0, fmaf(a.y, w1, fmaf(a.z, w2, fmaf(a.w, w3, acc[it]))));
            }
        }
        for (int u4 = 0; u4 < 32; u4 += 4) {
            float w0 = W_sc_v[(u4 + 0) * MUL1 + v];
            float w1 = W_sc_v[(u4 + 1) * MUL1 + v];
            float w2 = W_sc_v[(u4 + 2) * MUL1 + v];
            float w3 = W_sc_v[(u4 + 3) * MUL1 + v];
            #pragma unroll
            for (int it = 0; it < 8; ++it) {
                int nt = it * 2 + np;
                float4 b = *(const float4*)&s_inv[(nt * 3 + d) * 32 + u4];
                scc[it] = fmaf(b.x, w0, fmaf(b.y, w1, fmaf(b.z, w2, fmaf(b.w, w3, scc[it]))));
            }
        }
        #pragma unroll
        for (int it = 0; it < 8; ++it) {
            int nt = it * 2 + np;
            s_out[nt * NODE_F + MUL0 + v * 3 + d] =
                s_attr[nt] * (s_cs[nt] * (INV_SQRT32 * scc[it]) + s_sn[nt] * acc[it]);
        }
    }
    __syncthreads();

    // ---- coalesced store ----
    {
        float4* gdst = (float4*)(out + (size_t)n0 * NODE_F);
        const float4* lsrc = (const float4*)s_out;
        int cnt4 = nv * (NODE_F / 4);
        for (int i = tid; i < cnt4; i += 320)
            gdst[i] = lsrc[i];
    }
}

extern "C" void kernel_launch(void* const* d_in, const int* in_sizes, int n_in,
                              void* d_out, int out_size, void* d_ws, size_t ws_size,
                              hipStream_t stream)
{
    const float* node_input   = (const float*)d_in[0];
    const float* node_attr    = (const float*)d_in[1];
    const float* edge_attr    = (const float*)d_in[2];
    const float* edge_scalars = (const float*)d_in[3];
    const float* W_sc_s       = (const float*)d_in[4];
    const float* W_sc_v       = (const float*)d_in[5];
    const float* W1_s         = (const float*)d_in[6];
    const float* W1_v         = (const float*)d_in[7];
    const float* W2_s         = (const float*)d_in[8];
    const float* W2_v         = (const float*)d_in[9];
    const float* W3           = (const float*)d_in[10];
    const float* fcW1         = (const float*)d_in[11];
    const float* fcW2         = (const float*)d_in[12];
    const int*   edge_src     = (const int*)d_in[13];
    const int*   edge_dst     = (const int*)d_in[14];
    float* out = (float*)d_out;

    const int N = in_sizes[1];
    const int E = in_sizes[13];

    // ---- workspace layout ----
    char* p = (char*)d_ws;
    float* agg = (float*)p;  p += (size_t)N * AGG_F * sizeof(float);
    int*   deg = (int*)p;    p += (size_t)N * sizeof(int);
    int*   cur = (int*)p;    p += (size_t)N * sizeof(int);
    int*   csr = (int*)p;    p += (size_t)E * sizeof(int);
    int*   off = (int*)p;    p += (size_t)(N + 1) * sizeof(int);

    float* f = out;   // f lives in d_out, overwritten by k_out at the end

    hipMemsetAsync(deg, 0, (size_t)N * sizeof(int), stream);
    hipMemsetAsync(agg, 0, (size_t)N * AGG_F * sizeof(float), stream);

    int eb = (E + 255) / 256;
    k_count<<<eb, 256, 0, stream>>>(edge_dst, deg, E);
    k_scan<<<1, 1024, 0, stream>>>(deg, off, cur, N);
    k_scatter<<<eb, 256, 0, stream>>>(edge_dst, cur, csr, E);

    int nt = N * NODE_F;
    k_node_lin<<<(nt + 255) / 256, 256, 0, stream>>>(node_input, node_attr, W1_s, W1_v, f, N);

    int tiles = (E + 63) / 64;
    int gridF = tiles < 1024 ? tiles : 1024;
    k_edge_fused<<<gridF, 256, 0, stream>>>(f, edge_scalars, edge_attr, fcW1, fcW2,
                                            edge_src, edge_dst, csr, agg, E);

    k_out<<<(N + ONT - 1) / ONT, 320, 0, stream>>>(node_input, node_attr, agg,
                                                   W_sc_s, W_sc_v, W2_s, W2_v, W3, out, N);
}

// Round 7
// 400.008 us; speedup vs baseline: 4.6534x; 1.1600x over previous
//
#include <hip/hip_runtime.h>
#include <math.h>

#define MUL0 64
#define MUL1 32
#define RADF 8
#define HIDF 64
#define WNUM 192
#define NODE_F 160   // 64 + 96
#define AGG_F  384   // A(64) | D(32) | mv_d0(96) | mv_d1(96) | mv_d2(96)

#define INV_SQRT64 0.125f
#define INV_SQRT32 0.17677669529663687f
#define INV_SQRT8  0.35355339059327373f
#define INV_SQRT96 0.10206207261596575f
#define INV_SQRT10 0.31622776601683794f
#define INV_SQRT3  0.5773502691896258f

typedef __attribute__((ext_vector_type(8))) short bf16x8;
typedef __attribute__((ext_vector_type(4))) float f32x4;

__device__ __forceinline__ float bf2f(unsigned short u) {
    return __uint_as_float((unsigned)u << 16);
}
__device__ __forceinline__ unsigned short f2bfu(float x) {
    unsigned ua = __float_as_uint(x);
    return (unsigned short)((ua + 0x7FFF + ((ua >> 16) & 1)) >> 16);
}
__device__ __forceinline__ unsigned bf16pack(float a, float b) {
    unsigned ua = __float_as_uint(a);
    unsigned ub = __float_as_uint(b);
    ua = (ua + 0x7FFF + ((ua >> 16) & 1)) >> 16;
    ub = (ub + 0x7FFF + ((ub >> 16) & 1)) >> 16;
    return ua | (ub << 16);
}
__device__ __forceinline__ int rdlane(int v, int i) {
    return __builtin_amdgcn_readlane(v, i);
}
__device__ __forceinline__ float rdlanef(float v, int i) {
    return __int_as_float(__builtin_amdgcn_readlane(__float_as_int(v), i));
}

// ---------------- kernel: f = _lin(s_in, v_in, W1_s, W1_v, attr), d-major output ----------------
// f layout: [n][0:64]=s ; [n][64 + d*32 + u] = v[u][d]
__global__ void k_node_lin(const float* __restrict__ node_input,
                           const float* __restrict__ node_attr,
                           const float* __restrict__ W1_s,
                           const float* __restrict__ W1_v,
                           float* __restrict__ f, int N)
{
    int t = blockIdx.x * blockDim.x + threadIdx.x;
    int n = t / NODE_F;
    int c = t % NODE_F;
    if (n >= N) return;
    const float* row = node_input + (size_t)n * NODE_F;
    float attr = node_attr[n];
    float acc = 0.f;
    if (c < MUL0) {
        #pragma unroll
        for (int u = 0; u < MUL0; ++u)
            acc = fmaf(row[u], W1_s[u * MUL0 + c], acc);
        acc *= attr * INV_SQRT64;
    } else {
        int cc = c - MUL0;
        int d = cc >> 5, v = cc & 31;
        #pragma unroll
        for (int u = 0; u < MUL1; ++u)
            acc = fmaf(row[MUL0 + u * 3 + d], W1_v[u * MUL1 + v], acc);
        acc *= attr * INV_SQRT32;
    }
    f[(size_t)n * NODE_F + c] = acc;
}

// ---------------- CSR build ----------------
__global__ void k_count(const int* __restrict__ edge_dst, int* deg, int E)
{
    int e = blockIdx.x * blockDim.x + threadIdx.x;
    if (e < E) atomicAdd(&deg[edge_dst[e]], 1);
}

__global__ __launch_bounds__(1024) void k_scan(const int* __restrict__ deg,
                                               int* __restrict__ off,
                                               int* __restrict__ cur, int N)
{
    __shared__ int swsum[16];
    __shared__ int swoff[16];
    __shared__ int sbase;
    __shared__ int stotal;
    int lane = threadIdx.x & 63, wid = threadIdx.x >> 6;
    if (threadIdx.x == 0) sbase = 0;
    __syncthreads();
    int ngroups = N >> 2;
    for (int base = 0; base < ngroups; base += 1024) {
        int g = base + threadIdx.x;
        int4 v = make_int4(0, 0, 0, 0);
        if (g < ngroups) v = ((const int4*)deg)[g];
        int s = v.x + v.y + v.z + v.w;
        int val = s;
        #pragma unroll
        for (int sh = 1; sh < 64; sh <<= 1) {
            int t = __shfl_up(val, sh);
            if (lane >= sh) val += t;
        }
        if (lane == 63) swsum[wid] = val;
        __syncthreads();
        if (threadIdx.x < 16) {
            int x = swsum[threadIdx.x];
            int xv = x;
            #pragma unroll
            for (int sh = 1; sh < 16; sh <<= 1) {
                int t = __shfl_up(xv, sh);
                if ((int)threadIdx.x >= sh) xv += t;
            }
            swoff[threadIdx.x] = xv - x;
            if (threadIdx.x == 15) stotal = xv;
        }
        __syncthreads();
        if (g < ngroups) {
            int b = sbase + swoff[wid] + (val - s);
            int4 o;
            o.x = b; o.y = b + v.x; o.z = o.y + v.y; o.w = o.z + v.z;
            ((int4*)off)[g] = o;
            ((int4*)cur)[g] = o;
        }
        __syncthreads();
        if (threadIdx.x == 0) sbase += stotal;
        __syncthreads();
    }
    if (threadIdx.x == 0) {
        int b = sbase;
        for (int i = (ngroups << 2); i < N; ++i) { off[i] = b; cur[i] = b; b += deg[i]; }
        off[N] = b;
    }
}

__global__ void k_scatter(const int* __restrict__ edge_dst,
                          int* cur, int* __restrict__ csr, int E)
{
    int e = blockIdx.x * blockDim.x + threadIdx.x;
    if (e < E) {
        int d = edge_dst[e];
        int pos = atomicAdd(&cur[d], 1);
        csr[pos] = e;
    }
}

// ---------------- fused edge kernel: per-wave 16-edge tiles, barrier-free ----------------
#define FLUSH_AGG(node)                                              \
    do {                                                             \
        float* an = agg + (size_t)(node) * AGG_F;                    \
        atomicAdd(&an[lane], accA);                                  \
        atomicAdd(&an[96  + lane], accB0);                           \
        atomicAdd(&an[192 + lane], accB1);                           \
        atomicAdd(&an[288 + lane], accB2);                           \
        if (lane < 32) {                                             \
            atomicAdd(&an[160 + u], accX0);                          \
            atomicAdd(&an[256 + u], accX1);                          \
            atomicAdd(&an[352 + u], accX2);                          \
        } else {                                                     \
            atomicAdd(&an[64 + u], accX0);                           \
        }                                                            \
    } while (0)

__global__ __launch_bounds__(256, 3) void k_edge_fused(
    const float* __restrict__ f,
    const float* __restrict__ edge_scalars,
    const float* __restrict__ edge_attr,
    const float* __restrict__ fcW1,
    const float* __restrict__ fcW2,
    const int* __restrict__ edge_src,
    const int* __restrict__ edge_dst,
    const int* __restrict__ csr,
    float* agg, int E)
{
    // fcW2 transposed, bf16, k-oct-major: s_w2t[oct][col][8k]   24576 B
    __shared__ unsigned short s_w2t[8 * 192 * 8];
    // per-wave private w slices [16 edges][216]                  27648 B
    __shared__ unsigned short s_w[4][16 * 216];
    __shared__ float s_fcW1[512];                              //  2048 B
    // total 54272 B -> 3 blocks/CU

    int tid  = threadIdx.x;
    int lane = tid & 63;
    int wv   = tid >> 6;
    int l15  = lane & 15, lh = lane >> 4;
    int u    = lane & 31;

    // ---- once per block: stage fcW2^T (bf16) and fcW1 ----
    for (int task = tid; task < 1536; task += 256) {
        int col = task % 192, oct = task / 192;
        const float* wp = fcW2 + (size_t)(oct * 8) * WNUM + col;
        unsigned pk0 = bf16pack(wp[0 * WNUM], wp[1 * WNUM]);
        unsigned pk1 = bf16pack(wp[2 * WNUM], wp[3 * WNUM]);
        unsigned pk2 = bf16pack(wp[4 * WNUM], wp[5 * WNUM]);
        unsigned pk3 = bf16pack(wp[6 * WNUM], wp[7 * WNUM]);
        *(uint4*)&s_w2t[oct * 1536 + col * 8] = make_uint4(pk0, pk1, pk2, pk3);
    }
    for (int i = tid; i < 512; i += 256)
        s_fcW1[i] = fcW1[i];
    __syncthreads();      // the only block barrier

    unsigned short* sw = s_w[wv];
    int nwt = (E + 15) >> 4;

    for (int wt = blockIdx.x * 4 + wv; wt < nwt; wt += gridDim.x * 4) {
        int P = wt << 4;
        int m = min(16, E - P);

        // ---- metadata in registers (lane l15 owns edge P+l15; 4x redundant across lh) ----
        int el  = P + min(l15, m - 1);
        int e   = csr[el];
        int src = edge_src[e];
        int dst = edge_dst[e];
        float4 ea = *(const float4*)(edge_attr + (size_t)e * 4);
        const float4* esp = (const float4*)(edge_scalars + (size_t)e * RADF);
        float4 es0 = esp[0], es1 = esp[1];

        // ---- prefetch f rows for all 16 edges (issued before h-compute) ----
        float xs[16], xv0[16], xv1[16], xv2[16];
        #pragma unroll
        for (int i = 0; i < 16; ++i) {
            int si = rdlane(src, i);
            const float* fb = f + (size_t)si * NODE_F;
            xs[i]  = fb[lane];
            xv0[i] = fb[64 + u];
            xv1[i] = fb[96 + u];
            xv2[i] = fb[128 + u];
        }

        // ---- h for own edge (l15): k = lh*8+j (A0), 32+lh*8+j (A1); pure registers ----
        float es[8] = {es0.x, es0.y, es0.z, es0.w, es1.x, es1.y, es1.z, es1.w};
        union { unsigned q[4]; bf16x8 v; } A0, A1;
        #pragma unroll
        for (int jp = 0; jp < 4; ++jp) {
            int k0 = lh * 8 + 2 * jp;
            float aL0 = 0.f, aL1 = 0.f, aH0 = 0.f, aH1 = 0.f;
            #pragma unroll
            for (int r = 0; r < 8; ++r) {
                float2 wl = *(const float2*)&s_fcW1[r * 64 + k0];
                float2 wh = *(const float2*)&s_fcW1[r * 64 + 32 + k0];
                aL0 = fmaf(es[r], wl.x, aL0);
                aL1 = fmaf(es[r], wl.y, aL1);
                aH0 = fmaf(es[r], wh.x, aH0);
                aH1 = fmaf(es[r], wh.y, aH1);
            }
            aL0 *= INV_SQRT8; aL1 *= INV_SQRT8; aH0 *= INV_SQRT8; aH1 *= INV_SQRT8;
            aL0 = aL0 / (1.f + __expf(-aL0));
            aL1 = aL1 / (1.f + __expf(-aL1));
            aH0 = aH0 / (1.f + __expf(-aH0));
            aH1 = aH1 / (1.f + __expf(-aH1));
            A0.q[jp] = bf16pack(aL0, aL1);
            A1.q[jp] = bf16pack(aH0, aH1);
        }

        // ---- w = h @ fcW2 / sqrt(64) via MFMA into private s_w slice ----
        #pragma unroll
        for (int cb = 0; cb < 12; ++cb) {
            bf16x8 b0 = *(const bf16x8*)&s_w2t[ lh      * 1536 + (cb * 16 + l15) * 8];
            bf16x8 b1 = *(const bf16x8*)&s_w2t[(4 + lh) * 1536 + (cb * 16 + l15) * 8];
            f32x4 acc = {0.f, 0.f, 0.f, 0.f};
            acc = __builtin_amdgcn_mfma_f32_16x16x32_bf16(A0.v, b0, acc, 0, 0, 0);
            acc = __builtin_amdgcn_mfma_f32_16x16x32_bf16(A1.v, b1, acc, 0, 0, 0);
            #pragma unroll
            for (int r = 0; r < 4; ++r)
                sw[(lh * 4 + r) * 216 + cb * 16 + l15] = f2bfu(acc[r] * INV_SQRT64);
        }

        // ---- tensor product + dst-segmented atomic reduction (same wave, no barrier) ----
        float accA = 0.f, accB0 = 0.f, accB1 = 0.f, accB2 = 0.f;
        float accX0 = 0.f, accX1 = 0.f, accX2 = 0.f;
        int curd = rdlane(dst, 0);
        #pragma unroll
        for (int i = 0; i < 16; ++i) {
            if (i < m) {
                int di = rdlane(dst, i);
                if (di != curd) {
                    FLUSH_AGG(curd);
                    accA = accB0 = accB1 = accB2 = 0.f;
                    accX0 = accX1 = accX2 = 0.f;
                    curd = di;
                }
                float eax = rdlanef(ea.x, i);
                float eay = rdlanef(ea.y, i);
                float eaz = rdlanef(ea.z, i);
                float eaw = rdlanef(ea.w, i);
                float W0 = bf2f(sw[i * 216 + lane]);
                float W1 = bf2f(sw[i * 216 + 64 + lane]);
                float W2 = bf2f(sw[i * 216 + 128 + lane]);
                accA = fmaf(W0 * xs[i], eax, accA);
                float bx = W1 * xs[i];
                accB0 = fmaf(bx, eay, accB0);
                accB1 = fmaf(bx, eaz, accB1);
                accB2 = fmaf(bx, eaw, accB2);
                if (lane < 32) {
                    float cc = W2 * eax;
                    accX0 = fmaf(cc, xv0[i], accX0);
                    accX1 = fmaf(cc, xv1[i], accX1);
                    accX2 = fmaf(cc, xv2[i], accX2);
                } else {
                    float dv = xv0[i] * eay + xv1[i] * eaz + xv2[i] * eaw;
                    accX0 = fmaf(W2 * INV_SQRT3, dv, accX0);
                }
            }
        }
        FLUSH_AGG(curd);
    }
}

// ---------------- kernel: output combine (LDS-tiled mini-GEMM + fused angle) ----------------
#define ONT 16   // nodes per block
__global__ __launch_bounds__(320) void k_out(
    const float* __restrict__ node_input,
    const float* __restrict__ node_attr,
    const float* __restrict__ agg,
    const float* __restrict__ W_sc_s,
    const float* __restrict__ W_sc_v,
    const float* __restrict__ W2_s,
    const float* __restrict__ W2_v,
    const float* __restrict__ W3,
    float* __restrict__ out, int N)
{
    __shared__ float s_ag [ONT * AGG_F];      // 24.6 KB (prescaled)
    __shared__ float s_ins[ONT * 64];         // 4 KB
    __shared__ float s_inv[ONT * 3 * 32];     // 6 KB (d-major)
    __shared__ float s_out[ONT * NODE_F];     // 10.2 KB
    __shared__ float s_cs[ONT], s_sn[ONT], s_attr[ONT];

    int tid = threadIdx.x;
    int n0 = blockIdx.x * ONT;
    int nv = min(ONT, N - n0);
    const float pre = INV_SQRT10 * INV_SQRT96;

    // ---- stage ----
    {
        const float4* gsrc = (const float4*)(agg + (size_t)n0 * AGG_F);
        float4* ldst = (float4*)s_ag;
        int cnt4 = nv * (AGG_F / 4);
        for (int i = tid; i < ONT * (AGG_F / 4); i += 320) {
            float4 v = (i < cnt4) ? gsrc[i] : make_float4(0, 0, 0, 0);
            v.x *= pre; v.y *= pre; v.z *= pre; v.w *= pre;
            ldst[i] = v;
        }
        const float* isrc = node_input + (size_t)n0 * NODE_F;
        int icnt = nv * NODE_F;
        for (int i = tid; i < ONT * NODE_F; i += 320) {
            float val = (i < icnt) ? isrc[i] : 0.f;
            int nt = i / NODE_F, c = i % NODE_F;
            if (c < MUL0) s_ins[nt * 64 + c] = val;
            else {
                int cc = c - MUL0;
                s_inv[(nt * 3 + (cc % 3)) * 32 + (cc / 3)] = val;
            }
        }
        if (tid < ONT) {
            s_attr[tid] = (tid < nv) ? node_attr[n0 + tid] : 0.f;
        }
    }
    __syncthreads();

    // ---- angle: per-node dot(ms, W3) over prescaled s_ag[0:96] ----
    {
        int g = tid >> 5;        // half-wave group 0..9
        int hl = tid & 31;
        #pragma unroll
        for (int pass = 0; pass < 2; ++pass) {
            int nt = pass * 10 + g;
            if (nt < ONT) {
                const float* ag = s_ag + nt * AGG_F;
                float pa = ag[hl] * W3[hl]
                         + ag[32 + hl] * W3[32 + hl]
                         + ag[64 + hl] * W3[64 + hl];
                #pragma unroll
                for (int s = 16; s >= 1; s >>= 1)
                    pa += __shfl_xor(pa, s);
                if (hl == 0) {
                    float ang = 0.1f * s_attr[nt] * pa;
                    s_cs[nt] = cosf(ang);
                    s_sn[nt] = sinf(ang);
                }
            }
        }
    }
    __syncthreads();

    int wid = tid >> 6;
    int lane = tid & 63;

    if (wid < 2) {
        // ---- scalar part: lane = channel, 8 nodes ----
        int qbase = wid * 8;
        float acc[8] = {0,0,0,0,0,0,0,0};
        float scc[8] = {0,0,0,0,0,0,0,0};
        for (int j4 = 0; j4 < 96; j4 += 4) {
            float w0 = W2_s[(j4 + 0) * MUL0 + lane];
            float w1 = W2_s[(j4 + 1) * MUL0 + lane];
            float w2 = W2_s[(j4 + 2) * MUL0 + lane];
            float w3 = W2_s[(j4 + 3) * MUL0 + lane];
            #pragma unroll
            for (int q = 0; q < 8; ++q) {
                float4 a = *(const float4*)&s_ag[(qbase + q) * AGG_F + j4];
                acc[q] = fmaf(a.x, w0, fmaf(a.y, w1, fmaf(a.z, w2, fmaf(a.w, w3, acc[q]))));
            }
        }
        for (int u4 = 0; u4 < 64; u4 += 4) {
            float w0 = W_sc_s[(u4 + 0) * MUL0 + lane];
            float w1 = W_sc_s[(u4 + 1) * MUL0 + lane];
            float w2 = W_sc_s[(u4 + 2) * MUL0 + lane];
            float w3 = W_sc_s[(u4 + 3) * MUL0 + lane];
            #pragma unroll
            for (int q = 0; q < 8; ++q) {
                float4 b = *(const float4*)&s_ins[(qbase + q) * 64 + u4];
                scc[q] = fmaf(b.x, w0, fmaf(b.y, w1, fmaf(b.z, w2, fmaf(b.w, w3, scc[q]))));
            }
        }
        #pragma unroll
        for (int q = 0; q < 8; ++q) {
            int nt = qbase + q;
            s_out[nt * NODE_F + lane] =
                s_attr[nt] * (s_cs[nt] * (INV_SQRT64 * scc[q]) + s_sn[nt] * acc[q]);
        }
    } else {
        // ---- vector part: d = wid-2; lanes = 2 nodes x 32 v-channels ----
        int d = wid - 2;
        int v = lane & 31;
        int np = lane >> 5;
        float acc[8] = {0,0,0,0,0,0,0,0};
        float scc[8] = {0,0,0,0,0,0,0,0};
        int agoff = 96 + d * 96;
        for (int j4 = 0; j4 < 96; j4 += 4) {
            float w0 = W2_v[(j4 + 0) * MUL1 + v];
            float w1 = W2_v[(j4 + 1) * MUL1 + v];
            float w2 = W2_v[(j4 + 2) * MUL1 + v];
            float w3 = W2_v[(j4 + 3) * MUL1 + v];
            #pragma unroll
            for (int it = 0; it < 8; ++it) {
                int nt = it * 2 + np;
                float4 a = *(const float4*)&s_ag[nt * AGG_F + agoff + j4];
                acc[it] = fmaf(a.x, w0, fmaf(a.y, w1, fmaf(a.z, w2, fmaf(a.w, w3, acc[it]))));
            }
        }
        for (int u4 = 0; u4 < 32; u4 += 4) {
            float w0 = W_sc_v[(u4 + 0) * MUL1 + v];
            float w1 = W_sc_v[(u4 + 1) * MUL1 + v];
            float w2 = W_sc_v[(u4 + 2) * MUL1 + v];
            float w3 = W_sc_v[(u4 + 3) * MUL1 + v];
            #pragma unroll
            for (int it = 0; it < 8; ++it) {
                int nt = it * 2 + np;
                float4 b = *(const float4*)&s_inv[(nt * 3 + d) * 32 + u4];
                scc[it] = fmaf(b.x, w0, fmaf(b.y, w1, fmaf(b.z, w2, fmaf(b.w, w3, scc[it]))));
            }
        }
        #pragma unroll
        for (int it = 0; it < 8; ++it) {
            int nt = it * 2 + np;
            s_out[nt * NODE_F + MUL0 + v * 3 + d] =
                s_attr[nt] * (s_cs[nt] * (INV_SQRT32 * scc[it]) + s_sn[nt] * acc[it]);
        }
    }
    __syncthreads();

    // ---- coalesced store ----
    {
        float4* gdst = (float4*)(out + (size_t)n0 * NODE_F);
        const float4* lsrc = (const float4*)s_out;
        int cnt4 = nv * (NODE_F / 4);
        for (int i = tid; i < cnt4; i += 320)
            gdst[i] = lsrc[i];
    }
}

extern "C" void kernel_launch(void* const* d_in, const int* in_sizes, int n_in,
                              void* d_out, int out_size, void* d_ws, size_t ws_size,
                              hipStream_t stream)
{
    const float* node_input   = (const float*)d_in[0];
    const float* node_attr    = (const float*)d_in[1];
    const float* edge_attr    = (const float*)d_in[2];
    const float* edge_scalars = (const float*)d_in[3];
    const float* W_sc_s       = (const float*)d_in[4];
    const float* W_sc_v       = (const float*)d_in[5];
    const float* W1_s         = (const float*)d_in[6];
    const float* W1_v         = (const float*)d_in[7];
    const float* W2_s         = (const float*)d_in[8];
    const float* W2_v         = (const float*)d_in[9];
    const float* W3           = (const float*)d_in[10];
    const float* fcW1         = (const float*)d_in[11];
    const float* fcW2         = (const float*)d_in[12];
    const int*   edge_src     = (const int*)d_in[13];
    const int*   edge_dst     = (const int*)d_in[14];
    float* out = (float*)d_out;

    const int N = in_sizes[1];
    const int E = in_sizes[13];

    // ---- workspace layout ----
    char* p = (char*)d_ws;
    float* agg = (float*)p;  p += (size_t)N * AGG_F * sizeof(float);
    int*   deg = (int*)p;    p += (size_t)N * sizeof(int);
    int*   cur = (int*)p;    p += (size_t)N * sizeof(int);
    int*   csr = (int*)p;    p += (size_t)E * sizeof(int);
    int*   off = (int*)p;    p += (size_t)(N + 1) * sizeof(int);

    float* f = out;   // f lives in d_out, overwritten by k_out at the end

    hipMemsetAsync(deg, 0, (size_t)N * sizeof(int), stream);
    hipMemsetAsync(agg, 0, (size_t)N * AGG_F * sizeof(float), stream);

    int eb = (E + 255) / 256;
    k_count<<<eb, 256, 0, stream>>>(edge_dst, deg, E);
    k_scan<<<1, 1024, 0, stream>>>(deg, off, cur, N);
    k_scatter<<<eb, 256, 0, stream>>>(edge_dst, cur, csr, E);

    int nt = N * NODE_F;
    k_node_lin<<<(nt + 255) / 256, 256, 0, stream>>>(node_input, node_attr, W1_s, W1_v, f, N);

    int nwt = (E + 15) / 16;
    int gridF = (nwt + 3) / 4;
    if (gridF > 1536) gridF = 1536;
    k_edge_fused<<<gridF, 256, 0, stream>>>(f, edge_scalars, edge_attr, fcW1, fcW2,
                                            edge_src, edge_dst, csr, agg, E);

    k_out<<<(N + ONT - 1) / ONT, 320, 0, stream>>>(node_input, node_attr, agg,
                                                   W_sc_s, W_sc_v, W2_s, W2_v, W3, out, N);
}

// Round 8
// 396.288 us; speedup vs baseline: 4.6971x; 1.0094x over previous
//
#include <hip/hip_runtime.h>
#include <math.h>

#define MUL0 64
#define MUL1 32
#define RADF 8
#define HIDF 64
#define WNUM 192
#define NODE_F 160   // 64 + 96
#define AGG_F  384   // A(64) | D(32) | mv_d0(96) | mv_d1(96) | mv_d2(96)

#define INV_SQRT64 0.125f
#define INV_SQRT32 0.17677669529663687f
#define INV_SQRT8  0.35355339059327373f
#define INV_SQRT96 0.10206207261596575f
#define INV_SQRT10 0.31622776601683794f
#define INV_SQRT3  0.5773502691896258f

typedef __attribute__((ext_vector_type(8))) short bf16x8;
typedef __attribute__((ext_vector_type(4))) float f32x4;

__device__ __forceinline__ float bf2f(unsigned short u) {
    return __uint_as_float((unsigned)u << 16);
}
__device__ __forceinline__ unsigned short f2bfu(float x) {
    unsigned ua = __float_as_uint(x);
    return (unsigned short)((ua + 0x7FFF + ((ua >> 16) & 1)) >> 16);
}
__device__ __forceinline__ unsigned bf16pack(float a, float b) {
    unsigned ua = __float_as_uint(a);
    unsigned ub = __float_as_uint(b);
    ua = (ua + 0x7FFF + ((ua >> 16) & 1)) >> 16;
    ub = (ub + 0x7FFF + ((ub >> 16) & 1)) >> 16;
    return ua | (ub << 16);
}
__device__ __forceinline__ int rdlane(int v, int i) {
    return __builtin_amdgcn_readlane(v, i);
}
__device__ __forceinline__ float rdlanef(float v, int i) {
    return __int_as_float(__builtin_amdgcn_readlane(__float_as_int(v), i));
}

// ---------------- kernel: f = _lin(...), wave per 8 nodes, no LDS ----------------
// f layout: [n][0:64]=s ; [n][64 + d*32 + u] = v[u][d]
__global__ __launch_bounds__(256) void k_node_lin(
    const float* __restrict__ node_input,
    const float* __restrict__ node_attr,
    const float* __restrict__ W1_s,
    const float* __restrict__ W1_v,
    float* __restrict__ f, int N)
{
    int lane = threadIdx.x & 63;
    int gw = (blockIdx.x * blockDim.x + threadIdx.x) >> 6;
    int n0 = gw * 8;
    if (n0 >= N) return;
    int nv = min(8, N - n0);
    int v = lane & 31, np = lane >> 5;

    float attr[8];
    #pragma unroll
    for (int q = 0; q < 8; ++q)
        attr[q] = node_attr[n0 + (q < nv ? q : 0)];

    // ---- s-part: lane = channel c ----
    {
        float acc[8] = {0,0,0,0,0,0,0,0};
        for (int u4 = 0; u4 < 64; u4 += 4) {
            float w0 = W1_s[(u4 + 0) * MUL0 + lane];
            float w1 = W1_s[(u4 + 1) * MUL0 + lane];
            float w2 = W1_s[(u4 + 2) * MUL0 + lane];
            float w3 = W1_s[(u4 + 3) * MUL0 + lane];
            #pragma unroll
            for (int q = 0; q < 8; ++q) {
                int nq = n0 + (q < nv ? q : 0);
                float4 a = *(const float4*)&node_input[(size_t)nq * NODE_F + u4];
                acc[q] = fmaf(a.x, w0, fmaf(a.y, w1, fmaf(a.z, w2, fmaf(a.w, w3, acc[q]))));
            }
        }
        #pragma unroll
        for (int q = 0; q < 8; ++q)
            if (q < nv)
                f[(size_t)(n0 + q) * NODE_F + lane] = acc[q] * attr[q] * INV_SQRT64;
    }

    // ---- v-part: half-wave = 32 channels x 2 node-slots, d outer ----
    #pragma unroll
    for (int d = 0; d < 3; ++d) {
        float vacc[4] = {0,0,0,0};
        for (int u4 = 0; u4 < 32; u4 += 4) {
            float w0 = W1_v[(u4 + 0) * MUL1 + v];
            float w1 = W1_v[(u4 + 1) * MUL1 + v];
            float w2 = W1_v[(u4 + 2) * MUL1 + v];
            float w3 = W1_v[(u4 + 3) * MUL1 + v];
            #pragma unroll
            for (int p = 0; p < 4; ++p) {
                int q = p * 2 + np;
                int nq = n0 + (q < nv ? q : 0);
                const float* ip = node_input + (size_t)nq * NODE_F + 64 + d;
                vacc[p] = fmaf(ip[3 * (u4 + 0)], w0,
                          fmaf(ip[3 * (u4 + 1)], w1,
                          fmaf(ip[3 * (u4 + 2)], w2,
                          fmaf(ip[3 * (u4 + 3)], w3, vacc[p]))));
            }
        }
        #pragma unroll
        for (int p = 0; p < 4; ++p) {
            int q = p * 2 + np;
            float at = np ? attr[p * 2 + 1] : attr[p * 2];
            if (q < nv)
                f[(size_t)(n0 + q) * NODE_F + 64 + d * 32 + v] = vacc[p] * at * INV_SQRT32;
        }
    }
}

// ---------------- CSR build ----------------
__global__ void k_count(const int* __restrict__ edge_dst, int* deg, int E)
{
    int e = blockIdx.x * blockDim.x + threadIdx.x;
    if (e < E) atomicAdd(&deg[edge_dst[e]], 1);
}

__global__ __launch_bounds__(1024) void k_scan(const int* __restrict__ deg,
                                               int* __restrict__ off,
                                               int* __restrict__ cur, int N)
{
    __shared__ int swsum[16];
    __shared__ int swoff[16];
    __shared__ int sbase;
    __shared__ int stotal;
    int lane = threadIdx.x & 63, wid = threadIdx.x >> 6;
    if (threadIdx.x == 0) sbase = 0;
    __syncthreads();
    int ngroups = N >> 2;
    for (int base = 0; base < ngroups; base += 1024) {
        int g = base + threadIdx.x;
        int4 v = make_int4(0, 0, 0, 0);
        if (g < ngroups) v = ((const int4*)deg)[g];
        int s = v.x + v.y + v.z + v.w;
        int val = s;
        #pragma unroll
        for (int sh = 1; sh < 64; sh <<= 1) {
            int t = __shfl_up(val, sh);
            if (lane >= sh) val += t;
        }
        if (lane == 63) swsum[wid] = val;
        __syncthreads();
        if (threadIdx.x < 16) {
            int x = swsum[threadIdx.x];
            int xv = x;
            #pragma unroll
            for (int sh = 1; sh < 16; sh <<= 1) {
                int t = __shfl_up(xv, sh);
                if ((int)threadIdx.x >= sh) xv += t;
            }
            swoff[threadIdx.x] = xv - x;
            if (threadIdx.x == 15) stotal = xv;
        }
        __syncthreads();
        if (g < ngroups) {
            int b = sbase + swoff[wid] + (val - s);
            int4 o;
            o.x = b; o.y = b + v.x; o.z = o.y + v.y; o.w = o.z + v.z;
            ((int4*)off)[g] = o;
            ((int4*)cur)[g] = o;
        }
        __syncthreads();
        if (threadIdx.x == 0) sbase += stotal;
        __syncthreads();
    }
    if (threadIdx.x == 0) {
        int b = sbase;
        for (int i = (ngroups << 2); i < N; ++i) { off[i] = b; cur[i] = b; b += deg[i]; }
        off[N] = b;
    }
}

__global__ void k_scatter(const int* __restrict__ edge_dst,
                          int* cur, int* __restrict__ csr, int E)
{
    int e = blockIdx.x * blockDim.x + threadIdx.x;
    if (e < E) {
        int d = edge_dst[e];
        int pos = atomicAdd(&cur[d], 1);
        csr[pos] = e;
    }
}

// ---------------- fused edge kernel: per-wave 16-edge tiles, barrier-free ----------------
#define FLUSH_AGG(node)                                              \
    do {                                                             \
        float* an = agg + (size_t)(node) * AGG_F;                    \
        atomicAdd(&an[lane], accA);                                  \
        atomicAdd(&an[96  + lane], accB0);                           \
        atomicAdd(&an[192 + lane], accB1);                           \
        atomicAdd(&an[288 + lane], accB2);                           \
        if (lane < 32) {                                             \
            atomicAdd(&an[160 + u], accX0);                          \
            atomicAdd(&an[256 + u], accX1);                          \
            atomicAdd(&an[352 + u], accX2);                          \
        } else {                                                     \
            atomicAdd(&an[64 + u], accX0);                           \
        }                                                            \
    } while (0)

__global__ __launch_bounds__(256, 3) void k_edge_fused(
    const float* __restrict__ f,
    const float* __restrict__ edge_scalars,
    const float* __restrict__ edge_attr,
    const float* __restrict__ fcW1,
    const float* __restrict__ fcW2,
    const int* __restrict__ edge_src,
    const int* __restrict__ edge_dst,
    const int* __restrict__ csr,
    float* agg, int E)
{
    __shared__ unsigned short s_w2t[8 * 192 * 8];   // 24576 B
    __shared__ unsigned short s_w[4][16 * 216];     // 27648 B
    __shared__ float s_fcW1[512];                   //  2048 B

    int tid  = threadIdx.x;
    int lane = tid & 63;
    int wv   = tid >> 6;
    int l15  = lane & 15, lh = lane >> 4;
    int u    = lane & 31;

    for (int task = tid; task < 1536; task += 256) {
        int col = task % 192, oct = task / 192;
        const float* wp = fcW2 + (size_t)(oct * 8) * WNUM + col;
        unsigned pk0 = bf16pack(wp[0 * WNUM], wp[1 * WNUM]);
        unsigned pk1 = bf16pack(wp[2 * WNUM], wp[3 * WNUM]);
        unsigned pk2 = bf16pack(wp[4 * WNUM], wp[5 * WNUM]);
        unsigned pk3 = bf16pack(wp[6 * WNUM], wp[7 * WNUM]);
        *(uint4*)&s_w2t[oct * 1536 + col * 8] = make_uint4(pk0, pk1, pk2, pk3);
    }
    for (int i = tid; i < 512; i += 256)
        s_fcW1[i] = fcW1[i];
    __syncthreads();      // the only block barrier

    unsigned short* sw = s_w[wv];
    int nwt = (E + 15) >> 4;

    for (int wt = blockIdx.x * 4 + wv; wt < nwt; wt += gridDim.x * 4) {
        int P = wt << 4;
        int m = min(16, E - P);

        int el  = P + min(l15, m - 1);
        int e   = csr[el];
        int src = edge_src[e];
        int dst = edge_dst[e];
        float4 ea = *(const float4*)(edge_attr + (size_t)e * 4);
        const float4* esp = (const float4*)(edge_scalars + (size_t)e * RADF);
        float4 es0 = esp[0], es1 = esp[1];

        float xs[16], xv0[16], xv1[16], xv2[16];
        #pragma unroll
        for (int i = 0; i < 16; ++i) {
            int si = rdlane(src, i);
            const float* fb = f + (size_t)si * NODE_F;
            xs[i]  = fb[lane];
            xv0[i] = fb[64 + u];
            xv1[i] = fb[96 + u];
            xv2[i] = fb[128 + u];
        }

        float es[8] = {es0.x, es0.y, es0.z, es0.w, es1.x, es1.y, es1.z, es1.w};
        union { unsigned q[4]; bf16x8 v; } A0, A1;
        #pragma unroll
        for (int jp = 0; jp < 4; ++jp) {
            int k0 = lh * 8 + 2 * jp;
            float aL0 = 0.f, aL1 = 0.f, aH0 = 0.f, aH1 = 0.f;
            #pragma unroll
            for (int r = 0; r < 8; ++r) {
                float2 wl = *(const float2*)&s_fcW1[r * 64 + k0];
                float2 wh = *(const float2*)&s_fcW1[r * 64 + 32 + k0];
                aL0 = fmaf(es[r], wl.x, aL0);
                aL1 = fmaf(es[r], wl.y, aL1);
                aH0 = fmaf(es[r], wh.x, aH0);
                aH1 = fmaf(es[r], wh.y, aH1);
            }
            aL0 *= INV_SQRT8; aL1 *= INV_SQRT8; aH0 *= INV_SQRT8; aH1 *= INV_SQRT8;
            aL0 = aL0 / (1.f + __expf(-aL0));
            aL1 = aL1 / (1.f + __expf(-aL1));
            aH0 = aH0 / (1.f + __expf(-aH0));
            aH1 = aH1 / (1.f + __expf(-aH1));
            A0.q[jp] = bf16pack(aL0, aL1);
            A1.q[jp] = bf16pack(aH0, aH1);
        }

        #pragma unroll
        for (int cb = 0; cb < 12; ++cb) {
            bf16x8 b0 = *(const bf16x8*)&s_w2t[ lh      * 1536 + (cb * 16 + l15) * 8];
            bf16x8 b1 = *(const bf16x8*)&s_w2t[(4 + lh) * 1536 + (cb * 16 + l15) * 8];
            f32x4 acc = {0.f, 0.f, 0.f, 0.f};
            acc = __builtin_amdgcn_mfma_f32_16x16x32_bf16(A0.v, b0, acc, 0, 0, 0);
            acc = __builtin_amdgcn_mfma_f32_16x16x32_bf16(A1.v, b1, acc, 0, 0, 0);
            #pragma unroll
            for (int r = 0; r < 4; ++r)
                sw[(lh * 4 + r) * 216 + cb * 16 + l15] = f2bfu(acc[r] * INV_SQRT64);
        }

        float accA = 0.f, accB0 = 0.f, accB1 = 0.f, accB2 = 0.f;
        float accX0 = 0.f, accX1 = 0.f, accX2 = 0.f;
        int curd = rdlane(dst, 0);
        #pragma unroll
        for (int i = 0; i < 16; ++i) {
            if (i < m) {
                int di = rdlane(dst, i);
                if (di != curd) {
                    FLUSH_AGG(curd);
                    accA = accB0 = accB1 = accB2 = 0.f;
                    accX0 = accX1 = accX2 = 0.f;
                    curd = di;
                }
                float eax = rdlanef(ea.x, i);
                float eay = rdlanef(ea.y, i);
                float eaz = rdlanef(ea.z, i);
                float eaw = rdlanef(ea.w, i);
                float W0 = bf2f(sw[i * 216 + lane]);
                float W1 = bf2f(sw[i * 216 + 64 + lane]);
                float W2 = bf2f(sw[i * 216 + 128 + lane]);
                accA = fmaf(W0 * xs[i], eax, accA);
                float bx = W1 * xs[i];
                accB0 = fmaf(bx, eay, accB0);
                accB1 = fmaf(bx, eaz, accB1);
                accB2 = fmaf(bx, eaw, accB2);
                if (lane < 32) {
                    float cc = W2 * eax;
                    accX0 = fmaf(cc, xv0[i], accX0);
                    accX1 = fmaf(cc, xv1[i], accX1);
                    accX2 = fmaf(cc, xv2[i], accX2);
                } else {
                    float dv = xv0[i] * eay + xv1[i] * eaz + xv2[i] * eaw;
                    accX0 = fmaf(W2 * INV_SQRT3, dv, accX0);
                }
            }
        }
        FLUSH_AGG(curd);
    }
}

// ---------------- kernel: output combine, wave per 8 nodes, no LDS ----------------
__global__ __launch_bounds__(256) void k_out(
    const float* __restrict__ node_input,
    const float* __restrict__ node_attr,
    const float* __restrict__ agg,
    const float* __restrict__ W_sc_s,
    const float* __restrict__ W_sc_v,
    const float* __restrict__ W2_s,
    const float* __restrict__ W2_v,
    const float* __restrict__ W3,
    float* __restrict__ out, int N)
{
    int lane = threadIdx.x & 63;
    int gw = (blockIdx.x * blockDim.x + threadIdx.x) >> 6;
    int n0 = gw * 8;
    if (n0 >= N) return;
    int nv = min(8, N - n0);
    int v = lane & 31, np = lane >> 5;
    const float pre = INV_SQRT10 * INV_SQRT96;

    // ---- per-node attr + angle (lane-parallel dot + wave reduce) ----
    float w3a = W3[lane];
    float w3b = (lane < 32) ? W3[64 + lane] : 0.f;
    float attr[8], cs[8], sn[8];
    #pragma unroll
    for (int q = 0; q < 8; ++q) {
        int nq = n0 + (q < nv ? q : 0);
        attr[q] = node_attr[nq];
        const float* ag = agg + (size_t)nq * AGG_F;
        float pa = ag[lane] * w3a;
        if (lane < 32) pa = fmaf(ag[64 + lane], w3b, pa);
        #pragma unroll
        for (int s = 32; s >= 1; s >>= 1)
            pa += __shfl_xor(pa, s);
        float ang = 0.1f * pre * attr[q] * pa;
        cs[q] = cosf(ang);
        sn[q] = sinf(ang);
    }

    // ---- s-part: lane = channel ----
    {
        float acc[8] = {0,0,0,0,0,0,0,0};
        float scc[8] = {0,0,0,0,0,0,0,0};
        for (int j4 = 0; j4 < 96; j4 += 4) {
            float w0 = W2_s[(j4 + 0) * MUL0 + lane];
            float w1 = W2_s[(j4 + 1) * MUL0 + lane];
            float w2 = W2_s[(j4 + 2) * MUL0 + lane];
            float w3 = W2_s[(j4 + 3) * MUL0 + lane];
            #pragma unroll
            for (int q = 0; q < 8; ++q) {
                int nq = n0 + (q < nv ? q : 0);
                float4 a = *(const float4*)&agg[(size_t)nq * AGG_F + j4];
                acc[q] = fmaf(a.x, w0, fmaf(a.y, w1, fmaf(a.z, w2, fmaf(a.w, w3, acc[q]))));
            }
        }
        for (int u4 = 0; u4 < 64; u4 += 4) {
            float w0 = W_sc_s[(u4 + 0) * MUL0 + lane];
            float w1 = W_sc_s[(u4 + 1) * MUL0 + lane];
            float w2 = W_sc_s[(u4 + 2) * MUL0 + lane];
            float w3 = W_sc_s[(u4 + 3) * MUL0 + lane];
            #pragma unroll
            for (int q = 0; q < 8; ++q) {
                int nq = n0 + (q < nv ? q : 0);
                float4 b = *(const float4*)&node_input[(size_t)nq * NODE_F + u4];
                scc[q] = fmaf(b.x, w0, fmaf(b.y, w1, fmaf(b.z, w2, fmaf(b.w, w3, scc[q]))));
            }
        }
        #pragma unroll
        for (int q = 0; q < 8; ++q)
            if (q < nv)
                out[(size_t)(n0 + q) * NODE_F + lane] =
                    attr[q] * (cs[q] * (INV_SQRT64 * scc[q]) + sn[q] * (pre * acc[q]));
    }

    // ---- v-part: half-wave = 32 channels x 2 node-slots, d outer ----
    #pragma unroll
    for (int d = 0; d < 3; ++d) {
        float acc[4] = {0,0,0,0};
        float scc[4] = {0,0,0,0};
        int agoff = 96 + d * 96;
        for (int j4 = 0; j4 < 96; j4 += 4) {
            float w0 = W2_v[(j4 + 0) * MUL1 + v];
            float w1 = W2_v[(j4 + 1) * MUL1 + v];
            float w2 = W2_v[(j4 + 2) * MUL1 + v];
            float w3 = W2_v[(j4 + 3) * MUL1 + v];
            #pragma unroll
            for (int p = 0; p < 4; ++p) {
                int q = p * 2 + np;
                int nq = n0 + (q < nv ? q : 0);
                float4 a = *(const float4*)&agg[(size_t)nq * AGG_F + agoff + j4];
                acc[p] = fmaf(a.x, w0, fmaf(a.y, w1, fmaf(a.z, w2, fmaf(a.w, w3, acc[p]))));
            }
        }
        for (int u4 = 0; u4 < 32; u4 += 4) {
            float w0 = W_sc_v[(u4 + 0) * MUL1 + v];
            float w1 = W_sc_v[(u4 + 1) * MUL1 + v];
            float w2 = W_sc_v[(u4 + 2) * MUL1 + v];
            float w3 = W_sc_v[(u4 + 3) * MUL1 + v];
            #pragma unroll
            for (int p = 0; p < 4; ++p) {
                int q = p * 2 + np;
                int nq = n0 + (q < nv ? q : 0);
                const float* ip = node_input + (size_t)nq * NODE_F + 64 + d;
                scc[p] = fmaf(ip[3 * (u4 + 0)], w0,
                         fmaf(ip[3 * (u4 + 1)], w1,
                         fmaf(ip[3 * (u4 + 2)], w2,
                         fmaf(ip[3 * (u4 + 3)], w3, scc[p]))));
            }
        }
        #pragma unroll
        for (int p = 0; p < 4; ++p) {
            int q = p * 2 + np;
            float at = np ? attr[p * 2 + 1] : attr[p * 2];
            float c  = np ? cs[p * 2 + 1]   : cs[p * 2];
            float s  = np ? sn[p * 2 + 1]   : sn[p * 2];
            if (q < nv)
                out[(size_t)(n0 + q) * NODE_F + 64 + 3 * v + d] =
                    at * (c * (INV_SQRT32 * scc[p]) + s * (pre * acc[p]));
        }
    }
}

extern "C" void kernel_launch(void* const* d_in, const int* in_sizes, int n_in,
                              void* d_out, int out_size, void* d_ws, size_t ws_size,
                              hipStream_t stream)
{
    const float* node_input   = (const float*)d_in[0];
    const float* node_attr    = (const float*)d_in[1];
    const float* edge_attr    = (const float*)d_in[2];
    const float* edge_scalars = (const float*)d_in[3];
    const float* W_sc_s       = (const float*)d_in[4];
    const float* W_sc_v       = (const float*)d_in[5];
    const float* W1_s         = (const float*)d_in[6];
    const float* W1_v         = (const float*)d_in[7];
    const float* W2_s         = (const float*)d_in[8];
    const float* W2_v         = (const float*)d_in[9];
    const float* W3           = (const float*)d_in[10];
    const float* fcW1         = (const float*)d_in[11];
    const float* fcW2         = (const float*)d_in[12];
    const int*   edge_src     = (const int*)d_in[13];
    const int*   edge_dst     = (const int*)d_in[14];
    float* out = (float*)d_out;

    const int N = in_sizes[1];
    const int E = in_sizes[13];

    // ---- workspace layout ----
    char* p = (char*)d_ws;
    float* agg = (float*)p;  p += (size_t)N * AGG_F * sizeof(float);
    int*   deg = (int*)p;    p += (size_t)N * sizeof(int);
    int*   cur = (int*)p;    p += (size_t)N * sizeof(int);
    int*   csr = (int*)p;    p += (size_t)E * sizeof(int);
    int*   off = (int*)p;    p += (size_t)(N + 1) * sizeof(int);

    float* f = out;   // f lives in d_out, overwritten by k_out at the end

    hipMemsetAsync(deg, 0, (size_t)N * sizeof(int), stream);
    hipMemsetAsync(agg, 0, (size_t)N * AGG_F * sizeof(float), stream);

    int eb = (E + 255) / 256;
    k_count<<<eb, 256, 0, stream>>>(edge_dst, deg, E);
    k_scan<<<1, 1024, 0, stream>>>(deg, off, cur, N);
    k_scatter<<<eb, 256, 0, stream>>>(edge_dst, cur, csr, E);

    int ngroups = (N + 7) / 8;                       // waves
    int gridN = (ngroups + 3) / 4;                   // 4 waves/block
    k_node_lin<<<gridN, 256, 0, stream>>>(node_input, node_attr, W1_s, W1_v, f, N);

    int nwt = (E + 15) / 16;
    int gridF = (nwt + 3) / 4;
    if (gridF > 1536) gridF = 1536;
    k_edge_fused<<<gridF, 256, 0, stream>>>(f, edge_scalars, edge_attr, fcW1, fcW2,
                                            edge_src, edge_dst, csr, agg, E);

    k_out<<<gridN, 256, 0, stream>>>(node_input, node_attr, agg,
                                     W_sc_s, W_sc_v, W2_s, W2_v, W3, out, N);
}

// Round 9
// 358.720 us; speedup vs baseline: 5.1890x; 1.1047x over previous
//
#include <hip/hip_runtime.h>
#include <math.h>

#define MUL0 64
#define MUL1 32
#define RADF 8
#define HIDF 64
#define WNUM 192
#define NODE_F 160   // 64 + 96
#define AGG_F  384   // A(64) | D(32) | mv_d0(96) | mv_d1(96) | mv_d2(96)

#define INV_SQRT64 0.125f
#define INV_SQRT32 0.17677669529663687f
#define INV_SQRT8  0.35355339059327373f
#define INV_SQRT96 0.10206207261596575f
#define INV_SQRT10 0.31622776601683794f
#define INV_SQRT3  0.5773502691896258f

typedef __attribute__((ext_vector_type(8))) short bf16x8;
typedef __attribute__((ext_vector_type(4))) float f32x4;

__device__ __forceinline__ float bf2f(unsigned short u) {
    return __uint_as_float((unsigned)u << 16);
}
__device__ __forceinline__ unsigned short f2bfu(float x) {
    unsigned ua = __float_as_uint(x);
    return (unsigned short)((ua + 0x7FFF + ((ua >> 16) & 1)) >> 16);
}
__device__ __forceinline__ unsigned bf16pack(float a, float b) {
    unsigned ua = __float_as_uint(a);
    unsigned ub = __float_as_uint(b);
    ua = (ua + 0x7FFF + ((ua >> 16) & 1)) >> 16;
    ub = (ub + 0x7FFF + ((ub >> 16) & 1)) >> 16;
    return ua | (ub << 16);
}
__device__ __forceinline__ int rdlane(int v, int i) {
    return __builtin_amdgcn_readlane(v, i);
}
__device__ __forceinline__ float rdlanef(float v, int i) {
    return __int_as_float(__builtin_amdgcn_readlane(__float_as_int(v), i));
}

// ---------------- kernel: f = _lin(...), wave per 8 nodes, LDS weights ----------------
// f layout: [n][0:64]=s ; [n][64 + d*32 + u] = v[u][d]
__global__ __launch_bounds__(256) void k_node_lin(
    const float* __restrict__ node_input,
    const float* __restrict__ node_attr,
    const float* __restrict__ W1_s,
    const float* __restrict__ W1_v,
    float* __restrict__ f, int N)
{
    __shared__ float s_ws[64 * 64];   // 16 KB
    __shared__ float s_wv[32 * 32];   //  4 KB
    int tid = threadIdx.x;
    for (int i = tid; i < 64 * 64; i += 256) s_ws[i] = W1_s[i];
    for (int i = tid; i < 32 * 32; i += 256) s_wv[i] = W1_v[i];
    __syncthreads();

    int lane = tid & 63;
    int wv = tid >> 6;
    int v = lane & 31, np = lane >> 5;
    int ngrp = (N + 7) >> 3;

    for (int grp = blockIdx.x * 4 + wv; grp < ngrp; grp += gridDim.x * 4) {
        int n0 = grp * 8;
        int nv = min(8, N - n0);

        float attr[8];
        #pragma unroll
        for (int q = 0; q < 8; ++q)
            attr[q] = node_attr[n0 + (q < nv ? q : 0)];

        // ---- s-part: lane = channel c ----
        {
            float acc[8] = {0,0,0,0,0,0,0,0};
            #pragma unroll 2
            for (int u4 = 0; u4 < 64; u4 += 4) {
                float w0 = s_ws[(u4 + 0) * MUL0 + lane];
                float w1 = s_ws[(u4 + 1) * MUL0 + lane];
                float w2 = s_ws[(u4 + 2) * MUL0 + lane];
                float w3 = s_ws[(u4 + 3) * MUL0 + lane];
                #pragma unroll
                for (int q = 0; q < 8; ++q) {
                    int nq = n0 + (q < nv ? q : 0);
                    float4 a = *(const float4*)&node_input[(size_t)nq * NODE_F + u4];
                    acc[q] = fmaf(a.x, w0, fmaf(a.y, w1, fmaf(a.z, w2, fmaf(a.w, w3, acc[q]))));
                }
            }
            #pragma unroll
            for (int q = 0; q < 8; ++q)
                if (q < nv)
                    f[(size_t)(n0 + q) * NODE_F + lane] = acc[q] * attr[q] * INV_SQRT64;
        }

        // ---- v-part: half-wave = 32 channels x 2 node-slots, d outer ----
        #pragma unroll
        for (int d = 0; d < 3; ++d) {
            float vacc[4] = {0,0,0,0};
            #pragma unroll 2
            for (int u4 = 0; u4 < 32; u4 += 4) {
                float w0 = s_wv[(u4 + 0) * MUL1 + v];
                float w1 = s_wv[(u4 + 1) * MUL1 + v];
                float w2 = s_wv[(u4 + 2) * MUL1 + v];
                float w3 = s_wv[(u4 + 3) * MUL1 + v];
                #pragma unroll
                for (int p = 0; p < 4; ++p) {
                    int q = p * 2 + np;
                    int nq = n0 + (q < nv ? q : 0);
                    const float* ip = node_input + (size_t)nq * NODE_F + 64 + d;
                    vacc[p] = fmaf(ip[3 * (u4 + 0)], w0,
                              fmaf(ip[3 * (u4 + 1)], w1,
                              fmaf(ip[3 * (u4 + 2)], w2,
                              fmaf(ip[3 * (u4 + 3)], w3, vacc[p]))));
                }
            }
            #pragma unroll
            for (int p = 0; p < 4; ++p) {
                int q = p * 2 + np;
                float at = np ? attr[p * 2 + 1] : attr[p * 2];
                if (q < nv)
                    f[(size_t)(n0 + q) * NODE_F + 64 + d * 32 + v] = vacc[p] * at * INV_SQRT32;
            }
        }
    }
}

// ---------------- CSR build ----------------
__global__ void k_count(const int* __restrict__ edge_dst, int* deg, int E)
{
    int e = blockIdx.x * blockDim.x + threadIdx.x;
    if (e < E) atomicAdd(&deg[edge_dst[e]], 1);
}

__global__ __launch_bounds__(1024) void k_scan(const int* __restrict__ deg,
                                               int* __restrict__ off,
                                               int* __restrict__ cur, int N)
{
    __shared__ int swsum[16];
    __shared__ int swoff[16];
    __shared__ int sbase;
    __shared__ int stotal;
    int lane = threadIdx.x & 63, wid = threadIdx.x >> 6;
    if (threadIdx.x == 0) sbase = 0;
    __syncthreads();
    int ngroups = N >> 2;
    for (int base = 0; base < ngroups; base += 1024) {
        int g = base + threadIdx.x;
        int4 v = make_int4(0, 0, 0, 0);
        if (g < ngroups) v = ((const int4*)deg)[g];
        int s = v.x + v.y + v.z + v.w;
        int val = s;
        #pragma unroll
        for (int sh = 1; sh < 64; sh <<= 1) {
            int t = __shfl_up(val, sh);
            if (lane >= sh) val += t;
        }
        if (lane == 63) swsum[wid] = val;
        __syncthreads();
        if (threadIdx.x < 16) {
            int x = swsum[threadIdx.x];
            int xv = x;
            #pragma unroll
            for (int sh = 1; sh < 16; sh <<= 1) {
                int t = __shfl_up(xv, sh);
                if ((int)threadIdx.x >= sh) xv += t;
            }
            swoff[threadIdx.x] = xv - x;
            if (threadIdx.x == 15) stotal = xv;
        }
        __syncthreads();
        if (g < ngroups) {
            int b = sbase + swoff[wid] + (val - s);
            int4 o;
            o.x = b; o.y = b + v.x; o.z = o.y + v.y; o.w = o.z + v.z;
            ((int4*)off)[g] = o;
            ((int4*)cur)[g] = o;
        }
        __syncthreads();
        if (threadIdx.x == 0) sbase += stotal;
        __syncthreads();
    }
    if (threadIdx.x == 0) {
        int b = sbase;
        for (int i = (ngroups << 2); i < N; ++i) { off[i] = b; cur[i] = b; b += deg[i]; }
        off[N] = b;
    }
}

__global__ void k_scatter(const int* __restrict__ edge_dst,
                          int* cur, int* __restrict__ csr, int E)
{
    int e = blockIdx.x * blockDim.x + threadIdx.x;
    if (e < E) {
        int d = edge_dst[e];
        int pos = atomicAdd(&cur[d], 1);
        csr[pos] = e;
    }
}

// ---------------- fused edge kernel: per-wave 16-edge tiles, barrier-free ----------------
#define FLUSH_AGG(node)                                              \
    do {                                                             \
        float* an = agg + (size_t)(node) * AGG_F;                    \
        atomicAdd(&an[lane], accA);                                  \
        atomicAdd(&an[96  + lane], accB0);                           \
        atomicAdd(&an[192 + lane], accB1);                           \
        atomicAdd(&an[288 + lane], accB2);                           \
        if (lane < 32) {                                             \
            atomicAdd(&an[160 + u], accX0);                          \
            atomicAdd(&an[256 + u], accX1);                          \
            atomicAdd(&an[352 + u], accX2);                          \
        } else {                                                     \
            atomicAdd(&an[64 + u], accX0);                           \
        }                                                            \
    } while (0)

__global__ __launch_bounds__(256, 3) void k_edge_fused(
    const float* __restrict__ f,
    const float* __restrict__ edge_scalars,
    const float* __restrict__ edge_attr,
    const float* __restrict__ fcW1,
    const float* __restrict__ fcW2,
    const int* __restrict__ edge_src,
    const int* __restrict__ edge_dst,
    const int* __restrict__ csr,
    float* agg, int E)
{
    __shared__ unsigned short s_w2t[8 * 192 * 8];   // 24576 B
    __shared__ unsigned short s_w[4][16 * 216];     // 27648 B
    __shared__ float s_fcW1[512];                   //  2048 B

    int tid  = threadIdx.x;
    int lane = tid & 63;
    int wv   = tid >> 6;
    int l15  = lane & 15, lh = lane >> 4;
    int u    = lane & 31;

    for (int task = tid; task < 1536; task += 256) {
        int col = task % 192, oct = task / 192;
        const float* wp = fcW2 + (size_t)(oct * 8) * WNUM + col;
        unsigned pk0 = bf16pack(wp[0 * WNUM], wp[1 * WNUM]);
        unsigned pk1 = bf16pack(wp[2 * WNUM], wp[3 * WNUM]);
        unsigned pk2 = bf16pack(wp[4 * WNUM], wp[5 * WNUM]);
        unsigned pk3 = bf16pack(wp[6 * WNUM], wp[7 * WNUM]);
        *(uint4*)&s_w2t[oct * 1536 + col * 8] = make_uint4(pk0, pk1, pk2, pk3);
    }
    for (int i = tid; i < 512; i += 256)
        s_fcW1[i] = fcW1[i];
    __syncthreads();      // the only block barrier

    unsigned short* sw = s_w[wv];
    int nwt = (E + 15) >> 4;

    for (int wt = blockIdx.x * 4 + wv; wt < nwt; wt += gridDim.x * 4) {
        int P = wt << 4;
        int m = min(16, E - P);

        int el  = P + min(l15, m - 1);
        int e   = csr[el];
        int src = edge_src[e];
        int dst = edge_dst[e];
        float4 ea = *(const float4*)(edge_attr + (size_t)e * 4);
        const float4* esp = (const float4*)(edge_scalars + (size_t)e * RADF);
        float4 es0 = esp[0], es1 = esp[1];

        float xs[16], xv0[16], xv1[16], xv2[16];
        #pragma unroll
        for (int i = 0; i < 16; ++i) {
            int si = rdlane(src, i);
            const float* fb = f + (size_t)si * NODE_F;
            xs[i]  = fb[lane];
            xv0[i] = fb[64 + u];
            xv1[i] = fb[96 + u];
            xv2[i] = fb[128 + u];
        }

        float es[8] = {es0.x, es0.y, es0.z, es0.w, es1.x, es1.y, es1.z, es1.w};
        union { unsigned q[4]; bf16x8 v; } A0, A1;
        #pragma unroll
        for (int jp = 0; jp < 4; ++jp) {
            int k0 = lh * 8 + 2 * jp;
            float aL0 = 0.f, aL1 = 0.f, aH0 = 0.f, aH1 = 0.f;
            #pragma unroll
            for (int r = 0; r < 8; ++r) {
                float2 wl = *(const float2*)&s_fcW1[r * 64 + k0];
                float2 wh = *(const float2*)&s_fcW1[r * 64 + 32 + k0];
                aL0 = fmaf(es[r], wl.x, aL0);
                aL1 = fmaf(es[r], wl.y, aL1);
                aH0 = fmaf(es[r], wh.x, aH0);
                aH1 = fmaf(es[r], wh.y, aH1);
            }
            aL0 *= INV_SQRT8; aL1 *= INV_SQRT8; aH0 *= INV_SQRT8; aH1 *= INV_SQRT8;
            aL0 = aL0 / (1.f + __expf(-aL0));
            aL1 = aL1 / (1.f + __expf(-aL1));
            aH0 = aH0 / (1.f + __expf(-aH0));
            aH1 = aH1 / (1.f + __expf(-aH1));
            A0.q[jp] = bf16pack(aL0, aL1);
            A1.q[jp] = bf16pack(aH0, aH1);
        }

        #pragma unroll
        for (int cb = 0; cb < 12; ++cb) {
            bf16x8 b0 = *(const bf16x8*)&s_w2t[ lh      * 1536 + (cb * 16 + l15) * 8];
            bf16x8 b1 = *(const bf16x8*)&s_w2t[(4 + lh) * 1536 + (cb * 16 + l15) * 8];
            f32x4 acc = {0.f, 0.f, 0.f, 0.f};
            acc = __builtin_amdgcn_mfma_f32_16x16x32_bf16(A0.v, b0, acc, 0, 0, 0);
            acc = __builtin_amdgcn_mfma_f32_16x16x32_bf16(A1.v, b1, acc, 0, 0, 0);
            #pragma unroll
            for (int r = 0; r < 4; ++r)
                sw[(lh * 4 + r) * 216 + cb * 16 + l15] = f2bfu(acc[r] * INV_SQRT64);
        }

        float accA = 0.f, accB0 = 0.f, accB1 = 0.f, accB2 = 0.f;
        float accX0 = 0.f, accX1 = 0.f, accX2 = 0.f;
        int curd = rdlane(dst, 0);
        #pragma unroll
        for (int i = 0; i < 16; ++i) {
            if (i < m) {
                int di = rdlane(dst, i);
                if (di != curd) {
                    FLUSH_AGG(curd);
                    accA = accB0 = accB1 = accB2 = 0.f;
                    accX0 = accX1 = accX2 = 0.f;
                    curd = di;
                }
                float eax = rdlanef(ea.x, i);
                float eay = rdlanef(ea.y, i);
                float eaz = rdlanef(ea.z, i);
                float eaw = rdlanef(ea.w, i);
                float W0 = bf2f(sw[i * 216 + lane]);
                float W1 = bf2f(sw[i * 216 + 64 + lane]);
                float W2 = bf2f(sw[i * 216 + 128 + lane]);
                accA = fmaf(W0 * xs[i], eax, accA);
                float bx = W1 * xs[i];
                accB0 = fmaf(bx, eay, accB0);
                accB1 = fmaf(bx, eaz, accB1);
                accB2 = fmaf(bx, eaw, accB2);
                if (lane < 32) {
                    float cc = W2 * eax;
                    accX0 = fmaf(cc, xv0[i], accX0);
                    accX1 = fmaf(cc, xv1[i], accX1);
                    accX2 = fmaf(cc, xv2[i], accX2);
                } else {
                    float dv = xv0[i] * eay + xv1[i] * eaz + xv2[i] * eaw;
                    accX0 = fmaf(W2 * INV_SQRT3, dv, accX0);
                }
            }
        }
        FLUSH_AGG(curd);
    }
}

// ---------------- kernel: output combine, wave per 8 nodes, LDS weights ----------------
__global__ __launch_bounds__(256) void k_out(
    const float* __restrict__ node_input,
    const float* __restrict__ node_attr,
    const float* __restrict__ agg,
    const float* __restrict__ W_sc_s,
    const float* __restrict__ W_sc_v,
    const float* __restrict__ W2_s,
    const float* __restrict__ W2_v,
    const float* __restrict__ W3,
    float* __restrict__ out, int N)
{
    __shared__ float s_w2s[96 * 64];   // 24.5 KB
    __shared__ float s_wss[64 * 64];   // 16 KB
    __shared__ float s_w2v[96 * 32];   // 12 KB
    __shared__ float s_wsv[32 * 32];   //  4 KB
    __shared__ float s_w3[96];         // 0.4 KB -> total 57.3 KB, 2 blocks/CU

    int tid = threadIdx.x;
    for (int i = tid; i < 96 * 64; i += 256) s_w2s[i] = W2_s[i];
    for (int i = tid; i < 64 * 64; i += 256) s_wss[i] = W_sc_s[i];
    for (int i = tid; i < 96 * 32; i += 256) s_w2v[i] = W2_v[i];
    for (int i = tid; i < 32 * 32; i += 256) s_wsv[i] = W_sc_v[i];
    if (tid < 96) s_w3[tid] = W3[tid];
    __syncthreads();

    int lane = tid & 63;
    int wv = tid >> 6;
    int v = lane & 31, np = lane >> 5;
    const float pre = INV_SQRT10 * INV_SQRT96;
    int ngrp = (N + 7) >> 3;

    float w3a = s_w3[lane];
    float w3b = (lane < 32) ? s_w3[64 + lane] : 0.f;

    for (int grp = blockIdx.x * 4 + wv; grp < ngrp; grp += gridDim.x * 4) {
        int n0 = grp * 8;
        int nv = min(8, N - n0);

        // ---- per-node attr + angle (lane-parallel dot + wave reduce) ----
        float attr[8], cs[8], sn[8];
        #pragma unroll
        for (int q = 0; q < 8; ++q) {
            int nq = n0 + (q < nv ? q : 0);
            attr[q] = node_attr[nq];
            const float* ag = agg + (size_t)nq * AGG_F;
            float pa = ag[lane] * w3a;
            if (lane < 32) pa = fmaf(ag[64 + lane], w3b, pa);
            #pragma unroll
            for (int s = 32; s >= 1; s >>= 1)
                pa += __shfl_xor(pa, s);
            float ang = 0.1f * pre * attr[q] * pa;
            cs[q] = cosf(ang);
            sn[q] = sinf(ang);
        }

        // ---- s-part: lane = channel ----
        {
            float acc[8] = {0,0,0,0,0,0,0,0};
            float scc[8] = {0,0,0,0,0,0,0,0};
            #pragma unroll 2
            for (int j4 = 0; j4 < 96; j4 += 4) {
                float w0 = s_w2s[(j4 + 0) * MUL0 + lane];
                float w1 = s_w2s[(j4 + 1) * MUL0 + lane];
                float w2 = s_w2s[(j4 + 2) * MUL0 + lane];
                float w3 = s_w2s[(j4 + 3) * MUL0 + lane];
                #pragma unroll
                for (int q = 0; q < 8; ++q) {
                    int nq = n0 + (q < nv ? q : 0);
                    float4 a = *(const float4*)&agg[(size_t)nq * AGG_F + j4];
                    acc[q] = fmaf(a.x, w0, fmaf(a.y, w1, fmaf(a.z, w2, fmaf(a.w, w3, acc[q]))));
                }
            }
            #pragma unroll 2
            for (int u4 = 0; u4 < 64; u4 += 4) {
                float w0 = s_wss[(u4 + 0) * MUL0 + lane];
                float w1 = s_wss[(u4 + 1) * MUL0 + lane];
                float w2 = s_wss[(u4 + 2) * MUL0 + lane];
                float w3 = s_wss[(u4 + 3) * MUL0 + lane];
                #pragma unroll
                for (int q = 0; q < 8; ++q) {
                    int nq = n0 + (q < nv ? q : 0);
                    float4 b = *(const float4*)&node_input[(size_t)nq * NODE_F + u4];
                    scc[q] = fmaf(b.x, w0, fmaf(b.y, w1, fmaf(b.z, w2, fmaf(b.w, w3, scc[q]))));
                }
            }
            #pragma unroll
            for (int q = 0; q < 8; ++q)
                if (q < nv)
                    out[(size_t)(n0 + q) * NODE_F + lane] =
                        attr[q] * (cs[q] * (INV_SQRT64 * scc[q]) + sn[q] * (pre * acc[q]));
        }

        // ---- v-part: half-wave = 32 channels x 2 node-slots, d outer ----
        #pragma unroll
        for (int d = 0; d < 3; ++d) {
            float acc[4] = {0,0,0,0};
            float scc[4] = {0,0,0,0};
            int agoff = 96 + d * 96;
            #pragma unroll 2
            for (int j4 = 0; j4 < 96; j4 += 4) {
                float w0 = s_w2v[(j4 + 0) * MUL1 + v];
                float w1 = s_w2v[(j4 + 1) * MUL1 + v];
                float w2 = s_w2v[(j4 + 2) * MUL1 + v];
                float w3 = s_w2v[(j4 + 3) * MUL1 + v];
                #pragma unroll
                for (int p = 0; p < 4; ++p) {
                    int q = p * 2 + np;
                    int nq = n0 + (q < nv ? q : 0);
                    float4 a = *(const float4*)&agg[(size_t)nq * AGG_F + agoff + j4];
                    acc[p] = fmaf(a.x, w0, fmaf(a.y, w1, fmaf(a.z, w2, fmaf(a.w, w3, acc[p]))));
                }
            }
            #pragma unroll 2
            for (int u4 = 0; u4 < 32; u4 += 4) {
                float w0 = s_wsv[(u4 + 0) * MUL1 + v];
                float w1 = s_wsv[(u4 + 1) * MUL1 + v];
                float w2 = s_wsv[(u4 + 2) * MUL1 + v];
                float w3 = s_wsv[(u4 + 3) * MUL1 + v];
                #pragma unroll
                for (int p = 0; p < 4; ++p) {
                    int q = p * 2 + np;
                    int nq = n0 + (q < nv ? q : 0);
                    const float* ip = node_input + (size_t)nq * NODE_F + 64 + d;
                    scc[p] = fmaf(ip[3 * (u4 + 0)], w0,
                             fmaf(ip[3 * (u4 + 1)], w1,
                             fmaf(ip[3 * (u4 + 2)], w2,
                             fmaf(ip[3 * (u4 + 3)], w3, scc[p]))));
                }
            }
            #pragma unroll
            for (int p = 0; p < 4; ++p) {
                int q = p * 2 + np;
                float at = np ? attr[p * 2 + 1] : attr[p * 2];
                float c  = np ? cs[p * 2 + 1]   : cs[p * 2];
                float s  = np ? sn[p * 2 + 1]   : sn[p * 2];
                if (q < nv)
                    out[(size_t)(n0 + q) * NODE_F + 64 + 3 * v + d] =
                        at * (c * (INV_SQRT32 * scc[p]) + s * (pre * acc[p]));
            }
        }
    }
}

extern "C" void kernel_launch(void* const* d_in, const int* in_sizes, int n_in,
                              void* d_out, int out_size, void* d_ws, size_t ws_size,
                              hipStream_t stream)
{
    const float* node_input   = (const float*)d_in[0];
    const float* node_attr    = (const float*)d_in[1];
    const float* edge_attr    = (const float*)d_in[2];
    const float* edge_scalars = (const float*)d_in[3];
    const float* W_sc_s       = (const float*)d_in[4];
    const float* W_sc_v       = (const float*)d_in[5];
    const float* W1_s         = (const float*)d_in[6];
    const float* W1_v         = (const float*)d_in[7];
    const float* W2_s         = (const float*)d_in[8];
    const float* W2_v         = (const float*)d_in[9];
    const float* W3           = (const float*)d_in[10];
    const float* fcW1         = (const float*)d_in[11];
    const float* fcW2         = (const float*)d_in[12];
    const int*   edge_src     = (const int*)d_in[13];
    const int*   edge_dst     = (const int*)d_in[14];
    float* out = (float*)d_out;

    const int N = in_sizes[1];
    const int E = in_sizes[13];

    // ---- workspace layout ----
    char* p = (char*)d_ws;
    float* agg = (float*)p;  p += (size_t)N * AGG_F * sizeof(float);
    int*   deg = (int*)p;    p += (size_t)N * sizeof(int);
    int*   cur = (int*)p;    p += (size_t)N * sizeof(int);
    int*   csr = (int*)p;    p += (size_t)E * sizeof(int);
    int*   off = (int*)p;    p += (size_t)(N + 1) * sizeof(int);

    float* f = out;   // f lives in d_out, overwritten by k_out at the end

    hipMemsetAsync(deg, 0, (size_t)N * sizeof(int), stream);
    hipMemsetAsync(agg, 0, (size_t)N * AGG_F * sizeof(float), stream);

    int eb = (E + 255) / 256;
    k_count<<<eb, 256, 0, stream>>>(edge_dst, deg, E);
    k_scan<<<1, 1024, 0, stream>>>(deg, off, cur, N);
    k_scatter<<<eb, 256, 0, stream>>>(edge_dst, cur, csr, E);

    k_node_lin<<<768, 256, 0, stream>>>(node_input, node_attr, W1_s, W1_v, f, N);

    int nwt = (E + 15) / 16;
    int gridF = (nwt + 3) / 4;
    if (gridF > 1536) gridF = 1536;
    k_edge_fused<<<gridF, 256, 0, stream>>>(f, edge_scalars, edge_attr, fcW1, fcW2,
                                            edge_src, edge_dst, csr, agg, E);

    k_out<<<512, 256, 0, stream>>>(node_input, node_attr, agg,
                                   W_sc_s, W_sc_v, W2_s, W2_v, W3, out, N);
}

// Round 10
// 269.872 us; speedup vs baseline: 6.8973x; 1.3292x over previous
//
#include <hip/hip_runtime.h>
#include <math.h>

#define MUL0 64
#define MUL1 32
#define RADF 8
#define HIDF 64
#define WNUM 192
#define NODE_F 160   // 64 + 96
#define AGG_F  384   // A(64) | D(32) | mv_d0(96) | mv_d1(96) | mv_d2(96)

#define INV_SQRT64 0.125f
#define INV_SQRT32 0.17677669529663687f
#define INV_SQRT8  0.35355339059327373f
#define INV_SQRT96 0.10206207261596575f
#define INV_SQRT10 0.31622776601683794f
#define INV_SQRT3  0.5773502691896258f

typedef __attribute__((ext_vector_type(8))) short bf16x8;
typedef __attribute__((ext_vector_type(4))) float f32x4;

__device__ __forceinline__ float bf2f(unsigned short u) {
    return __uint_as_float((unsigned)u << 16);
}
__device__ __forceinline__ unsigned short f2bfu(float x) {
    unsigned ua = __float_as_uint(x);
    return (unsigned short)((ua + 0x7FFF + ((ua >> 16) & 1)) >> 16);
}
__device__ __forceinline__ unsigned bf16pack(float a, float b) {
    unsigned ua = __float_as_uint(a);
    unsigned ub = __float_as_uint(b);
    ua = (ua + 0x7FFF + ((ua >> 16) & 1)) >> 16;
    ub = (ub + 0x7FFF + ((ub >> 16) & 1)) >> 16;
    return ua | (ub << 16);
}
__device__ __forceinline__ int rdlane(int v, int i) {
    return __builtin_amdgcn_readlane(v, i);
}
__device__ __forceinline__ float rdlanef(float v, int i) {
    return __int_as_float(__builtin_amdgcn_readlane(__float_as_int(v), i));
}
__device__ __forceinline__ bf16x8 cvt8(float4 a, float4 b) {
    union { unsigned q[4]; bf16x8 v; } r;
    r.q[0] = bf16pack(a.x, a.y);
    r.q[1] = bf16pack(a.z, a.w);
    r.q[2] = bf16pack(b.x, b.y);
    r.q[3] = bf16pack(b.z, b.w);
    return r.v;
}

// ---------------- kernel: f = _lin(...), wave per 8 nodes, LDS weights ----------------
// f layout: [n][0:64]=s ; [n][64 + d*32 + u] = v[u][d]
__global__ __launch_bounds__(256) void k_node_lin(
    const float* __restrict__ node_input,
    const float* __restrict__ node_attr,
    const float* __restrict__ W1_s,
    const float* __restrict__ W1_v,
    float* __restrict__ f, int N)
{
    __shared__ float s_ws[64 * 64];   // 16 KB
    __shared__ float s_wv[32 * 32];   //  4 KB
    int tid = threadIdx.x;
    for (int i = tid; i < 64 * 64; i += 256) s_ws[i] = W1_s[i];
    for (int i = tid; i < 32 * 32; i += 256) s_wv[i] = W1_v[i];
    __syncthreads();

    int lane = tid & 63;
    int wv = tid >> 6;
    int v = lane & 31, np = lane >> 5;
    int ngrp = (N + 7) >> 3;

    for (int grp = blockIdx.x * 4 + wv; grp < ngrp; grp += gridDim.x * 4) {
        int n0 = grp * 8;
        int nv = min(8, N - n0);

        float attr[8];
        #pragma unroll
        for (int q = 0; q < 8; ++q)
            attr[q] = node_attr[n0 + (q < nv ? q : 0)];

        // ---- s-part: lane = channel c ----
        {
            float acc[8] = {0,0,0,0,0,0,0,0};
            #pragma unroll 2
            for (int u4 = 0; u4 < 64; u4 += 4) {
                float w0 = s_ws[(u4 + 0) * MUL0 + lane];
                float w1 = s_ws[(u4 + 1) * MUL0 + lane];
                float w2 = s_ws[(u4 + 2) * MUL0 + lane];
                float w3 = s_ws[(u4 + 3) * MUL0 + lane];
                #pragma unroll
                for (int q = 0; q < 8; ++q) {
                    int nq = n0 + (q < nv ? q : 0);
                    float4 a = *(const float4*)&node_input[(size_t)nq * NODE_F + u4];
                    acc[q] = fmaf(a.x, w0, fmaf(a.y, w1, fmaf(a.z, w2, fmaf(a.w, w3, acc[q]))));
                }
            }
            #pragma unroll
            for (int q = 0; q < 8; ++q)
                if (q < nv)
                    f[(size_t)(n0 + q) * NODE_F + lane] = acc[q] * attr[q] * INV_SQRT64;
        }

        // ---- v-part: half-wave = 32 channels x 2 node-slots, d outer ----
        #pragma unroll
        for (int d = 0; d < 3; ++d) {
            float vacc[4] = {0,0,0,0};
            #pragma unroll 2
            for (int u4 = 0; u4 < 32; u4 += 4) {
                float w0 = s_wv[(u4 + 0) * MUL1 + v];
                float w1 = s_wv[(u4 + 1) * MUL1 + v];
                float w2 = s_wv[(u4 + 2) * MUL1 + v];
                float w3 = s_wv[(u4 + 3) * MUL1 + v];
                #pragma unroll
                for (int p = 0; p < 4; ++p) {
                    int q = p * 2 + np;
                    int nq = n0 + (q < nv ? q : 0);
                    const float* ip = node_input + (size_t)nq * NODE_F + 64 + d;
                    vacc[p] = fmaf(ip[3 * (u4 + 0)], w0,
                              fmaf(ip[3 * (u4 + 1)], w1,
                              fmaf(ip[3 * (u4 + 2)], w2,
                              fmaf(ip[3 * (u4 + 3)], w3, vacc[p]))));
                }
            }
            #pragma unroll
            for (int p = 0; p < 4; ++p) {
                int q = p * 2 + np;
                float at = np ? attr[p * 2 + 1] : attr[p * 2];
                if (q < nv)
                    f[(size_t)(n0 + q) * NODE_F + 64 + d * 32 + v] = vacc[p] * at * INV_SQRT32;
            }
        }
    }
}

// ---------------- CSR build ----------------
__global__ void k_count(const int* __restrict__ edge_dst, int* deg, int E)
{
    int e = blockIdx.x * blockDim.x + threadIdx.x;
    if (e < E) atomicAdd(&deg[edge_dst[e]], 1);
}

__global__ __launch_bounds__(1024) void k_scan(const int* __restrict__ deg,
                                               int* __restrict__ off,
                                               int* __restrict__ cur, int N)
{
    __shared__ int swsum[16];
    __shared__ int swoff[16];
    __shared__ int sbase;
    __shared__ int stotal;
    int lane = threadIdx.x & 63, wid = threadIdx.x >> 6;
    if (threadIdx.x == 0) sbase = 0;
    __syncthreads();
    int ngroups = N >> 2;
    for (int base = 0; base < ngroups; base += 1024) {
        int g = base + threadIdx.x;
        int4 v = make_int4(0, 0, 0, 0);
        if (g < ngroups) v = ((const int4*)deg)[g];
        int s = v.x + v.y + v.z + v.w;
        int val = s;
        #pragma unroll
        for (int sh = 1; sh < 64; sh <<= 1) {
            int t = __shfl_up(val, sh);
            if (lane >= sh) val += t;
        }
        if (lane == 63) swsum[wid] = val;
        __syncthreads();
        if (threadIdx.x < 16) {
            int x = swsum[threadIdx.x];
            int xv = x;
            #pragma unroll
            for (int sh = 1; sh < 16; sh <<= 1) {
                int t = __shfl_up(xv, sh);
                if ((int)threadIdx.x >= sh) xv += t;
            }
            swoff[threadIdx.x] = xv - x;
            if (threadIdx.x == 15) stotal = xv;
        }
        __syncthreads();
        if (g < ngroups) {
            int b = sbase + swoff[wid] + (val - s);
            int4 o;
            o.x = b; o.y = b + v.x; o.z = o.y + v.y; o.w = o.z + v.z;
            ((int4*)off)[g] = o;
            ((int4*)cur)[g] = o;
        }
        __syncthreads();
        if (threadIdx.x == 0) sbase += stotal;
        __syncthreads();
    }
    if (threadIdx.x == 0) {
        int b = sbase;
        for (int i = (ngroups << 2); i < N; ++i) { off[i] = b; cur[i] = b; b += deg[i]; }
        off[N] = b;
    }
}

__global__ void k_scatter(const int* __restrict__ edge_dst,
                          int* cur, int* __restrict__ csr, int E)
{
    int e = blockIdx.x * blockDim.x + threadIdx.x;
    if (e < E) {
        int d = edge_dst[e];
        int pos = atomicAdd(&cur[d], 1);
        csr[pos] = e;
    }
}

// ---------------- fused edge kernel: per-wave 16-edge tiles, barrier-free ----------------
#define FLUSH_AGG(node)                                              \
    do {                                                             \
        float* an = agg + (size_t)(node) * AGG_F;                    \
        atomicAdd(&an[lane], accA);                                  \
        atomicAdd(&an[96  + lane], accB0);                           \
        atomicAdd(&an[192 + lane], accB1);                           \
        atomicAdd(&an[288 + lane], accB2);                           \
        if (lane < 32) {                                             \
            atomicAdd(&an[160 + u], accX0);                          \
            atomicAdd(&an[256 + u], accX1);                          \
            atomicAdd(&an[352 + u], accX2);                          \
        } else {                                                     \
            atomicAdd(&an[64 + u], accX0);                           \
        }                                                            \
    } while (0)

__global__ __launch_bounds__(256, 3) void k_edge_fused(
    const float* __restrict__ f,
    const float* __restrict__ edge_scalars,
    const float* __restrict__ edge_attr,
    const float* __restrict__ fcW1,
    const float* __restrict__ fcW2,
    const int* __restrict__ edge_src,
    const int* __restrict__ edge_dst,
    const int* __restrict__ csr,
    float* agg, int E)
{
    __shared__ unsigned short s_w2t[8 * 192 * 8];   // 24576 B
    __shared__ unsigned short s_w[4][16 * 216];     // 27648 B
    __shared__ float s_fcW1[512];                   //  2048 B

    int tid  = threadIdx.x;
    int lane = tid & 63;
    int wv   = tid >> 6;
    int l15  = lane & 15, lh = lane >> 4;
    int u    = lane & 31;

    for (int task = tid; task < 1536; task += 256) {
        int col = task % 192, oct = task / 192;
        const float* wp = fcW2 + (size_t)(oct * 8) * WNUM + col;
        unsigned pk0 = bf16pack(wp[0 * WNUM], wp[1 * WNUM]);
        unsigned pk1 = bf16pack(wp[2 * WNUM], wp[3 * WNUM]);
        unsigned pk2 = bf16pack(wp[4 * WNUM], wp[5 * WNUM]);
        unsigned pk3 = bf16pack(wp[6 * WNUM], wp[7 * WNUM]);
        *(uint4*)&s_w2t[oct * 1536 + col * 8] = make_uint4(pk0, pk1, pk2, pk3);
    }
    for (int i = tid; i < 512; i += 256)
        s_fcW1[i] = fcW1[i];
    __syncthreads();      // the only block barrier

    unsigned short* sw = s_w[wv];
    int nwt = (E + 15) >> 4;

    for (int wt = blockIdx.x * 4 + wv; wt < nwt; wt += gridDim.x * 4) {
        int P = wt << 4;
        int m = min(16, E - P);

        int el  = P + min(l15, m - 1);
        int e   = csr[el];
        int src = edge_src[e];
        int dst = edge_dst[e];
        float4 ea = *(const float4*)(edge_attr + (size_t)e * 4);
        const float4* esp = (const float4*)(edge_scalars + (size_t)e * RADF);
        float4 es0 = esp[0], es1 = esp[1];

        float xs[16], xv0[16], xv1[16], xv2[16];
        #pragma unroll
        for (int i = 0; i < 16; ++i) {
            int si = rdlane(src, i);
            const float* fb = f + (size_t)si * NODE_F;
            xs[i]  = fb[lane];
            xv0[i] = fb[64 + u];
            xv1[i] = fb[96 + u];
            xv2[i] = fb[128 + u];
        }

        float es[8] = {es0.x, es0.y, es0.z, es0.w, es1.x, es1.y, es1.z, es1.w};
        union { unsigned q[4]; bf16x8 v; } A0, A1;
        #pragma unroll
        for (int jp = 0; jp < 4; ++jp) {
            int k0 = lh * 8 + 2 * jp;
            float aL0 = 0.f, aL1 = 0.f, aH0 = 0.f, aH1 = 0.f;
            #pragma unroll
            for (int r = 0; r < 8; ++r) {
                float2 wl = *(const float2*)&s_fcW1[r * 64 + k0];
                float2 wh = *(const float2*)&s_fcW1[r * 64 + 32 + k0];
                aL0 = fmaf(es[r], wl.x, aL0);
                aL1 = fmaf(es[r], wl.y, aL1);
                aH0 = fmaf(es[r], wh.x, aH0);
                aH1 = fmaf(es[r], wh.y, aH1);
            }
            aL0 *= INV_SQRT8; aL1 *= INV_SQRT8; aH0 *= INV_SQRT8; aH1 *= INV_SQRT8;
            aL0 = aL0 / (1.f + __expf(-aL0));
            aL1 = aL1 / (1.f + __expf(-aL1));
            aH0 = aH0 / (1.f + __expf(-aH0));
            aH1 = aH1 / (1.f + __expf(-aH1));
            A0.q[jp] = bf16pack(aL0, aL1);
            A1.q[jp] = bf16pack(aH0, aH1);
        }

        #pragma unroll
        for (int cb = 0; cb < 12; ++cb) {
            bf16x8 b0 = *(const bf16x8*)&s_w2t[ lh      * 1536 + (cb * 16 + l15) * 8];
            bf16x8 b1 = *(const bf16x8*)&s_w2t[(4 + lh) * 1536 + (cb * 16 + l15) * 8];
            f32x4 acc = {0.f, 0.f, 0.f, 0.f};
            acc = __builtin_amdgcn_mfma_f32_16x16x32_bf16(A0.v, b0, acc, 0, 0, 0);
            acc = __builtin_amdgcn_mfma_f32_16x16x32_bf16(A1.v, b1, acc, 0, 0, 0);
            #pragma unroll
            for (int r = 0; r < 4; ++r)
                sw[(lh * 4 + r) * 216 + cb * 16 + l15] = f2bfu(acc[r] * INV_SQRT64);
        }

        float accA = 0.f, accB0 = 0.f, accB1 = 0.f, accB2 = 0.f;
        float accX0 = 0.f, accX1 = 0.f, accX2 = 0.f;
        int curd = rdlane(dst, 0);
        #pragma unroll
        for (int i = 0; i < 16; ++i) {
            if (i < m) {
                int di = rdlane(dst, i);
                if (di != curd) {
                    FLUSH_AGG(curd);
                    accA = accB0 = accB1 = accB2 = 0.f;
                    accX0 = accX1 = accX2 = 0.f;
                    curd = di;
                }
                float eax = rdlanef(ea.x, i);
                float eay = rdlanef(ea.y, i);
                float eaz = rdlanef(ea.z, i);
                float eaw = rdlanef(ea.w, i);
                float W0 = bf2f(sw[i * 216 + lane]);
                float W1 = bf2f(sw[i * 216 + 64 + lane]);
                float W2 = bf2f(sw[i * 216 + 128 + lane]);
                accA = fmaf(W0 * xs[i], eax, accA);
                float bx = W1 * xs[i];
                accB0 = fmaf(bx, eay, accB0);
                accB1 = fmaf(bx, eaz, accB1);
                accB2 = fmaf(bx, eaw, accB2);
                if (lane < 32) {
                    float cc = W2 * eax;
                    accX0 = fmaf(cc, xv0[i], accX0);
                    accX1 = fmaf(cc, xv1[i], accX1);
                    accX2 = fmaf(cc, xv2[i], accX2);
                } else {
                    float dv = xv0[i] * eay + xv1[i] * eaz + xv2[i] * eaw;
                    accX0 = fmaf(W2 * INV_SQRT3, dv, accX0);
                }
            }
        }
        FLUSH_AGG(curd);
    }
}

// ---------------- kernel: output combine via MFMA, wave per 16 nodes ----------------
// LDS B-matrices (bf16, k-oct-major, norm constants folded):
//  s_w2s [12][64][8] : W2_s * pre        s_wss [8][64][8] : W_sc_s * 1/sqrt(64)
//  s_w2v [12][32][8] : W2_v * pre        s_wsv [4][32][8] : W_sc_v * 1/sqrt(32)
//  s_w3  [12][16][8] : col0 = W3 * 0.1 * pre, cols 1-15 = 0
__global__ __launch_bounds__(256) void k_out(
    const float* __restrict__ node_input,
    const float* __restrict__ node_attr,
    const float* __restrict__ agg,
    const float* __restrict__ W_sc_s,
    const float* __restrict__ W_sc_v,
    const float* __restrict__ W2_s,
    const float* __restrict__ W2_v,
    const float* __restrict__ W3,
    float* __restrict__ out, int N)
{
    __shared__ unsigned short s_w2s[12 * 64 * 8];   // 12288 B
    __shared__ unsigned short s_wss[ 8 * 64 * 8];   //  8192 B
    __shared__ unsigned short s_w2v[12 * 32 * 8];   //  6144 B
    __shared__ unsigned short s_wsv[ 4 * 32 * 8];   //  2048 B
    __shared__ unsigned short s_w3 [12 * 16 * 8];   //  3072 B  -> 31744 B total

    const float pre = INV_SQRT10 * INV_SQRT96;
    int tid = threadIdx.x;

    // ---- stage weights (transpose to k-oct-major bf16, fold constants) ----
    for (int task = tid; task < 12 * 64; task += 256) {         // W2_s
        int col = task & 63, koct = task >> 6;
        const float* wp = W2_s + (size_t)(koct * 8) * MUL0 + col;
        unsigned pk0 = bf16pack(wp[0 * MUL0] * pre, wp[1 * MUL0] * pre);
        unsigned pk1 = bf16pack(wp[2 * MUL0] * pre, wp[3 * MUL0] * pre);
        unsigned pk2 = bf16pack(wp[4 * MUL0] * pre, wp[5 * MUL0] * pre);
        unsigned pk3 = bf16pack(wp[6 * MUL0] * pre, wp[7 * MUL0] * pre);
        *(uint4*)&s_w2s[task * 8] = make_uint4(pk0, pk1, pk2, pk3);
    }
    for (int task = tid; task < 8 * 64; task += 256) {          // W_sc_s
        int col = task & 63, koct = task >> 6;
        const float* wp = W_sc_s + (size_t)(koct * 8) * MUL0 + col;
        unsigned pk0 = bf16pack(wp[0 * MUL0] * INV_SQRT64, wp[1 * MUL0] * INV_SQRT64);
        unsigned pk1 = bf16pack(wp[2 * MUL0] * INV_SQRT64, wp[3 * MUL0] * INV_SQRT64);
        unsigned pk2 = bf16pack(wp[4 * MUL0] * INV_SQRT64, wp[5 * MUL0] * INV_SQRT64);
        unsigned pk3 = bf16pack(wp[6 * MUL0] * INV_SQRT64, wp[7 * MUL0] * INV_SQRT64);
        *(uint4*)&s_wss[task * 8] = make_uint4(pk0, pk1, pk2, pk3);
    }
    for (int task = tid; task < 12 * 32; task += 256) {         // W2_v
        int col = task & 31, koct = task >> 5;
        const float* wp = W2_v + (size_t)(koct * 8) * MUL1 + col;
        unsigned pk0 = bf16pack(wp[0 * MUL1] * pre, wp[1 * MUL1] * pre);
        unsigned pk1 = bf16pack(wp[2 * MUL1] * pre, wp[3 * MUL1] * pre);
        unsigned pk2 = bf16pack(wp[4 * MUL1] * pre, wp[5 * MUL1] * pre);
        unsigned pk3 = bf16pack(wp[6 * MUL1] * pre, wp[7 * MUL1] * pre);
        *(uint4*)&s_w2v[task * 8] = make_uint4(pk0, pk1, pk2, pk3);
    }
    for (int task = tid; task < 4 * 32; task += 256) {          // W_sc_v
        int col = task & 31, koct = task >> 5;
        const float* wp = W_sc_v + (size_t)(koct * 8) * MUL1 + col;
        unsigned pk0 = bf16pack(wp[0 * MUL1] * INV_SQRT32, wp[1 * MUL1] * INV_SQRT32);
        unsigned pk1 = bf16pack(wp[2 * MUL1] * INV_SQRT32, wp[3 * MUL1] * INV_SQRT32);
        unsigned pk2 = bf16pack(wp[4 * MUL1] * INV_SQRT32, wp[5 * MUL1] * INV_SQRT32);
        unsigned pk3 = bf16pack(wp[6 * MUL1] * INV_SQRT32, wp[7 * MUL1] * INV_SQRT32);
        *(uint4*)&s_w3[0] = *(uint4*)&s_w3[0];  // no-op keep structure
        *(uint4*)&s_wsv[task * 8] = make_uint4(pk0, pk1, pk2, pk3);
    }
    for (int task = tid; task < 12 * 16; task += 256) {         // W3 block
        int col = task & 15, koct = task >> 4;
        const float sc3 = 0.1f * pre;
        unsigned pk0 = 0, pk1 = 0, pk2 = 0, pk3 = 0;
        if (col == 0) {
            const float* wp = W3 + koct * 8;
            pk0 = bf16pack(wp[0] * sc3, wp[1] * sc3);
            pk1 = bf16pack(wp[2] * sc3, wp[3] * sc3);
            pk2 = bf16pack(wp[4] * sc3, wp[5] * sc3);
            pk3 = bf16pack(wp[6] * sc3, wp[7] * sc3);
        }
        *(uint4*)&s_w3[task * 8] = make_uint4(pk0, pk1, pk2, pk3);
    }
    __syncthreads();

    int lane = tid & 63;
    int wv = tid >> 6;
    int l15 = lane & 15, lh = lane >> 4;
    int ntiles = (N + 15) >> 4;

    for (int tile = blockIdx.x * 4 + wv; tile < ntiles; tile += gridDim.x * 4) {
        int n0 = tile << 4;
        int m = min(16, N - n0);
        int nrow = n0 + min(l15, m - 1);
        const float* agn = agg + (size_t)nrow * AGG_F;
        const float* inn = node_input + (size_t)nrow * NODE_F;

        // ---- s-phase A fragments ----
        bf16x8 aggA[3], inS[2];
        #pragma unroll
        for (int kk = 0; kk < 3; ++kk) {
            const float* p0 = agn + kk * 32 + lh * 8;
            aggA[kk] = cvt8(*(const float4*)p0, *(const float4*)(p0 + 4));
        }
        #pragma unroll
        for (int kk = 0; kk < 2; ++kk) {
            const float* p0 = inn + kk * 32 + lh * 8;
            inS[kk] = cvt8(*(const float4*)p0, *(const float4*)(p0 + 4));
        }

        // ---- MFMA: conv_s, sc_s, angle ----
        f32x4 convS[4], scS[4], angD = {0.f, 0.f, 0.f, 0.f};
        #pragma unroll
        for (int cb = 0; cb < 4; ++cb) {
            f32x4 a = {0.f, 0.f, 0.f, 0.f};
            #pragma unroll
            for (int kk = 0; kk < 3; ++kk) {
                bf16x8 b = *(const bf16x8*)&s_w2s[(((kk * 4 + lh) * 64) + cb * 16 + l15) * 8];
                a = __builtin_amdgcn_mfma_f32_16x16x32_bf16(aggA[kk], b, a, 0, 0, 0);
            }
            convS[cb] = a;
            f32x4 s = {0.f, 0.f, 0.f, 0.f};
            #pragma unroll
            for (int kk = 0; kk < 2; ++kk) {
                bf16x8 b = *(const bf16x8*)&s_wss[(((kk * 4 + lh) * 64) + cb * 16 + l15) * 8];
                s = __builtin_amdgcn_mfma_f32_16x16x32_bf16(inS[kk], b, s, 0, 0, 0);
            }
            scS[cb] = s;
        }
        #pragma unroll
        for (int kk = 0; kk < 3; ++kk) {
            bf16x8 b = *(const bf16x8*)&s_w3[(((kk * 4 + lh) * 16) + l15) * 8];
            angD = __builtin_amdgcn_mfma_f32_16x16x32_bf16(aggA[kk], b, angD, 0, 0, 0);
        }

        // ---- angle broadcast + trig + attr ----
        float attr[4], cs[4], sn[4];
        #pragma unroll
        for (int r = 0; r < 4; ++r) {
            attr[r] = node_attr[n0 + min(lh * 4 + r, m - 1)];
            float ang = __shfl(angD[r], lane & 48) * attr[r];
            cs[r] = cosf(ang);
            sn[r] = sinf(ang);
        }

        // ---- s store ----
        #pragma unroll
        for (int cb = 0; cb < 4; ++cb)
            #pragma unroll
            for (int r = 0; r < 4; ++r) {
                int node = lh * 4 + r;
                if (node < m)
                    out[(size_t)(n0 + node) * NODE_F + cb * 16 + l15] =
                        attr[r] * (cs[r] * scS[cb][r] + sn[r] * convS[cb][r]);
            }

        // ---- v-phase per d ----
        #pragma unroll
        for (int d = 0; d < 3; ++d) {
            bf16x8 aggV[3], inV;
            #pragma unroll
            for (int kk = 0; kk < 3; ++kk) {
                const float* p0 = agn + 96 + d * 96 + kk * 32 + lh * 8;
                aggV[kk] = cvt8(*(const float4*)p0, *(const float4*)(p0 + 4));
            }
            {
                float t[8];
                #pragma unroll
                for (int j = 0; j < 8; ++j)
                    t[j] = inn[64 + (lh * 8 + j) * 3 + d];
                inV = cvt8(make_float4(t[0], t[1], t[2], t[3]),
                           make_float4(t[4], t[5], t[6], t[7]));
            }
            #pragma unroll
            for (int cb = 0; cb < 2; ++cb) {
                f32x4 a = {0.f, 0.f, 0.f, 0.f};
                #pragma unroll
                for (int kk = 0; kk < 3; ++kk) {
                    bf16x8 b = *(const bf16x8*)&s_w2v[(((kk * 4 + lh) * 32) + cb * 16 + l15) * 8];
                    a = __builtin_amdgcn_mfma_f32_16x16x32_bf16(aggV[kk], b, a, 0, 0, 0);
                }
                f32x4 s = {0.f, 0.f, 0.f, 0.f};
                {
                    bf16x8 b = *(const bf16x8*)&s_wsv[((lh * 32) + cb * 16 + l15) * 8];
                    s = __builtin_amdgcn_mfma_f32_16x16x32_bf16(inV, b, s, 0, 0, 0);
                }
                #pragma unroll
                for (int r = 0; r < 4; ++r) {
                    int node = lh * 4 + r;
                    if (node < m)
                        out[(size_t)(n0 + node) * NODE_F + 64 + (cb * 16 + l15) * 3 + d] =
                            attr[r] * (cs[r] * s[r] + sn[r] * a[r]);
                }
            }
        }
    }
}

extern "C" void kernel_launch(void* const* d_in, const int* in_sizes, int n_in,
                              void* d_out, int out_size, void* d_ws, size_t ws_size,
                              hipStream_t stream)
{
    const float* node_input   = (const float*)d_in[0];
    const float* node_attr    = (const float*)d_in[1];
    const float* edge_attr    = (const float*)d_in[2];
    const float* edge_scalars = (const float*)d_in[3];
    const float* W_sc_s       = (const float*)d_in[4];
    const float* W_sc_v       = (const float*)d_in[5];
    const float* W1_s         = (const float*)d_in[6];
    const float* W1_v         = (const float*)d_in[7];
    const float* W2_s         = (const float*)d_in[8];
    const float* W2_v         = (const float*)d_in[9];
    const float* W3           = (const float*)d_in[10];
    const float* fcW1         = (const float*)d_in[11];
    const float* fcW2         = (const float*)d_in[12];
    const int*   edge_src     = (const int*)d_in[13];
    const int*   edge_dst     = (const int*)d_in[14];
    float* out = (float*)d_out;

    const int N = in_sizes[1];
    const int E = in_sizes[13];

    // ---- workspace layout ----
    char* p = (char*)d_ws;
    float* agg = (float*)p;  p += (size_t)N * AGG_F * sizeof(float);
    int*   deg = (int*)p;    p += (size_t)N * sizeof(int);
    int*   cur = (int*)p;    p += (size_t)N * sizeof(int);
    int*   csr = (int*)p;    p += (size_t)E * sizeof(int);
    int*   off = (int*)p;    p += (size_t)(N + 1) * sizeof(int);

    float* f = out;   // f lives in d_out, overwritten by k_out at the end

    hipMemsetAsync(deg, 0, (size_t)N * sizeof(int), stream);
    hipMemsetAsync(agg, 0, (size_t)N * AGG_F * sizeof(float), stream);

    int eb = (E + 255) / 256;
    k_count<<<eb, 256, 0, stream>>>(edge_dst, deg, E);
    k_scan<<<1, 1024, 0, stream>>>(deg, off, cur, N);
    k_scatter<<<eb, 256, 0, stream>>>(edge_dst, cur, csr, E);

    k_node_lin<<<768, 256, 0, stream>>>(node_input, node_attr, W1_s, W1_v, f, N);

    int nwt = (E + 15) / 16;
    int gridF = (nwt + 3) / 4;
    if (gridF > 1536) gridF = 1536;
    k_edge_fused<<<gridF, 256, 0, stream>>>(f, edge_scalars, edge_attr, fcW1, fcW2,
                                            edge_src, edge_dst, csr, agg, E);

    int ntiles = (N + 15) / 16;
    int gridO = (ntiles + 3) / 4;
    if (gridO > 640) gridO = 640;
    k_out<<<gridO, 256, 0, stream>>>(node_input, node_attr, agg,
                                     W_sc_s, W_sc_v, W2_s, W2_v, W3, out, N);
}

// Round 11
// 244.355 us; speedup vs baseline: 7.6176x; 1.1044x over previous
//
#include <hip/hip_runtime.h>
#include <math.h>

#define MUL0 64
#define MUL1 32
#define RADF 8
#define HIDF 64
#define WNUM 192
#define NODE_F 160   // 64 + 96
#define AGG_F  384   // A(64) | D(32) | mv_d0(96) | mv_d1(96) | mv_d2(96)

#define INV_SQRT64 0.125f
#define INV_SQRT32 0.17677669529663687f
#define INV_SQRT8  0.35355339059327373f
#define INV_SQRT96 0.10206207261596575f
#define INV_SQRT10 0.31622776601683794f
#define INV_SQRT3  0.5773502691896258f

typedef __attribute__((ext_vector_type(8))) short bf16x8;
typedef __attribute__((ext_vector_type(4))) float f32x4;

__device__ __forceinline__ float bf2f(unsigned short u) {
    return __uint_as_float((unsigned)u << 16);
}
__device__ __forceinline__ unsigned short f2bfu(float x) {
    unsigned ua = __float_as_uint(x);
    return (unsigned short)((ua + 0x7FFF + ((ua >> 16) & 1)) >> 16);
}
__device__ __forceinline__ unsigned bf16pack(float a, float b) {
    unsigned ua = __float_as_uint(a);
    unsigned ub = __float_as_uint(b);
    ua = (ua + 0x7FFF + ((ua >> 16) & 1)) >> 16;
    ub = (ub + 0x7FFF + ((ub >> 16) & 1)) >> 16;
    return ua | (ub << 16);
}
__device__ __forceinline__ int rdlane(int v, int i) {
    return __builtin_amdgcn_readlane(v, i);
}
__device__ __forceinline__ float rdlanef(float v, int i) {
    return __int_as_float(__builtin_amdgcn_readlane(__float_as_int(v), i));
}
__device__ __forceinline__ bf16x8 cvt8(float4 a, float4 b) {
    union { unsigned q[4]; bf16x8 v; } r;
    r.q[0] = bf16pack(a.x, a.y);
    r.q[1] = bf16pack(a.z, a.w);
    r.q[2] = bf16pack(b.x, b.y);
    r.q[3] = bf16pack(b.z, b.w);
    return r.v;
}

// ---------------- kernel: f = _lin(...) via MFMA, wave per 16 nodes ----------------
// f layout: [n][0:64]=s ; [n][64 + d*32 + u] = v[u][d]
__global__ __launch_bounds__(256) void k_node_lin(
    const float* __restrict__ node_input,
    const float* __restrict__ node_attr,
    const float* __restrict__ W1_s,
    const float* __restrict__ W1_v,
    float* __restrict__ f, int N)
{
    __shared__ unsigned short s_w1s[8 * 64 * 8];   // 8 KB
    __shared__ unsigned short s_w1v[4 * 32 * 8];   // 2 KB
    int tid = threadIdx.x;

    for (int task = tid; task < 8 * 64; task += 256) {
        int col = task & 63, koct = task >> 6;
        const float* wp = W1_s + (size_t)(koct * 8) * MUL0 + col;
        unsigned pk0 = bf16pack(wp[0 * MUL0] * INV_SQRT64, wp[1 * MUL0] * INV_SQRT64);
        unsigned pk1 = bf16pack(wp[2 * MUL0] * INV_SQRT64, wp[3 * MUL0] * INV_SQRT64);
        unsigned pk2 = bf16pack(wp[4 * MUL0] * INV_SQRT64, wp[5 * MUL0] * INV_SQRT64);
        unsigned pk3 = bf16pack(wp[6 * MUL0] * INV_SQRT64, wp[7 * MUL0] * INV_SQRT64);
        *(uint4*)&s_w1s[task * 8] = make_uint4(pk0, pk1, pk2, pk3);
    }
    for (int task = tid; task < 4 * 32; task += 256) {
        int col = task & 31, koct = task >> 5;
        const float* wp = W1_v + (size_t)(koct * 8) * MUL1 + col;
        unsigned pk0 = bf16pack(wp[0 * MUL1] * INV_SQRT32, wp[1 * MUL1] * INV_SQRT32);
        unsigned pk1 = bf16pack(wp[2 * MUL1] * INV_SQRT32, wp[3 * MUL1] * INV_SQRT32);
        unsigned pk2 = bf16pack(wp[4 * MUL1] * INV_SQRT32, wp[5 * MUL1] * INV_SQRT32);
        unsigned pk3 = bf16pack(wp[6 * MUL1] * INV_SQRT32, wp[7 * MUL1] * INV_SQRT32);
        *(uint4*)&s_w1v[task * 8] = make_uint4(pk0, pk1, pk2, pk3);
    }
    __syncthreads();

    int lane = tid & 63;
    int wv = tid >> 6;
    int l15 = lane & 15, lh = lane >> 4;
    int ntiles = (N + 15) >> 4;

    for (int tile = blockIdx.x * 4 + wv; tile < ntiles; tile += gridDim.x * 4) {
        int n0 = tile << 4;
        int m = min(16, N - n0);
        int nrow = n0 + min(l15, m - 1);
        const float* inn = node_input + (size_t)nrow * NODE_F;

        float attr[4];
        #pragma unroll
        for (int r = 0; r < 4; ++r)
            attr[r] = node_attr[n0 + min(lh * 4 + r, m - 1)];

        // ---- s: [16x64] = in_s @ W1_s ----
        bf16x8 inS[2];
        #pragma unroll
        for (int kk = 0; kk < 2; ++kk) {
            const float* p0 = inn + kk * 32 + lh * 8;
            inS[kk] = cvt8(*(const float4*)p0, *(const float4*)(p0 + 4));
        }
        #pragma unroll
        for (int cb = 0; cb < 4; ++cb) {
            f32x4 a = {0.f, 0.f, 0.f, 0.f};
            #pragma unroll
            for (int kk = 0; kk < 2; ++kk) {
                bf16x8 b = *(const bf16x8*)&s_w1s[(((kk * 4 + lh) * 64) + cb * 16 + l15) * 8];
                a = __builtin_amdgcn_mfma_f32_16x16x32_bf16(inS[kk], b, a, 0, 0, 0);
            }
            #pragma unroll
            for (int r = 0; r < 4; ++r) {
                int node = lh * 4 + r;
                if (node < m)
                    f[(size_t)(n0 + node) * NODE_F + cb * 16 + l15] = a[r] * attr[r];
            }
        }

        // ---- v per d: [16x32] = in_v_d @ W1_v ----
        #pragma unroll
        for (int d = 0; d < 3; ++d) {
            float t[8];
            #pragma unroll
            for (int j = 0; j < 8; ++j)
                t[j] = inn[64 + (lh * 8 + j) * 3 + d];
            bf16x8 inV = cvt8(make_float4(t[0], t[1], t[2], t[3]),
                              make_float4(t[4], t[5], t[6], t[7]));
            #pragma unroll
            for (int cb = 0; cb < 2; ++cb) {
                bf16x8 b = *(const bf16x8*)&s_w1v[((lh * 32) + cb * 16 + l15) * 8];
                f32x4 a = {0.f, 0.f, 0.f, 0.f};
                a = __builtin_amdgcn_mfma_f32_16x16x32_bf16(inV, b, a, 0, 0, 0);
                #pragma unroll
                for (int r = 0; r < 4; ++r) {
                    int node = lh * 4 + r;
                    if (node < m)
                        f[(size_t)(n0 + node) * NODE_F + 64 + d * 32 + cb * 16 + l15] =
                            a[r] * attr[r];
                }
            }
        }
    }
}

// ---------------- CSR build ----------------
__global__ void k_count(const int* __restrict__ edge_dst, int* deg, int E)
{
    int e = blockIdx.x * blockDim.x + threadIdx.x;
    if (e < E) atomicAdd(&deg[edge_dst[e]], 1);
}

__global__ __launch_bounds__(1024) void k_scan(const int* __restrict__ deg,
                                               int* __restrict__ off,
                                               int* __restrict__ cur, int N)
{
    __shared__ int swsum[16];
    __shared__ int swoff[16];
    __shared__ int sbase;
    __shared__ int stotal;
    int lane = threadIdx.x & 63, wid = threadIdx.x >> 6;
    if (threadIdx.x == 0) sbase = 0;
    __syncthreads();
    int ngroups = N >> 2;
    for (int base = 0; base < ngroups; base += 1024) {
        int g = base + threadIdx.x;
        int4 v = make_int4(0, 0, 0, 0);
        if (g < ngroups) v = ((const int4*)deg)[g];
        int s = v.x + v.y + v.z + v.w;
        int val = s;
        #pragma unroll
        for (int sh = 1; sh < 64; sh <<= 1) {
            int t = __shfl_up(val, sh);
            if (lane >= sh) val += t;
        }
        if (lane == 63) swsum[wid] = val;
        __syncthreads();
        if (threadIdx.x < 16) {
            int x = swsum[threadIdx.x];
            int xv = x;
            #pragma unroll
            for (int sh = 1; sh < 16; sh <<= 1) {
                int t = __shfl_up(xv, sh);
                if ((int)threadIdx.x >= sh) xv += t;
            }
            swoff[threadIdx.x] = xv - x;
            if (threadIdx.x == 15) stotal = xv;
        }
        __syncthreads();
        if (g < ngroups) {
            int b = sbase + swoff[wid] + (val - s);
            int4 o;
            o.x = b; o.y = b + v.x; o.z = o.y + v.y; o.w = o.z + v.z;
            ((int4*)off)[g] = o;
            ((int4*)cur)[g] = o;
        }
        __syncthreads();
        if (threadIdx.x == 0) sbase += stotal;
        __syncthreads();
    }
    if (threadIdx.x == 0) {
        int b = sbase;
        for (int i = (ngroups << 2); i < N; ++i) { off[i] = b; cur[i] = b; b += deg[i]; }
        off[N] = b;
    }
}

__global__ void k_scatter(const int* __restrict__ edge_dst,
                          int* cur, int* __restrict__ csr, int E)
{
    int e = blockIdx.x * blockDim.x + threadIdx.x;
    if (e < E) {
        int d = edge_dst[e];
        int pos = atomicAdd(&cur[d], 1);
        csr[pos] = e;
    }
}

// ---------------- fused edge kernel: pipelined per-wave 16-edge tiles ----------------
#define FLUSH_AGG(node)                                              \
    do {                                                             \
        float* an = agg + (size_t)(node) * AGG_F;                    \
        atomicAdd(&an[lane], accA);                                  \
        atomicAdd(&an[96  + lane], accB0);                           \
        atomicAdd(&an[192 + lane], accB1);                           \
        atomicAdd(&an[288 + lane], accB2);                           \
        if (lane < 32) {                                             \
            atomicAdd(&an[160 + u], accX0);                          \
            atomicAdd(&an[256 + u], accX1);                          \
            atomicAdd(&an[352 + u], accX2);                          \
        } else {                                                     \
            atomicAdd(&an[64 + u], accX0);                           \
        }                                                            \
    } while (0)

__global__ __launch_bounds__(256, 3) void k_edge_fused(
    const float* __restrict__ f,
    const float* __restrict__ edge_scalars,
    const float* __restrict__ edge_attr,
    const float* __restrict__ fcW1,
    const float* __restrict__ fcW2,
    const int* __restrict__ edge_src,
    const int* __restrict__ edge_dst,
    const int* __restrict__ csr,
    float* agg, int E)
{
    __shared__ unsigned short s_w2t[8 * 192 * 8];   // 24576 B
    __shared__ unsigned short s_w[4][16 * 216];     // 27648 B
    __shared__ float s_fcW1[512];                   //  2048 B

    int tid  = threadIdx.x;
    int lane = tid & 63;
    int wv   = tid >> 6;
    int l15  = lane & 15, lh = lane >> 4;
    int u    = lane & 31;

    for (int task = tid; task < 1536; task += 256) {
        int col = task % 192, oct = task / 192;
        const float* wp = fcW2 + (size_t)(oct * 8) * WNUM + col;
        unsigned pk0 = bf16pack(wp[0 * WNUM], wp[1 * WNUM]);
        unsigned pk1 = bf16pack(wp[2 * WNUM], wp[3 * WNUM]);
        unsigned pk2 = bf16pack(wp[4 * WNUM], wp[5 * WNUM]);
        unsigned pk3 = bf16pack(wp[6 * WNUM], wp[7 * WNUM]);
        *(uint4*)&s_w2t[oct * 1536 + col * 8] = make_uint4(pk0, pk1, pk2, pk3);
    }
    for (int i = tid; i < 512; i += 256)
        s_fcW1[i] = fcW1[i];
    __syncthreads();      // the only block barrier

    unsigned short* sw = s_w[wv];
    int nwt = (E + 15) >> 4;
    int stride4 = gridDim.x * 4;

    int wt = blockIdx.x * 4 + wv;
    if (wt >= nwt) return;

    // ---- prologue: metadata chain for first tile ----
    int P = wt << 4;
    int m = min(16, E - P);
    int e0 = csr[P + min(l15, m - 1)];
    int src = edge_src[e0];
    int dst = edge_dst[e0];
    float4 ea = *(const float4*)(edge_attr + (size_t)e0 * 4);
    float4 es0, es1;
    {
        const float4* esp = (const float4*)(edge_scalars + (size_t)e0 * RADF);
        es0 = esp[0]; es1 = esp[1];
    }

    while (true) {
        int wt_n = wt + stride4;
        bool hn = wt_n < nwt;
        int P_n = hn ? (wt_n << 4) : 0;
        int m_n = hn ? min(16, E - P_n) : 1;

        // ---- issue next-tile csr FIRST (oldest in vmcnt order) ----
        int e_n = csr[hn ? (P_n + min(l15, m_n - 1)) : 0];

        // ---- issue current-tile f gather (64 loads) ----
        float xs[16], xv0[16], xv1[16], xv2[16];
        #pragma unroll
        for (int i = 0; i < 16; ++i) {
            int si = rdlane(src, i);
            const float* fb = f + (size_t)si * NODE_F;
            xs[i]  = fb[lane];
            xv0[i] = fb[64 + u];
            xv1[i] = fb[96 + u];
            xv2[i] = fb[128 + u];
        }

        // ---- h compute (registers only; covers csr latency) ----
        float es[8] = {es0.x, es0.y, es0.z, es0.w, es1.x, es1.y, es1.z, es1.w};
        union { unsigned q[4]; bf16x8 v; } A0, A1;
        #pragma unroll
        for (int jp = 0; jp < 4; ++jp) {
            int k0 = lh * 8 + 2 * jp;
            float aL0 = 0.f, aL1 = 0.f, aH0 = 0.f, aH1 = 0.f;
            #pragma unroll
            for (int r = 0; r < 8; ++r) {
                float2 wl = *(const float2*)&s_fcW1[r * 64 + k0];
                float2 wh = *(const float2*)&s_fcW1[r * 64 + 32 + k0];
                aL0 = fmaf(es[r], wl.x, aL0);
                aL1 = fmaf(es[r], wl.y, aL1);
                aH0 = fmaf(es[r], wh.x, aH0);
                aH1 = fmaf(es[r], wh.y, aH1);
            }
            aL0 *= INV_SQRT8; aL1 *= INV_SQRT8; aH0 *= INV_SQRT8; aH1 *= INV_SQRT8;
            aL0 = aL0 / (1.f + __expf(-aL0));
            aL1 = aL1 / (1.f + __expf(-aL1));
            aH0 = aH0 / (1.f + __expf(-aH0));
            aH1 = aH1 / (1.f + __expf(-aH1));
            A0.q[jp] = bf16pack(aL0, aL1);
            A1.q[jp] = bf16pack(aH0, aH1);
        }

        // ---- issue next-tile metadata (consumes e_n; hides under MFMA+TP) ----
        int src_n = edge_src[e_n];
        int dst_n = edge_dst[e_n];
        float4 ea_n = *(const float4*)(edge_attr + (size_t)e_n * 4);
        float4 es0_n, es1_n;
        {
            const float4* espn = (const float4*)(edge_scalars + (size_t)e_n * RADF);
            es0_n = espn[0]; es1_n = espn[1];
        }

        // ---- MFMA: w = h @ fcW2 / sqrt(64) ----
        #pragma unroll
        for (int cb = 0; cb < 12; ++cb) {
            bf16x8 b0 = *(const bf16x8*)&s_w2t[ lh      * 1536 + (cb * 16 + l15) * 8];
            bf16x8 b1 = *(const bf16x8*)&s_w2t[(4 + lh) * 1536 + (cb * 16 + l15) * 8];
            f32x4 acc = {0.f, 0.f, 0.f, 0.f};
            acc = __builtin_amdgcn_mfma_f32_16x16x32_bf16(A0.v, b0, acc, 0, 0, 0);
            acc = __builtin_amdgcn_mfma_f32_16x16x32_bf16(A1.v, b1, acc, 0, 0, 0);
            #pragma unroll
            for (int r = 0; r < 4; ++r)
                sw[(lh * 4 + r) * 216 + cb * 16 + l15] = f2bfu(acc[r] * INV_SQRT64);
        }

        // ---- TP + dst-segmented atomic reduction ----
        float accA = 0.f, accB0 = 0.f, accB1 = 0.f, accB2 = 0.f;
        float accX0 = 0.f, accX1 = 0.f, accX2 = 0.f;
        int curd = rdlane(dst, 0);
        #pragma unroll
        for (int i = 0; i < 16; ++i) {
            if (i < m) {
                int di = rdlane(dst, i);
                if (di != curd) {
                    FLUSH_AGG(curd);
                    accA = accB0 = accB1 = accB2 = 0.f;
                    accX0 = accX1 = accX2 = 0.f;
                    curd = di;
                }
                float eax = rdlanef(ea.x, i);
                float eay = rdlanef(ea.y, i);
                float eaz = rdlanef(ea.z, i);
                float eaw = rdlanef(ea.w, i);
                float W0 = bf2f(sw[i * 216 + lane]);
                float W1 = bf2f(sw[i * 216 + 64 + lane]);
                float W2 = bf2f(sw[i * 216 + 128 + lane]);
                accA = fmaf(W0 * xs[i], eax, accA);
                float bx = W1 * xs[i];
                accB0 = fmaf(bx, eay, accB0);
                accB1 = fmaf(bx, eaz, accB1);
                accB2 = fmaf(bx, eaw, accB2);
                if (lane < 32) {
                    float cc = W2 * eax;
                    accX0 = fmaf(cc, xv0[i], accX0);
                    accX1 = fmaf(cc, xv1[i], accX1);
                    accX2 = fmaf(cc, xv2[i], accX2);
                } else {
                    float dv = xv0[i] * eay + xv1[i] * eaz + xv2[i] * eaw;
                    accX0 = fmaf(W2 * INV_SQRT3, dv, accX0);
                }
            }
        }
        FLUSH_AGG(curd);

        if (!hn) break;
        wt = wt_n; P = P_n; m = m_n;
        src = src_n; dst = dst_n; ea = ea_n; es0 = es0_n; es1 = es1_n;
    }
}

// ---------------- kernel: output combine via MFMA, wave per 16 nodes ----------------
__global__ __launch_bounds__(256) void k_out(
    const float* __restrict__ node_input,
    const float* __restrict__ node_attr,
    const float* __restrict__ agg,
    const float* __restrict__ W_sc_s,
    const float* __restrict__ W_sc_v,
    const float* __restrict__ W2_s,
    const float* __restrict__ W2_v,
    const float* __restrict__ W3,
    float* __restrict__ out, int N)
{
    __shared__ unsigned short s_w2s[12 * 64 * 8];   // 12288 B
    __shared__ unsigned short s_wss[ 8 * 64 * 8];   //  8192 B
    __shared__ unsigned short s_w2v[12 * 32 * 8];   //  6144 B
    __shared__ unsigned short s_wsv[ 4 * 32 * 8];   //  2048 B
    __shared__ unsigned short s_w3 [12 * 16 * 8];   //  3072 B  -> 31744 B total

    const float pre = INV_SQRT10 * INV_SQRT96;
    int tid = threadIdx.x;

    for (int task = tid; task < 12 * 64; task += 256) {         // W2_s
        int col = task & 63, koct = task >> 6;
        const float* wp = W2_s + (size_t)(koct * 8) * MUL0 + col;
        unsigned pk0 = bf16pack(wp[0 * MUL0] * pre, wp[1 * MUL0] * pre);
        unsigned pk1 = bf16pack(wp[2 * MUL0] * pre, wp[3 * MUL0] * pre);
        unsigned pk2 = bf16pack(wp[4 * MUL0] * pre, wp[5 * MUL0] * pre);
        unsigned pk3 = bf16pack(wp[6 * MUL0] * pre, wp[7 * MUL0] * pre);
        *(uint4*)&s_w2s[task * 8] = make_uint4(pk0, pk1, pk2, pk3);
    }
    for (int task = tid; task < 8 * 64; task += 256) {          // W_sc_s
        int col = task & 63, koct = task >> 6;
        const float* wp = W_sc_s + (size_t)(koct * 8) * MUL0 + col;
        unsigned pk0 = bf16pack(wp[0 * MUL0] * INV_SQRT64, wp[1 * MUL0] * INV_SQRT64);
        unsigned pk1 = bf16pack(wp[2 * MUL0] * INV_SQRT64, wp[3 * MUL0] * INV_SQRT64);
        unsigned pk2 = bf16pack(wp[4 * MUL0] * INV_SQRT64, wp[5 * MUL0] * INV_SQRT64);
        unsigned pk3 = bf16pack(wp[6 * MUL0] * INV_SQRT64, wp[7 * MUL0] * INV_SQRT64);
        *(uint4*)&s_wss[task * 8] = make_uint4(pk0, pk1, pk2, pk3);
    }
    for (int task = tid; task < 12 * 32; task += 256) {         // W2_v
        int col = task & 31, koct = task >> 5;
        const float* wp = W2_v + (size_t)(koct * 8) * MUL1 + col;
        unsigned pk0 = bf16pack(wp[0 * MUL1] * pre, wp[1 * MUL1] * pre);
        unsigned pk1 = bf16pack(wp[2 * MUL1] * pre, wp[3 * MUL1] * pre);
        unsigned pk2 = bf16pack(wp[4 * MUL1] * pre, wp[5 * MUL1] * pre);
        unsigned pk3 = bf16pack(wp[6 * MUL1] * pre, wp[7 * MUL1] * pre);
        *(uint4*)&s_w2v[task * 8] = make_uint4(pk0, pk1, pk2, pk3);
    }
    for (int task = tid; task < 4 * 32; task += 256) {          // W_sc_v
        int col = task & 31, koct = task >> 5;
        const float* wp = W_sc_v + (size_t)(koct * 8) * MUL1 + col;
        unsigned pk0 = bf16pack(wp[0 * MUL1] * INV_SQRT32, wp[1 * MUL1] * INV_SQRT32);
        unsigned pk1 = bf16pack(wp[2 * MUL1] * INV_SQRT32, wp[3 * MUL1] * INV_SQRT32);
        unsigned pk2 = bf16pack(wp[4 * MUL1] * INV_SQRT32, wp[5 * MUL1] * INV_SQRT32);
        unsigned pk3 = bf16pack(wp[6 * MUL1] * INV_SQRT32, wp[7 * MUL1] * INV_SQRT32);
        *(uint4*)&s_wsv[task * 8] = make_uint4(pk0, pk1, pk2, pk3);
    }
    for (int task = tid; task < 12 * 16; task += 256) {         // W3 block
        int col = task & 15, koct = task >> 4;
        const float sc3 = 0.1f * pre;
        unsigned pk0 = 0, pk1 = 0, pk2 = 0, pk3 = 0;
        if (col == 0) {
            const float* wp = W3 + koct * 8;
            pk0 = bf16pack(wp[0] * sc3, wp[1] * sc3);
            pk1 = bf16pack(wp[2] * sc3, wp[3] * sc3);
            pk2 = bf16pack(wp[4] * sc3, wp[5] * sc3);
            pk3 = bf16pack(wp[6] * sc3, wp[7] * sc3);
        }
        *(uint4*)&s_w3[task * 8] = make_uint4(pk0, pk1, pk2, pk3);
    }
    __syncthreads();

    int lane = tid & 63;
    int wv = tid >> 6;
    int l15 = lane & 15, lh = lane >> 4;
    int ntiles = (N + 15) >> 4;

    for (int tile = blockIdx.x * 4 + wv; tile < ntiles; tile += gridDim.x * 4) {
        int n0 = tile << 4;
        int m = min(16, N - n0);
        int nrow = n0 + min(l15, m - 1);
        const float* agn = agg + (size_t)nrow * AGG_F;
        const float* inn = node_input + (size_t)nrow * NODE_F;

        bf16x8 aggA[3], inS[2];
        #pragma unroll
        for (int kk = 0; kk < 3; ++kk) {
            const float* p0 = agn + kk * 32 + lh * 8;
            aggA[kk] = cvt8(*(const float4*)p0, *(const float4*)(p0 + 4));
        }
        #pragma unroll
        for (int kk = 0; kk < 2; ++kk) {
            const float* p0 = inn + kk * 32 + lh * 8;
            inS[kk] = cvt8(*(const float4*)p0, *(const float4*)(p0 + 4));
        }

        f32x4 convS[4], scS[4], angD = {0.f, 0.f, 0.f, 0.f};
        #pragma unroll
        for (int cb = 0; cb < 4; ++cb) {
            f32x4 a = {0.f, 0.f, 0.f, 0.f};
            #pragma unroll
            for (int kk = 0; kk < 3; ++kk) {
                bf16x8 b = *(const bf16x8*)&s_w2s[(((kk * 4 + lh) * 64) + cb * 16 + l15) * 8];
                a = __builtin_amdgcn_mfma_f32_16x16x32_bf16(aggA[kk], b, a, 0, 0, 0);
            }
            convS[cb] = a;
            f32x4 s = {0.f, 0.f, 0.f, 0.f};
            #pragma unroll
            for (int kk = 0; kk < 2; ++kk) {
                bf16x8 b = *(const bf16x8*)&s_wss[(((kk * 4 + lh) * 64) + cb * 16 + l15) * 8];
                s = __builtin_amdgcn_mfma_f32_16x16x32_bf16(inS[kk], b, s, 0, 0, 0);
            }
            scS[cb] = s;
        }
        #pragma unroll
        for (int kk = 0; kk < 3; ++kk) {
            bf16x8 b = *(const bf16x8*)&s_w3[(((kk * 4 + lh) * 16) + l15) * 8];
            angD = __builtin_amdgcn_mfma_f32_16x16x32_bf16(aggA[kk], b, angD, 0, 0, 0);
        }

        float attr[4], cs[4], sn[4];
        #pragma unroll
        for (int r = 0; r < 4; ++r) {
            attr[r] = node_attr[n0 + min(lh * 4 + r, m - 1)];
            float ang = __shfl(angD[r], lane & 48) * attr[r];
            cs[r] = cosf(ang);
            sn[r] = sinf(ang);
        }

        #pragma unroll
        for (int cb = 0; cb < 4; ++cb)
            #pragma unroll
            for (int r = 0; r < 4; ++r) {
                int node = lh * 4 + r;
                if (node < m)
                    out[(size_t)(n0 + node) * NODE_F + cb * 16 + l15] =
                        attr[r] * (cs[r] * scS[cb][r] + sn[r] * convS[cb][r]);
            }

        #pragma unroll
        for (int d = 0; d < 3; ++d) {
            bf16x8 aggV[3], inV;
            #pragma unroll
            for (int kk = 0; kk < 3; ++kk) {
                const float* p0 = agn + 96 + d * 96 + kk * 32 + lh * 8;
                aggV[kk] = cvt8(*(const float4*)p0, *(const float4*)(p0 + 4));
            }
            {
                float t[8];
                #pragma unroll
                for (int j = 0; j < 8; ++j)
                    t[j] = inn[64 + (lh * 8 + j) * 3 + d];
                inV = cvt8(make_float4(t[0], t[1], t[2], t[3]),
                           make_float4(t[4], t[5], t[6], t[7]));
            }
            #pragma unroll
            for (int cb = 0; cb < 2; ++cb) {
                f32x4 a = {0.f, 0.f, 0.f, 0.f};
                #pragma unroll
                for (int kk = 0; kk < 3; ++kk) {
                    bf16x8 b = *(const bf16x8*)&s_w2v[(((kk * 4 + lh) * 32) + cb * 16 + l15) * 8];
                    a = __builtin_amdgcn_mfma_f32_16x16x32_bf16(aggV[kk], b, a, 0, 0, 0);
                }
                f32x4 s = {0.f, 0.f, 0.f, 0.f};
                {
                    bf16x8 b = *(const bf16x8*)&s_wsv[((lh * 32) + cb * 16 + l15) * 8];
                    s = __builtin_amdgcn_mfma_f32_16x16x32_bf16(inV, b, s, 0, 0, 0);
                }
                #pragma unroll
                for (int r = 0; r < 4; ++r) {
                    int node = lh * 4 + r;
                    if (node < m)
                        out[(size_t)(n0 + node) * NODE_F + 64 + (cb * 16 + l15) * 3 + d] =
                            attr[r] * (cs[r] * s[r] + sn[r] * a[r]);
                }
            }
        }
    }
}

extern "C" void kernel_launch(void* const* d_in, const int* in_sizes, int n_in,
                              void* d_out, int out_size, void* d_ws, size_t ws_size,
                              hipStream_t stream)
{
    const float* node_input   = (const float*)d_in[0];
    const float* node_attr    = (const float*)d_in[1];
    const float* edge_attr    = (const float*)d_in[2];
    const float* edge_scalars = (const float*)d_in[3];
    const float* W_sc_s       = (const float*)d_in[4];
    const float* W_sc_v       = (const float*)d_in[5];
    const float* W1_s         = (const float*)d_in[6];
    const float* W1_v         = (const float*)d_in[7];
    const float* W2_s         = (const float*)d_in[8];
    const float* W2_v         = (const float*)d_in[9];
    const float* W3           = (const float*)d_in[10];
    const float* fcW1         = (const float*)d_in[11];
    const float* fcW2         = (const float*)d_in[12];
    const int*   edge_src     = (const int*)d_in[13];
    const int*   edge_dst     = (const int*)d_in[14];
    float* out = (float*)d_out;

    const int N = in_sizes[1];
    const int E = in_sizes[13];

    // ---- workspace layout ----
    char* p = (char*)d_ws;
    float* agg = (float*)p;  p += (size_t)N * AGG_F * sizeof(float);
    int*   deg = (int*)p;    p += (size_t)N * sizeof(int);
    int*   cur = (int*)p;    p += (size_t)N * sizeof(int);
    int*   csr = (int*)p;    p += (size_t)E * sizeof(int);
    int*   off = (int*)p;    p += (size_t)(N + 1) * sizeof(int);

    float* f = out;   // f lives in d_out, overwritten by k_out at the end

    hipMemsetAsync(deg, 0, (size_t)N * sizeof(int), stream);
    hipMemsetAsync(agg, 0, (size_t)N * AGG_F * sizeof(float), stream);

    int eb = (E + 255) / 256;
    k_count<<<eb, 256, 0, stream>>>(edge_dst, deg, E);
    k_scan<<<1, 1024, 0, stream>>>(deg, off, cur, N);
    k_scatter<<<eb, 256, 0, stream>>>(edge_dst, cur, csr, E);

    int ntiles = (N + 15) / 16;
    int gridL = (ntiles + 3) / 4;
    k_node_lin<<<gridL, 256, 0, stream>>>(node_input, node_attr, W1_s, W1_v, f, N);

    int nwt = (E + 15) / 16;
    int gridF = (nwt + 3) / 4;
    if (gridF > 1536) gridF = 1536;
    k_edge_fused<<<gridF, 256, 0, stream>>>(f, edge_scalars, edge_attr, fcW1, fcW2,
                                            edge_src, edge_dst, csr, agg, E);

    int gridO = (ntiles + 3) / 4;
    if (gridO > 640) gridO = 640;
    k_out<<<gridO, 256, 0, stream>>>(node_input, node_attr, agg,
                                     W_sc_s, W_sc_v, W2_s, W2_v, W3, out, N);
}

// Round 12
// 239.143 us; speedup vs baseline: 7.7836x; 1.0218x over previous
//
#include <hip/hip_runtime.h>
#include <math.h>

#define MUL0 64
#define MUL1 32
#define RADF 8
#define HIDF 64
#define WNUM 192
#define NODE_F 160   // 64 + 96
#define AGG_F  384   // A(64) | D(32) | mv_d0(96) | mv_d1(96) | mv_d2(96)

#define INV_SQRT64 0.125f
#define INV_SQRT32 0.17677669529663687f
#define INV_SQRT8  0.35355339059327373f
#define INV_SQRT96 0.10206207261596575f
#define INV_SQRT10 0.31622776601683794f
#define INV_SQRT3  0.5773502691896258f

typedef __attribute__((ext_vector_type(8))) short bf16x8;
typedef __attribute__((ext_vector_type(4))) float f32x4;

__device__ __forceinline__ float bf2f(unsigned short u) {
    return __uint_as_float((unsigned)u << 16);
}
__device__ __forceinline__ unsigned short f2bfu(float x) {
    unsigned ua = __float_as_uint(x);
    return (unsigned short)((ua + 0x7FFF + ((ua >> 16) & 1)) >> 16);
}
__device__ __forceinline__ unsigned bf16pack(float a, float b) {
    unsigned ua = __float_as_uint(a);
    unsigned ub = __float_as_uint(b);
    ua = (ua + 0x7FFF + ((ua >> 16) & 1)) >> 16;
    ub = (ub + 0x7FFF + ((ub >> 16) & 1)) >> 16;
    return ua | (ub << 16);
}
__device__ __forceinline__ int rdlane(int v, int i) {
    return __builtin_amdgcn_readlane(v, i);
}
__device__ __forceinline__ float rdlanef(float v, int i) {
    return __int_as_float(__builtin_amdgcn_readlane(__float_as_int(v), i));
}
__device__ __forceinline__ bf16x8 cvt8(float4 a, float4 b) {
    union { unsigned q[4]; bf16x8 v; } r;
    r.q[0] = bf16pack(a.x, a.y);
    r.q[1] = bf16pack(a.z, a.w);
    r.q[2] = bf16pack(b.x, b.y);
    r.q[3] = bf16pack(b.z, b.w);
    return r.v;
}

// ---------------- kernel: f = _lin(...) via MFMA, wave per 16 nodes, bf16 output ----------------
// f layout (bf16): [n][0:64]=s ; [n][64 + d*32 + u] = v[u][d]
__global__ __launch_bounds__(256) void k_node_lin(
    const float* __restrict__ node_input,
    const float* __restrict__ node_attr,
    const float* __restrict__ W1_s,
    const float* __restrict__ W1_v,
    unsigned short* __restrict__ f, int N)
{
    __shared__ unsigned short s_w1s[8 * 64 * 8];   // 8 KB
    __shared__ unsigned short s_w1v[4 * 32 * 8];   // 2 KB
    int tid = threadIdx.x;

    for (int task = tid; task < 8 * 64; task += 256) {
        int col = task & 63, koct = task >> 6;
        const float* wp = W1_s + (size_t)(koct * 8) * MUL0 + col;
        unsigned pk0 = bf16pack(wp[0 * MUL0] * INV_SQRT64, wp[1 * MUL0] * INV_SQRT64);
        unsigned pk1 = bf16pack(wp[2 * MUL0] * INV_SQRT64, wp[3 * MUL0] * INV_SQRT64);
        unsigned pk2 = bf16pack(wp[4 * MUL0] * INV_SQRT64, wp[5 * MUL0] * INV_SQRT64);
        unsigned pk3 = bf16pack(wp[6 * MUL0] * INV_SQRT64, wp[7 * MUL0] * INV_SQRT64);
        *(uint4*)&s_w1s[task * 8] = make_uint4(pk0, pk1, pk2, pk3);
    }
    for (int task = tid; task < 4 * 32; task += 256) {
        int col = task & 31, koct = task >> 5;
        const float* wp = W1_v + (size_t)(koct * 8) * MUL1 + col;
        unsigned pk0 = bf16pack(wp[0 * MUL1] * INV_SQRT32, wp[1 * MUL1] * INV_SQRT32);
        unsigned pk1 = bf16pack(wp[2 * MUL1] * INV_SQRT32, wp[3 * MUL1] * INV_SQRT32);
        unsigned pk2 = bf16pack(wp[4 * MUL1] * INV_SQRT32, wp[5 * MUL1] * INV_SQRT32);
        unsigned pk3 = bf16pack(wp[6 * MUL1] * INV_SQRT32, wp[7 * MUL1] * INV_SQRT32);
        *(uint4*)&s_w1v[task * 8] = make_uint4(pk0, pk1, pk2, pk3);
    }
    __syncthreads();

    int lane = tid & 63;
    int wv = tid >> 6;
    int l15 = lane & 15, lh = lane >> 4;
    int ntiles = (N + 15) >> 4;

    for (int tile = blockIdx.x * 4 + wv; tile < ntiles; tile += gridDim.x * 4) {
        int n0 = tile << 4;
        int m = min(16, N - n0);
        int nrow = n0 + min(l15, m - 1);
        const float* inn = node_input + (size_t)nrow * NODE_F;

        float attr[4];
        #pragma unroll
        for (int r = 0; r < 4; ++r)
            attr[r] = node_attr[n0 + min(lh * 4 + r, m - 1)];

        // ---- s: [16x64] = in_s @ W1_s ----
        bf16x8 inS[2];
        #pragma unroll
        for (int kk = 0; kk < 2; ++kk) {
            const float* p0 = inn + kk * 32 + lh * 8;
            inS[kk] = cvt8(*(const float4*)p0, *(const float4*)(p0 + 4));
        }
        #pragma unroll
        for (int cb = 0; cb < 4; ++cb) {
            f32x4 a = {0.f, 0.f, 0.f, 0.f};
            #pragma unroll
            for (int kk = 0; kk < 2; ++kk) {
                bf16x8 b = *(const bf16x8*)&s_w1s[(((kk * 4 + lh) * 64) + cb * 16 + l15) * 8];
                a = __builtin_amdgcn_mfma_f32_16x16x32_bf16(inS[kk], b, a, 0, 0, 0);
            }
            #pragma unroll
            for (int r = 0; r < 4; ++r) {
                int node = lh * 4 + r;
                if (node < m)
                    f[(size_t)(n0 + node) * NODE_F + cb * 16 + l15] = f2bfu(a[r] * attr[r]);
            }
        }

        // ---- v per d: [16x32] = in_v_d @ W1_v ----
        #pragma unroll
        for (int d = 0; d < 3; ++d) {
            float t[8];
            #pragma unroll
            for (int j = 0; j < 8; ++j)
                t[j] = inn[64 + (lh * 8 + j) * 3 + d];
            bf16x8 inV = cvt8(make_float4(t[0], t[1], t[2], t[3]),
                              make_float4(t[4], t[5], t[6], t[7]));
            #pragma unroll
            for (int cb = 0; cb < 2; ++cb) {
                bf16x8 b = *(const bf16x8*)&s_w1v[((lh * 32) + cb * 16 + l15) * 8];
                f32x4 a = {0.f, 0.f, 0.f, 0.f};
                a = __builtin_amdgcn_mfma_f32_16x16x32_bf16(inV, b, a, 0, 0, 0);
                #pragma unroll
                for (int r = 0; r < 4; ++r) {
                    int node = lh * 4 + r;
                    if (node < m)
                        f[(size_t)(n0 + node) * NODE_F + 64 + d * 32 + cb * 16 + l15] =
                            f2bfu(a[r] * attr[r]);
                }
            }
        }
    }
}

// ---------------- CSR build ----------------
__global__ void k_count(const int* __restrict__ edge_dst, int* deg, int E)
{
    int e = blockIdx.x * blockDim.x + threadIdx.x;
    if (e < E) atomicAdd(&deg[edge_dst[e]], 1);
}

__global__ __launch_bounds__(1024) void k_scan(const int* __restrict__ deg,
                                               int* __restrict__ off,
                                               int* __restrict__ cur, int N)
{
    __shared__ int swsum[16];
    __shared__ int swoff[16];
    __shared__ int sbase;
    __shared__ int stotal;
    int lane = threadIdx.x & 63, wid = threadIdx.x >> 6;
    if (threadIdx.x == 0) sbase = 0;
    __syncthreads();
    int ngroups = N >> 2;
    for (int base = 0; base < ngroups; base += 1024) {
        int g = base + threadIdx.x;
        int4 v = make_int4(0, 0, 0, 0);
        if (g < ngroups) v = ((const int4*)deg)[g];
        int s = v.x + v.y + v.z + v.w;
        int val = s;
        #pragma unroll
        for (int sh = 1; sh < 64; sh <<= 1) {
            int t = __shfl_up(val, sh);
            if (lane >= sh) val += t;
        }
        if (lane == 63) swsum[wid] = val;
        __syncthreads();
        if (threadIdx.x < 16) {
            int x = swsum[threadIdx.x];
            int xv = x;
            #pragma unroll
            for (int sh = 1; sh < 16; sh <<= 1) {
                int t = __shfl_up(xv, sh);
                if ((int)threadIdx.x >= sh) xv += t;
            }
            swoff[threadIdx.x] = xv - x;
            if (threadIdx.x == 15) stotal = xv;
        }
        __syncthreads();
        if (g < ngroups) {
            int b = sbase + swoff[wid] + (val - s);
            int4 o;
            o.x = b; o.y = b + v.x; o.z = o.y + v.y; o.w = o.z + v.z;
            ((int4*)off)[g] = o;
            ((int4*)cur)[g] = o;
        }
        __syncthreads();
        if (threadIdx.x == 0) sbase += stotal;
        __syncthreads();
    }
    if (threadIdx.x == 0) {
        int b = sbase;
        for (int i = (ngroups << 2); i < N; ++i) { off[i] = b; cur[i] = b; b += deg[i]; }
        off[N] = b;
    }
}

__global__ void k_scatter(const int* __restrict__ edge_dst,
                          int* cur, int* __restrict__ csr, int E)
{
    int e = blockIdx.x * blockDim.x + threadIdx.x;
    if (e < E) {
        int d = edge_dst[e];
        int pos = atomicAdd(&cur[d], 1);
        csr[pos] = e;
    }
}

// ---------------- fused edge kernel: pipelined 16-edge tiles, boundary-aware flush ----------------
#define FLUSH_AGG(node, AT)                                          \
    do {                                                             \
        float* an = agg + (size_t)(node) * AGG_F;                    \
        if (AT) {                                                    \
            atomicAdd(&an[lane], accA);                              \
            atomicAdd(&an[96  + lane], accB0);                       \
            atomicAdd(&an[192 + lane], accB1);                       \
            atomicAdd(&an[288 + lane], accB2);                       \
            if (lane < 32) {                                         \
                atomicAdd(&an[160 + u], accX0);                      \
                atomicAdd(&an[256 + u], accX1);                      \
                atomicAdd(&an[352 + u], accX2);                      \
            } else {                                                 \
                atomicAdd(&an[64 + u], accX0);                       \
            }                                                        \
        } else {                                                     \
            an[lane] = accA;                                         \
            an[96  + lane] = accB0;                                  \
            an[192 + lane] = accB1;                                  \
            an[288 + lane] = accB2;                                  \
            if (lane < 32) {                                         \
                an[160 + u] = accX0;                                 \
                an[256 + u] = accX1;                                 \
                an[352 + u] = accX2;                                 \
            } else {                                                 \
                an[64 + u] = accX0;                                  \
            }                                                        \
        }                                                            \
    } while (0)

__global__ __launch_bounds__(256, 3) void k_edge_fused(
    const unsigned short* __restrict__ f,
    const float* __restrict__ edge_scalars,
    const float* __restrict__ edge_attr,
    const float* __restrict__ fcW1,
    const float* __restrict__ fcW2,
    const int* __restrict__ edge_src,
    const int* __restrict__ edge_dst,
    const int* __restrict__ csr,
    const int* __restrict__ off,
    float* agg, int E)
{
    __shared__ unsigned short s_w2t[8 * 192 * 8];   // 24576 B
    __shared__ unsigned short s_w[4][16 * 216];     // 27648 B
    __shared__ float s_fcW1[512];                   //  2048 B

    int tid  = threadIdx.x;
    int lane = tid & 63;
    int wv   = tid >> 6;
    int l15  = lane & 15, lh = lane >> 4;
    int u    = lane & 31;

    for (int task = tid; task < 1536; task += 256) {
        int col = task % 192, oct = task / 192;
        const float* wp = fcW2 + (size_t)(oct * 8) * WNUM + col;
        unsigned pk0 = bf16pack(wp[0 * WNUM], wp[1 * WNUM]);
        unsigned pk1 = bf16pack(wp[2 * WNUM], wp[3 * WNUM]);
        unsigned pk2 = bf16pack(wp[4 * WNUM], wp[5 * WNUM]);
        unsigned pk3 = bf16pack(wp[6 * WNUM], wp[7 * WNUM]);
        *(uint4*)&s_w2t[oct * 1536 + col * 8] = make_uint4(pk0, pk1, pk2, pk3);
    }
    for (int i = tid; i < 512; i += 256)
        s_fcW1[i] = fcW1[i];
    __syncthreads();      // the only block barrier

    unsigned short* sw = s_w[wv];
    int nwt = (E + 15) >> 4;
    int stride4 = gridDim.x * 4;

    int wt = blockIdx.x * 4 + wv;
    if (wt >= nwt) return;

    // ---- prologue: metadata chain for first tile ----
    int P = wt << 4;
    int m = min(16, E - P);
    int e0 = csr[P + min(l15, m - 1)];
    int src = edge_src[e0];
    int dst = edge_dst[e0];
    float4 ea = *(const float4*)(edge_attr + (size_t)e0 * 4);
    float4 es0, es1;
    {
        const float4* esp = (const float4*)(edge_scalars + (size_t)e0 * RADF);
        es0 = esp[0]; es1 = esp[1];
    }

    while (true) {
        // ---- segment-boundary info (wave-uniform scalar loads) ----
        int firstd = rdlane(dst, 0);
        int lastd  = rdlane(dst, m - 1);
        int off_first = off[firstd];
        int off_last  = off[lastd + 1];

        int wt_n = wt + stride4;
        bool hn = wt_n < nwt;
        int P_n = hn ? (wt_n << 4) : 0;
        int m_n = hn ? min(16, E - P_n) : 1;

        // ---- issue next-tile csr FIRST ----
        int e_n = csr[hn ? (P_n + min(l15, m_n - 1)) : 0];

        // ---- issue current-tile f gather (bf16, 64 loads) ----
        float xs[16], xv0[16], xv1[16], xv2[16];
        #pragma unroll
        for (int i = 0; i < 16; ++i) {
            int si = rdlane(src, i);
            const unsigned short* fb = f + (size_t)si * NODE_F;
            xs[i]  = bf2f(fb[lane]);
            xv0[i] = bf2f(fb[64 + u]);
            xv1[i] = bf2f(fb[96 + u]);
            xv2[i] = bf2f(fb[128 + u]);
        }

        // ---- h compute (registers only; covers csr latency) ----
        float es[8] = {es0.x, es0.y, es0.z, es0.w, es1.x, es1.y, es1.z, es1.w};
        union { unsigned q[4]; bf16x8 v; } A0, A1;
        #pragma unroll
        for (int jp = 0; jp < 4; ++jp) {
            int k0 = lh * 8 + 2 * jp;
            float aL0 = 0.f, aL1 = 0.f, aH0 = 0.f, aH1 = 0.f;
            #pragma unroll
            for (int r = 0; r < 8; ++r) {
                float2 wl = *(const float2*)&s_fcW1[r * 64 + k0];
                float2 wh = *(const float2*)&s_fcW1[r * 64 + 32 + k0];
                aL0 = fmaf(es[r], wl.x, aL0);
                aL1 = fmaf(es[r], wl.y, aL1);
                aH0 = fmaf(es[r], wh.x, aH0);
                aH1 = fmaf(es[r], wh.y, aH1);
            }
            aL0 *= INV_SQRT8; aL1 *= INV_SQRT8; aH0 *= INV_SQRT8; aH1 *= INV_SQRT8;
            aL0 = aL0 / (1.f + __expf(-aL0));
            aL1 = aL1 / (1.f + __expf(-aL1));
            aH0 = aH0 / (1.f + __expf(-aH0));
            aH1 = aH1 / (1.f + __expf(-aH1));
            A0.q[jp] = bf16pack(aL0, aL1);
            A1.q[jp] = bf16pack(aH0, aH1);
        }

        // ---- issue next-tile metadata ----
        int src_n = edge_src[e_n];
        int dst_n = edge_dst[e_n];
        float4 ea_n = *(const float4*)(edge_attr + (size_t)e_n * 4);
        float4 es0_n, es1_n;
        {
            const float4* espn = (const float4*)(edge_scalars + (size_t)e_n * RADF);
            es0_n = espn[0]; es1_n = espn[1];
        }

        // ---- MFMA: w = h @ fcW2 / sqrt(64) ----
        #pragma unroll
        for (int cb = 0; cb < 12; ++cb) {
            bf16x8 b0 = *(const bf16x8*)&s_w2t[ lh      * 1536 + (cb * 16 + l15) * 8];
            bf16x8 b1 = *(const bf16x8*)&s_w2t[(4 + lh) * 1536 + (cb * 16 + l15) * 8];
            f32x4 acc = {0.f, 0.f, 0.f, 0.f};
            acc = __builtin_amdgcn_mfma_f32_16x16x32_bf16(A0.v, b0, acc, 0, 0, 0);
            acc = __builtin_amdgcn_mfma_f32_16x16x32_bf16(A1.v, b1, acc, 0, 0, 0);
            #pragma unroll
            for (int r = 0; r < 4; ++r)
                sw[(lh * 4 + r) * 216 + cb * 16 + l15] = f2bfu(acc[r] * INV_SQRT64);
        }

        // ---- TP + dst-segmented reduction (plain store if segment contained) ----
        float accA = 0.f, accB0 = 0.f, accB1 = 0.f, accB2 = 0.f;
        float accX0 = 0.f, accX1 = 0.f, accX2 = 0.f;
        int curd = rdlane(dst, 0);
        #pragma unroll
        for (int i = 0; i < 16; ++i) {
            if (i < m) {
                int di = rdlane(dst, i);
                if (di != curd) {
                    bool at = (curd == firstd) && (off_first < P);
                    FLUSH_AGG(curd, at);
                    accA = accB0 = accB1 = accB2 = 0.f;
                    accX0 = accX1 = accX2 = 0.f;
                    curd = di;
                }
                float eax = rdlanef(ea.x, i);
                float eay = rdlanef(ea.y, i);
                float eaz = rdlanef(ea.z, i);
                float eaw = rdlanef(ea.w, i);
                float W0 = bf2f(sw[i * 216 + lane]);
                float W1 = bf2f(sw[i * 216 + 64 + lane]);
                float W2 = bf2f(sw[i * 216 + 128 + lane]);
                accA = fmaf(W0 * xs[i], eax, accA);
                float bx = W1 * xs[i];
                accB0 = fmaf(bx, eay, accB0);
                accB1 = fmaf(bx, eaz, accB1);
                accB2 = fmaf(bx, eaw, accB2);
                if (lane < 32) {
                    float cc = W2 * eax;
                    accX0 = fmaf(cc, xv0[i], accX0);
                    accX1 = fmaf(cc, xv1[i], accX1);
                    accX2 = fmaf(cc, xv2[i], accX2);
                } else {
                    float dv = xv0[i] * eay + xv1[i] * eaz + xv2[i] * eaw;
                    accX0 = fmaf(W2 * INV_SQRT3, dv, accX0);
                }
            }
        }
        {
            bool at_fin = ((curd == firstd) && (off_first < P)) || (off_last > P + m);
            FLUSH_AGG(curd, at_fin);
        }

        if (!hn) break;
        wt = wt_n; P = P_n; m = m_n;
        src = src_n; dst = dst_n; ea = ea_n; es0 = es0_n; es1 = es1_n;
    }
}

// ---------------- kernel: output combine via MFMA, wave per 16 nodes ----------------
__global__ __launch_bounds__(256) void k_out(
    const float* __restrict__ node_input,
    const float* __restrict__ node_attr,
    const float* __restrict__ agg,
    const float* __restrict__ W_sc_s,
    const float* __restrict__ W_sc_v,
    const float* __restrict__ W2_s,
    const float* __restrict__ W2_v,
    const float* __restrict__ W3,
    float* __restrict__ out, int N)
{
    __shared__ unsigned short s_w2s[12 * 64 * 8];   // 12288 B
    __shared__ unsigned short s_wss[ 8 * 64 * 8];   //  8192 B
    __shared__ unsigned short s_w2v[12 * 32 * 8];   //  6144 B
    __shared__ unsigned short s_wsv[ 4 * 32 * 8];   //  2048 B
    __shared__ unsigned short s_w3 [12 * 16 * 8];   //  3072 B  -> 31744 B total

    const float pre = INV_SQRT10 * INV_SQRT96;
    int tid = threadIdx.x;

    for (int task = tid; task < 12 * 64; task += 256) {         // W2_s
        int col = task & 63, koct = task >> 6;
        const float* wp = W2_s + (size_t)(koct * 8) * MUL0 + col;
        unsigned pk0 = bf16pack(wp[0 * MUL0] * pre, wp[1 * MUL0] * pre);
        unsigned pk1 = bf16pack(wp[2 * MUL0] * pre, wp[3 * MUL0] * pre);
        unsigned pk2 = bf16pack(wp[4 * MUL0] * pre, wp[5 * MUL0] * pre);
        unsigned pk3 = bf16pack(wp[6 * MUL0] * pre, wp[7 * MUL0] * pre);
        *(uint4*)&s_w2s[task * 8] = make_uint4(pk0, pk1, pk2, pk3);
    }
    for (int task = tid; task < 8 * 64; task += 256) {          // W_sc_s
        int col = task & 63, koct = task >> 6;
        const float* wp = W_sc_s + (size_t)(koct * 8) * MUL0 + col;
        unsigned pk0 = bf16pack(wp[0 * MUL0] * INV_SQRT64, wp[1 * MUL0] * INV_SQRT64);
        unsigned pk1 = bf16pack(wp[2 * MUL0] * INV_SQRT64, wp[3 * MUL0] * INV_SQRT64);
        unsigned pk2 = bf16pack(wp[4 * MUL0] * INV_SQRT64, wp[5 * MUL0] * INV_SQRT64);
        unsigned pk3 = bf16pack(wp[6 * MUL0] * INV_SQRT64, wp[7 * MUL0] * INV_SQRT64);
        *(uint4*)&s_wss[task * 8] = make_uint4(pk0, pk1, pk2, pk3);
    }
    for (int task = tid; task < 12 * 32; task += 256) {         // W2_v
        int col = task & 31, koct = task >> 5;
        const float* wp = W2_v + (size_t)(koct * 8) * MUL1 + col;
        unsigned pk0 = bf16pack(wp[0 * MUL1] * pre, wp[1 * MUL1] * pre);
        unsigned pk1 = bf16pack(wp[2 * MUL1] * pre, wp[3 * MUL1] * pre);
        unsigned pk2 = bf16pack(wp[4 * MUL1] * pre, wp[5 * MUL1] * pre);
        unsigned pk3 = bf16pack(wp[6 * MUL1] * pre, wp[7 * MUL1] * pre);
        *(uint4*)&s_w2v[task * 8] = make_uint4(pk0, pk1, pk2, pk3);
    }
    for (int task = tid; task < 4 * 32; task += 256) {          // W_sc_v
        int col = task & 31, koct = task >> 5;
        const float* wp = W_sc_v + (size_t)(koct * 8) * MUL1 + col;
        unsigned pk0 = bf16pack(wp[0 * MUL1] * INV_SQRT32, wp[1 * MUL1] * INV_SQRT32);
        unsigned pk1 = bf16pack(wp[2 * MUL1] * INV_SQRT32, wp[3 * MUL1] * INV_SQRT32);
        unsigned pk2 = bf16pack(wp[4 * MUL1] * INV_SQRT32, wp[5 * MUL1] * INV_SQRT32);
        unsigned pk3 = bf16pack(wp[6 * MUL1] * INV_SQRT32, wp[7 * MUL1] * INV_SQRT32);
        *(uint4*)&s_wsv[task * 8] = make_uint4(pk0, pk1, pk2, pk3);
    }
    for (int task = tid; task < 12 * 16; task += 256) {         // W3 block
        int col = task & 15, koct = task >> 4;
        const float sc3 = 0.1f * pre;
        unsigned pk0 = 0, pk1 = 0, pk2 = 0, pk3 = 0;
        if (col == 0) {
            const float* wp = W3 + koct * 8;
            pk0 = bf16pack(wp[0] * sc3, wp[1] * sc3);
            pk1 = bf16pack(wp[2] * sc3, wp[3] * sc3);
            pk2 = bf16pack(wp[4] * sc3, wp[5] * sc3);
            pk3 = bf16pack(wp[6] * sc3, wp[7] * sc3);
        }
        *(uint4*)&s_w3[task * 8] = make_uint4(pk0, pk1, pk2, pk3);
    }
    __syncthreads();

    int lane = tid & 63;
    int wv = tid >> 6;
    int l15 = lane & 15, lh = lane >> 4;
    int ntiles = (N + 15) >> 4;

    for (int tile = blockIdx.x * 4 + wv; tile < ntiles; tile += gridDim.x * 4) {
        int n0 = tile << 4;
        int m = min(16, N - n0);
        int nrow = n0 + min(l15, m - 1);
        const float* agn = agg + (size_t)nrow * AGG_F;
        const float* inn = node_input + (size_t)nrow * NODE_F;

        bf16x8 aggA[3], inS[2];
        #pragma unroll
        for (int kk = 0; kk < 3; ++kk) {
            const float* p0 = agn + kk * 32 + lh * 8;
            aggA[kk] = cvt8(*(const float4*)p0, *(const float4*)(p0 + 4));
        }
        #pragma unroll
        for (int kk = 0; kk < 2; ++kk) {
            const float* p0 = inn + kk * 32 + lh * 8;
            inS[kk] = cvt8(*(const float4*)p0, *(const float4*)(p0 + 4));
        }

        f32x4 convS[4], scS[4], angD = {0.f, 0.f, 0.f, 0.f};
        #pragma unroll
        for (int cb = 0; cb < 4; ++cb) {
            f32x4 a = {0.f, 0.f, 0.f, 0.f};
            #pragma unroll
            for (int kk = 0; kk < 3; ++kk) {
                bf16x8 b = *(const bf16x8*)&s_w2s[(((kk * 4 + lh) * 64) + cb * 16 + l15) * 8];
                a = __builtin_amdgcn_mfma_f32_16x16x32_bf16(aggA[kk], b, a, 0, 0, 0);
            }
            convS[cb] = a;
            f32x4 s = {0.f, 0.f, 0.f, 0.f};
            #pragma unroll
            for (int kk = 0; kk < 2; ++kk) {
                bf16x8 b = *(const bf16x8*)&s_wss[(((kk * 4 + lh) * 64) + cb * 16 + l15) * 8];
                s = __builtin_amdgcn_mfma_f32_16x16x32_bf16(inS[kk], b, s, 0, 0, 0);
            }
            scS[cb] = s;
        }
        #pragma unroll
        for (int kk = 0; kk < 3; ++kk) {
            bf16x8 b = *(const bf16x8*)&s_w3[(((kk * 4 + lh) * 16) + l15) * 8];
            angD = __builtin_amdgcn_mfma_f32_16x16x32_bf16(aggA[kk], b, angD, 0, 0, 0);
        }

        float attr[4], cs[4], sn[4];
        #pragma unroll
        for (int r = 0; r < 4; ++r) {
            attr[r] = node_attr[n0 + min(lh * 4 + r, m - 1)];
            float ang = __shfl(angD[r], lane & 48) * attr[r];
            cs[r] = cosf(ang);
            sn[r] = sinf(ang);
        }

        #pragma unroll
        for (int cb = 0; cb < 4; ++cb)
            #pragma unroll
            for (int r = 0; r < 4; ++r) {
                int node = lh * 4 + r;
                if (node < m)
                    out[(size_t)(n0 + node) * NODE_F + cb * 16 + l15] =
                        attr[r] * (cs[r] * scS[cb][r] + sn[r] * convS[cb][r]);
            }

        #pragma unroll
        for (int d = 0; d < 3; ++d) {
            bf16x8 aggV[3], inV;
            #pragma unroll
            for (int kk = 0; kk < 3; ++kk) {
                const float* p0 = agn + 96 + d * 96 + kk * 32 + lh * 8;
                aggV[kk] = cvt8(*(const float4*)p0, *(const float4*)(p0 + 4));
            }
            {
                float t[8];
                #pragma unroll
                for (int j = 0; j < 8; ++j)
                    t[j] = inn[64 + (lh * 8 + j) * 3 + d];
                inV = cvt8(make_float4(t[0], t[1], t[2], t[3]),
                           make_float4(t[4], t[5], t[6], t[7]));
            }
            #pragma unroll
            for (int cb = 0; cb < 2; ++cb) {
                f32x4 a = {0.f, 0.f, 0.f, 0.f};
                #pragma unroll
                for (int kk = 0; kk < 3; ++kk) {
                    bf16x8 b = *(const bf16x8*)&s_w2v[(((kk * 4 + lh) * 32) + cb * 16 + l15) * 8];
                    a = __builtin_amdgcn_mfma_f32_16x16x32_bf16(aggV[kk], b, a, 0, 0, 0);
                }
                f32x4 s = {0.f, 0.f, 0.f, 0.f};
                {
                    bf16x8 b = *(const bf16x8*)&s_wsv[((lh * 32) + cb * 16 + l15) * 8];
                    s = __builtin_amdgcn_mfma_f32_16x16x32_bf16(inV, b, s, 0, 0, 0);
                }
                #pragma unroll
                for (int r = 0; r < 4; ++r) {
                    int node = lh * 4 + r;
                    if (node < m)
                        out[(size_t)(n0 + node) * NODE_F + 64 + (cb * 16 + l15) * 3 + d] =
                            attr[r] * (cs[r] * s[r] + sn[r] * a[r]);
                }
            }
        }
    }
}

extern "C" void kernel_launch(void* const* d_in, const int* in_sizes, int n_in,
                              void* d_out, int out_size, void* d_ws, size_t ws_size,
                              hipStream_t stream)
{
    const float* node_input   = (const float*)d_in[0];
    const float* node_attr    = (const float*)d_in[1];
    const float* edge_attr    = (const float*)d_in[2];
    const float* edge_scalars = (const float*)d_in[3];
    const float* W_sc_s       = (const float*)d_in[4];
    const float* W_sc_v       = (const float*)d_in[5];
    const float* W1_s         = (const float*)d_in[6];
    const float* W1_v         = (const float*)d_in[7];
    const float* W2_s         = (const float*)d_in[8];
    const float* W2_v         = (const float*)d_in[9];
    const float* W3           = (const float*)d_in[10];
    const float* fcW1         = (const float*)d_in[11];
    const float* fcW2         = (const float*)d_in[12];
    const int*   edge_src     = (const int*)d_in[13];
    const int*   edge_dst     = (const int*)d_in[14];
    float* out = (float*)d_out;

    const int N = in_sizes[1];
    const int E = in_sizes[13];

    // ---- workspace layout ----
    char* p = (char*)d_ws;
    float* agg = (float*)p;            p += (size_t)N * AGG_F * sizeof(float);
    unsigned short* fbf = (unsigned short*)p;  p += (size_t)N * NODE_F * sizeof(unsigned short);
    int*   deg = (int*)p;              p += (size_t)N * sizeof(int);
    int*   cur = (int*)p;              p += (size_t)N * sizeof(int);
    int*   csr = (int*)p;              p += (size_t)E * sizeof(int);
    int*   off = (int*)p;              p += (size_t)(N + 1) * sizeof(int);

    hipMemsetAsync(deg, 0, (size_t)N * sizeof(int), stream);
    hipMemsetAsync(agg, 0, (size_t)N * AGG_F * sizeof(float), stream);

    int eb = (E + 255) / 256;
    k_count<<<eb, 256, 0, stream>>>(edge_dst, deg, E);
    k_scan<<<1, 1024, 0, stream>>>(deg, off, cur, N);
    k_scatter<<<eb, 256, 0, stream>>>(edge_dst, cur, csr, E);

    int ntiles = (N + 15) / 16;
    int gridL = (ntiles + 3) / 4;
    k_node_lin<<<gridL, 256, 0, stream>>>(node_input, node_attr, W1_s, W1_v, fbf, N);

    int nwt = (E + 15) / 16;
    int gridF = (nwt + 3) / 4;
    if (gridF > 1536) gridF = 1536;
    k_edge_fused<<<gridF, 256, 0, stream>>>(fbf, edge_scalars, edge_attr, fcW1, fcW2,
                                            edge_src, edge_dst, csr, off, agg, E);

    int gridO = (ntiles + 3) / 4;
    if (gridO > 640) gridO = 640;
    k_out<<<gridO, 256, 0, stream>>>(node_input, node_attr, agg,
                                     W_sc_s, W_sc_v, W2_s, W2_v, W3, out, N);
}